// Round 6
// baseline (518.246 us; speedup 1.0000x reference)
//
#include <hip/hip_runtime.h>
#include <hip/hip_bf16.h>
#include <math.h>

#define B_ 4
#define T_ 2049      // keys = prompt + 2048
#define TB 2048
#define Q_ 801
#define H_ 16
#define HD 64
#define E_ 1024
#define MROWS (B_ * T_)   // 8196
#define MT_TILES 513      // ceil(8196/16)

typedef short short8 __attribute__((ext_vector_type(8)));
typedef float floatx4 __attribute__((ext_vector_type(4)));
typedef int int4v __attribute__((ext_vector_type(4)));
typedef unsigned uint2v __attribute__((ext_vector_type(2)));

__device__ __forceinline__ ushort f2bf(float x) {
    unsigned u = __float_as_uint(x);
    unsigned r = (u + 0x7fffu + ((u >> 16) & 1u)) >> 16;
    return (ushort)r;
}
__device__ __forceinline__ float bf2f(ushort h) {
    return __uint_as_float(((unsigned)h) << 16);
}
__device__ __forceinline__ void gload16(const void* g, void* l) {
    __builtin_amdgcn_global_load_lds(
        (const __attribute__((address_space(1))) void*)g,
        (__attribute__((address_space(3))) void*)l, 16, 0, 0);
}
// raw v_exp_f32: computes 2^x (hardware exp2)
__device__ __forceinline__ float exp2raw(float x) {
    float r;
    asm("v_exp_f32 %0, %1" : "=v"(r) : "v"(x));
    return r;
}
// v_cvt_pk_bf16_f32: low16 = bf16(a), high16 = bf16(b)
__device__ __forceinline__ unsigned cvtpk(float a, float b) {
    unsigned r;
    asm("v_cvt_pk_bf16_f32 %0, %1, %2" : "=v"(r) : "v"(a), "v"(b));
    return r;
}

// ---------------- Kernel 1: proj50[r,c] = sum_i pe[r,i] * Wpos[c,i] --------
__global__ __launch_bounds__(256) void proj50_kernel(
    const float* __restrict__ pe, const float* __restrict__ Wpos,
    float* __restrict__ proj50) {
    __shared__ float pes[1024];
    const int r = blockIdx.x;        // 0..49
    const int t = threadIdx.x;       // 256
    for (int p = 0; p < 4; ++p) pes[t + p * 256] = pe[(size_t)r * 1024 + t + p * 256];
    __syncthreads();
    const int c = blockIdx.y * 256 + t;
    const float4* w4 = (const float4*)(Wpos + (size_t)c * 1024);
    float acc = 0.f;
    for (int i = 0; i < 256; ++i) {
        float4 wv = w4[i];
        acc = fmaf(pes[4 * i + 0], wv.x, acc);
        acc = fmaf(pes[4 * i + 1], wv.y, acc);
        acc = fmaf(pes[4 * i + 2], wv.z, acc);
        acc = fmaf(pes[4 * i + 3], wv.w, acc);
    }
    proj50[(size_t)r * 1024 + c] = acc;
}

// ---------------- split_kv: kv rows -> MFMA-A-frag-major bf16 hi/lo --------
__global__ __launch_bounds__(256) void split_kv_kernel(
    const float* __restrict__ x_b, const float* __restrict__ pe,
    const float* __restrict__ prompt,
    ushort* __restrict__ afhi, ushort* __restrict__ aflo) {
    const int mt = blockIdx.x;            // 0..512
    const int t = threadIdx.x;
    const int lane = t & 63, kq = t >> 6;
    const int row_in = lane & 15, quad = lane >> 4;
    int m = mt * 16 + row_in; if (m > MROWS - 1) m = MROWS - 1;
    const int b = m / T_, tt = m - b * T_;
    const float* src; const float* pesrc; float psc;
    if (tt == 0) { src = prompt; pesrc = pe; psc = 0.f; }
    else {
        src = x_b + ((size_t)b * TB + tt - 1) * 1024;
        pesrc = pe + (size_t)(tt - 1) * 1024;
        psc = 1.f;
    }
    #pragma unroll
    for (int rep = 0; rep < 8; ++rep) {
        int kc = rep * 4 + kq;
        int k0 = kc * 32 + quad * 8;
        float4 xa = *(const float4*)(src + k0);
        float4 xb2 = *(const float4*)(src + k0 + 4);
        float4 pa = *(const float4*)(pesrc + k0);
        float4 pb = *(const float4*)(pesrc + k0 + 4);
        float vv[8];
        vv[0] = fmaf(psc, pa.x, xa.x);  vv[1] = fmaf(psc, pa.y, xa.y);
        vv[2] = fmaf(psc, pa.z, xa.z);  vv[3] = fmaf(psc, pa.w, xa.w);
        vv[4] = fmaf(psc, pb.x, xb2.x); vv[5] = fmaf(psc, pb.y, xb2.y);
        vv[6] = fmaf(psc, pb.z, xb2.z); vv[7] = fmaf(psc, pb.w, xb2.w);
        union { ushort u[8]; short8 s; } hu, lu;
        #pragma unroll
        for (int j = 0; j < 8; ++j) {
            ushort h = f2bf(vv[j]);
            hu.u[j] = h;
            lu.u[j] = f2bf(vv[j] - bf2f(h));
        }
        size_t off = ((size_t)(mt * 32 + kc) * 64 + lane) * 8;
        *(short8*)(afhi + off) = hu.s;
        *(short8*)(aflo + off) = lu.s;
    }
}

// ---------------- split_w: [Wk; Wv] rows -> frag-major bf16 hi/lo ----------
__global__ __launch_bounds__(256) void split_w_kernel(
    const float* __restrict__ Wk, const float* __restrict__ Wv,
    ushort* __restrict__ wfhi, ushort* __restrict__ wflo) {
    const int nt = blockIdx.x;            // 0..127 (concat K rows then V rows)
    const int t = threadIdx.x;
    const int lane = t & 63, kq = t >> 6;
    const int row_in = lane & 15, quad = lane >> 4;
    const int n = nt * 16 + row_in;       // 0..2047
    const float* src = (n < 1024) ? Wk + (size_t)n * 1024
                                  : Wv + (size_t)(n - 1024) * 1024;
    #pragma unroll
    for (int rep = 0; rep < 8; ++rep) {
        int kc = rep * 4 + kq;
        int k0 = kc * 32 + quad * 8;
        float4 xa = *(const float4*)(src + k0);
        float4 xb2 = *(const float4*)(src + k0 + 4);
        float vv[8] = {xa.x, xa.y, xa.z, xa.w, xb2.x, xb2.y, xb2.z, xb2.w};
        union { ushort u[8]; short8 s; } hu, lu;
        #pragma unroll
        for (int j = 0; j < 8; ++j) {
            ushort h = f2bf(vv[j]);
            hu.u[j] = h;
            lu.u[j] = f2bf(vv[j] - bf2f(h));
        }
        size_t off = ((size_t)(nt * 32 + kc) * 64 + lane) * 8;
        *(short8*)(wfhi + off) = hu.s;
        *(short8*)(wflo + off) = lu.s;
    }
}

// ---------------- Kernel 2: barrier-free MFMA K/V GEMM, XCD-localized ------
__global__ __launch_bounds__(256) void kv_mfma_kernel(
    const ushort* __restrict__ afhi, const ushort* __restrict__ aflo,
    const ushort* __restrict__ wfhi, const ushort* __restrict__ wflo,
    ushort* __restrict__ khi, ushort* __restrict__ klo,
    ushort* __restrict__ vfrag, ushort* __restrict__ v2048) {

    const int t = threadIdx.x, lane = t & 63, w = t >> 6;
    const int wm = w >> 1, wn = w & 1;
    const int bid = blockIdx.x;
    const int c = bid & 7, jj2 = bid >> 3;
    int xx, yy;
    if (jj2 < 128) { yy = ((jj2 >> 4) << 3) + c; xx = jj2 & 15; }
    else           { yy = 64; xx = c * 2 + (jj2 - 128); }
    const int m0 = yy * 128, n0x = xx * 128;
    const bool isK = (xx < 8);
    const size_t lb = (size_t)lane * 8;

    const ushort* ah_p[4]; const ushort* al_p[4];
    const ushort* bh_p[4]; const ushort* bl_p[4];
    #pragma unroll
    for (int i = 0; i < 4; ++i) {
        size_t mt = (size_t)(yy * 8 + wm * 4 + i);
        ah_p[i] = afhi + mt * 16384 + lb;
        al_p[i] = aflo + mt * 16384 + lb;
        size_t nt = (size_t)(xx * 8 + wn * 4 + i);
        bh_p[i] = wfhi + nt * 16384 + lb;
        bl_p[i] = wflo + nt * 16384 + lb;
    }

    floatx4 acc[4][4];
    #pragma unroll
    for (int i = 0; i < 4; ++i)
        #pragma unroll
        for (int j = 0; j < 4; ++j)
            acc[i][j] = (floatx4){0.f, 0.f, 0.f, 0.f};

    if (isK) {
        short8 a0h[4], a0l[4], b0h[4], b0l[4];
        short8 a1h[4], a1l[4], b1h[4], b1l[4];
        #pragma unroll
        for (int i = 0; i < 4; ++i) {
            a0h[i] = *(const short8*)(ah_p[i]);
            a0l[i] = *(const short8*)(al_p[i]);
            b0h[i] = *(const short8*)(bh_p[i]);
            b0l[i] = *(const short8*)(bl_p[i]);
        }
        #pragma unroll 1
        for (int kc = 0; kc < 32; kc += 2) {
            {
                const int ko = (kc + 1) * 512;
                #pragma unroll
                for (int i = 0; i < 4; ++i) {
                    a1h[i] = *(const short8*)(ah_p[i] + ko);
                    a1l[i] = *(const short8*)(al_p[i] + ko);
                    b1h[i] = *(const short8*)(bh_p[i] + ko);
                    b1l[i] = *(const short8*)(bl_p[i] + ko);
                }
            }
            #pragma unroll
            for (int i = 0; i < 4; ++i)
                #pragma unroll
                for (int j = 0; j < 4; ++j) {
                    acc[i][j] = __builtin_amdgcn_mfma_f32_16x16x32_bf16(a0h[i], b0h[j], acc[i][j], 0, 0, 0);
                    acc[i][j] = __builtin_amdgcn_mfma_f32_16x16x32_bf16(a0h[i], b0l[j], acc[i][j], 0, 0, 0);
                    acc[i][j] = __builtin_amdgcn_mfma_f32_16x16x32_bf16(a0l[i], b0h[j], acc[i][j], 0, 0, 0);
                }
            if (kc + 2 < 32) {
                const int ko = (kc + 2) * 512;
                #pragma unroll
                for (int i = 0; i < 4; ++i) {
                    a0h[i] = *(const short8*)(ah_p[i] + ko);
                    a0l[i] = *(const short8*)(al_p[i] + ko);
                    b0h[i] = *(const short8*)(bh_p[i] + ko);
                    b0l[i] = *(const short8*)(bl_p[i] + ko);
                }
            }
            #pragma unroll
            for (int i = 0; i < 4; ++i)
                #pragma unroll
                for (int j = 0; j < 4; ++j) {
                    acc[i][j] = __builtin_amdgcn_mfma_f32_16x16x32_bf16(a1h[i], b1h[j], acc[i][j], 0, 0, 0);
                    acc[i][j] = __builtin_amdgcn_mfma_f32_16x16x32_bf16(a1h[i], b1l[j], acc[i][j], 0, 0, 0);
                    acc[i][j] = __builtin_amdgcn_mfma_f32_16x16x32_bf16(a1l[i], b1h[j], acc[i][j], 0, 0, 0);
                }
        }
    } else {
        short8 a0h[4], b0h[4], b0l[4];
        short8 a1h[4], b1h[4], b1l[4];
        #pragma unroll
        for (int i = 0; i < 4; ++i) {
            a0h[i] = *(const short8*)(ah_p[i]);
            b0h[i] = *(const short8*)(bh_p[i]);
            b0l[i] = *(const short8*)(bl_p[i]);
        }
        #pragma unroll 1
        for (int kc = 0; kc < 32; kc += 2) {
            {
                const int ko = (kc + 1) * 512;
                #pragma unroll
                for (int i = 0; i < 4; ++i) {
                    a1h[i] = *(const short8*)(ah_p[i] + ko);
                    b1h[i] = *(const short8*)(bh_p[i] + ko);
                    b1l[i] = *(const short8*)(bl_p[i] + ko);
                }
            }
            #pragma unroll
            for (int i = 0; i < 4; ++i)
                #pragma unroll
                for (int j = 0; j < 4; ++j) {
                    acc[i][j] = __builtin_amdgcn_mfma_f32_16x16x32_bf16(a0h[i], b0h[j], acc[i][j], 0, 0, 0);
                    acc[i][j] = __builtin_amdgcn_mfma_f32_16x16x32_bf16(a0h[i], b0l[j], acc[i][j], 0, 0, 0);
                }
            if (kc + 2 < 32) {
                const int ko = (kc + 2) * 512;
                #pragma unroll
                for (int i = 0; i < 4; ++i) {
                    a0h[i] = *(const short8*)(ah_p[i] + ko);
                    b0h[i] = *(const short8*)(bh_p[i] + ko);
                    b0l[i] = *(const short8*)(bl_p[i] + ko);
                }
            }
            #pragma unroll
            for (int i = 0; i < 4; ++i)
                #pragma unroll
                for (int j = 0; j < 4; ++j) {
                    acc[i][j] = __builtin_amdgcn_mfma_f32_16x16x32_bf16(a1h[i], b1h[j], acc[i][j], 0, 0, 0);
                    acc[i][j] = __builtin_amdgcn_mfma_f32_16x16x32_bf16(a1h[i], b1l[j], acc[i][j], 0, 0, 0);
                }
        }
    }

    // epilogue: C layout col = lane&15, row = (lane>>4)*4 + reg
    const int frow = lane & 15, foct = lane >> 4;
    const int ncol = (n0x & 1023) + wn * 64 + frow;
    if (isK) {
        #pragma unroll
        for (int i = 0; i < 4; ++i) {
            #pragma unroll
            for (int r = 0; r < 4; ++r) {
                int row = m0 + wm * 64 + i * 16 + foct * 4 + r;
                if (row < MROWS) {
                    #pragma unroll
                    for (int j = 0; j < 4; ++j) {
                        float v = acc[i][j][r];
                        ushort hv = f2bf(v);
                        ushort lv = f2bf(v - bf2f(hv));
                        khi[(size_t)row * 1024 + ncol + j * 16] = hv;
                        klo[(size_t)row * 1024 + ncol + j * 16] = lv;
                    }
                }
            }
        }
    } else {
        // V: direct V^T fragment-major write (replaces vprep)
        const int hh = ((n0x & 1023) + wn * 64) >> 6;   // head 0..15
        #pragma unroll
        for (int i = 0; i < 4; ++i) {
            #pragma unroll
            for (int r = 0; r < 4; ++r) {
                int row = m0 + wm * 64 + i * 16 + foct * 4 + r;
                if (row < MROWS) {
                    int bb = row / T_;
                    int tt = row - bb * T_;      // key index 0..2048
                    if (tt < 2048) {
                        size_t vb = ((size_t)(bb * 16 + hh) * 65 + (tt >> 5)) * 4;
                        size_t lo_ = (size_t)(((tt >> 3) & 3) * 16 + frow) * 8 + (tt & 7);
                        #pragma unroll
                        for (int j = 0; j < 4; ++j)
                            vfrag[(vb + j) * 512 + lo_] = f2bf(acc[i][j][r]);
                    } else {
                        #pragma unroll
                        for (int j = 0; j < 4; ++j)
                            v2048[bb * 1024 + hh * 64 + j * 16 + frow] = f2bf(acc[i][j][r]);
                    }
                }
            }
        }
    }
}

// ---------------- attn helpers: K-tile register load + tile body -----------
__device__ __forceinline__ void loadKtile(
    short8 (&kb)[16], int t0, int frow,
    const ushort* __restrict__ khi, const ushort* __restrict__ klo,
    size_t krb, int kgFrom, int kgTo) {
    #pragma unroll
    for (int kg = 0; kg < 4; ++kg) {
        if (kg >= kgFrom && kg < kgTo) {
            size_t ro = krb + (size_t)(t0 + kg * 16 + frow) * 1024;
            kb[kg * 4 + 0] = *(const short8*)(khi + ro);
            kb[kg * 4 + 1] = *(const short8*)(klo + ro);
            kb[kg * 4 + 2] = *(const short8*)(khi + ro + 32);
            kb[kg * 4 + 3] = *(const short8*)(klo + ro + 32);
        }
    }
}

// ---------------- Kernel 3: barrier-free reg-pipelined MFMA attention ------
// R5 post-mortem: the per-tile barrier phase-locks all resident waves (and
// co-resident blocks self-synchronize via shared-pipe contention), so each
// pipe's util equals its phase share (~28% each). R4 showed direct global K
// without prefetch is latency-bound. This version = R4 + the missing piece:
// K tile t+1 is prefetched into a REGISTER double-buffer during tile t's
// compute (~1300 cyc covers L2 ~300), prefetch issued right after each
// kg-pair of the use-buffer dies (caps live K regs ~96). No LDS K, no
// barriers at all (Psh is per-wave, R5-proven). 4-wave blocks, 2 waves/SIMD
// (launch_bounds(256,2) caps VGPR at 256) — waves free-run and de-phase.
__global__ __launch_bounds__(256, 2) void attn_mfma_kernel(
    const float* __restrict__ debug, const float* __restrict__ proj50,
    const ushort* __restrict__ khi, const ushort* __restrict__ klo,
    const ushort* __restrict__ vfrag, const ushort* __restrict__ v2048,
    float* __restrict__ pout, float* __restrict__ pl) {

    __shared__ __align__(16) unsigned Pshh[4][16][20];   // 5 KB per plane
    __shared__ __align__(16) unsigned Pshl[4][16][20];

    const int t = threadIdx.x, lane = t & 63, w = t >> 6;   // 4 waves
    const int frow = lane & 15, quad = lane >> 4;
    const int h = blockIdx.y, b = blockIdx.z;
    const int qt = blockIdx.x >> 1, slice = blockIdx.x & 1;
    const int qwave = qt * 64 + w * 16;
    const int tstart = slice ? 1088 : 0;
    const int ntiles = slice ? 15 : 17;     // keys [0,1088) / [1088,2048)

    // Q in exp2 domain: scale = 0.125 * log2(e)
    const float qscale = 0.1803368801111244f;
    short8 qh[2], ql[2];
    {
        int qrow = qwave + frow; if (qrow > Q_ - 1) qrow = Q_ - 1;
        int idx = (qrow * 50) / Q_;
        const float* dsrc = debug + (((size_t)(b * H_ + h)) * Q_ + qrow) * HD;
        const float* psrc = proj50 + (size_t)idx * 1024 + h * HD;
        #pragma unroll
        for (int dc = 0; dc < 2; ++dc) {
            int d0 = dc * 32 + quad * 8;
            union { ushort u[8]; short8 v; } hh, ll;
            #pragma unroll
            for (int j = 0; j < 8; ++j) {
                float v = (dsrc[d0 + j] + psrc[d0 + j]) * qscale;
                ushort hv = f2bf(v);
                hh.u[j] = hv;
                ll.u[j] = f2bf(v - bf2f(hv));
            }
            qh[dc] = hh.v; ql[dc] = ll.v;
        }
    }

    floatx4 oacc[4];    // O^T: oacc[df][r] = O[q=frow][dim=df*16+quad*4+r]
    #pragma unroll
    for (int d = 0; d < 4; ++d) oacc[d] = (floatx4){0.f, 0.f, 0.f, 0.f};
    float lsum = 0.f;

    unsigned* Pwh = &Pshh[w][0][0];
    unsigned* Pwl = &Pshl[w][0][0];
    const size_t bT = (size_t)b * T_;
    const size_t vbh = (size_t)(b * 16 + h) * 65;
    const size_t krb = bT * 1024 + (size_t)h * 64 + quad * 8;

    short8 ka[16], kb[16];
    loadKtile(ka, tstart, frow, khi, klo, krb, 0, 4);   // prologue: tile 0

    #pragma unroll 1
    for (int ti = 0; ti < ntiles; ti += 2) {
        #pragma unroll
        for (int half = 0; half < 2; ++half) {
            const int tj = ti + half;
            if (half == 1 && tj >= ntiles) break;
            const int t0 = tstart + tj * 64;
            const bool pre = (tj + 1 < ntiles);
            short8 (&ku)[16] = (half == 0) ? ka : kb;
            short8 (&kp)[16] = (half == 0) ? kb : ka;

            // V reg-loads for THIS tile (used ~400+ cyc later, self-covered)
            short8 vreg[2][4];
            #pragma unroll
            for (int kc = 0; kc < 2; ++kc) {
                int kcg = (t0 >> 5) + kc;
                const ushort* vsrc = vfrag + ((vbh + kcg) * 4) * 512 + lane * 8;
                #pragma unroll
                for (int df = 0; df < 4; ++df)
                    vreg[kc][df] = *(const short8*)(vsrc + df * 512);
            }

            // swapped QK^T: sacc[kg] = C[key_local=quad*4+r][q=frow]
            floatx4 sacc[4];
            __builtin_amdgcn_s_setprio(1);
            #pragma unroll
            for (int kg = 0; kg < 2; ++kg) {
                floatx4 s = (floatx4){0.f, 0.f, 0.f, 0.f};
                s = __builtin_amdgcn_mfma_f32_16x16x32_bf16(ku[kg*4+0], qh[0], s, 0, 0, 0);
                s = __builtin_amdgcn_mfma_f32_16x16x32_bf16(ku[kg*4+1], qh[0], s, 0, 0, 0);
                s = __builtin_amdgcn_mfma_f32_16x16x32_bf16(ku[kg*4+0], ql[0], s, 0, 0, 0);
                s = __builtin_amdgcn_mfma_f32_16x16x32_bf16(ku[kg*4+2], qh[1], s, 0, 0, 0);
                s = __builtin_amdgcn_mfma_f32_16x16x32_bf16(ku[kg*4+3], qh[1], s, 0, 0, 0);
                s = __builtin_amdgcn_mfma_f32_16x16x32_bf16(ku[kg*4+2], ql[1], s, 0, 0, 0);
                sacc[kg] = s;
            }
            __builtin_amdgcn_s_setprio(0);
            // prefetch next tile's kg0,kg1 (ku[0..7] now dead -> regs reusable)
            if (pre) loadKtile(kp, t0 + 64, frow, khi, klo, krb, 0, 2);
            __builtin_amdgcn_s_setprio(1);
            #pragma unroll
            for (int kg = 2; kg < 4; ++kg) {
                floatx4 s = (floatx4){0.f, 0.f, 0.f, 0.f};
                s = __builtin_amdgcn_mfma_f32_16x16x32_bf16(ku[kg*4+0], qh[0], s, 0, 0, 0);
                s = __builtin_amdgcn_mfma_f32_16x16x32_bf16(ku[kg*4+1], qh[0], s, 0, 0, 0);
                s = __builtin_amdgcn_mfma_f32_16x16x32_bf16(ku[kg*4+0], ql[0], s, 0, 0, 0);
                s = __builtin_amdgcn_mfma_f32_16x16x32_bf16(ku[kg*4+2], qh[1], s, 0, 0, 0);
                s = __builtin_amdgcn_mfma_f32_16x16x32_bf16(ku[kg*4+3], qh[1], s, 0, 0, 0);
                s = __builtin_amdgcn_mfma_f32_16x16x32_bf16(ku[kg*4+2], ql[1], s, 0, 0, 0);
                sacc[kg] = s;
            }
            __builtin_amdgcn_s_setprio(0);
            if (pre) loadKtile(kp, t0 + 64, frow, khi, klo, krb, 2, 4);

            // per-kc: exp + cvt_pk pack -> Psh(b64) -> b128 read = B-frag, PV
            #pragma unroll
            for (int kc = 0; kc < 2; ++kc) {
                #pragma unroll
                for (int kg2 = 0; kg2 < 2; ++kg2) {
                    int kg = kc * 2 + kg2;
                    float p0 = exp2raw(sacc[kg][0]);
                    float p1 = exp2raw(sacc[kg][1]);
                    float p2 = exp2raw(sacc[kg][2]);
                    float p3 = exp2raw(sacc[kg][3]);
                    lsum += (p0 + p1) + (p2 + p3);
                    unsigned dh0 = cvtpk(p0, p1);
                    float l0 = p0 - __uint_as_float(dh0 << 16);
                    float l1 = p1 - __uint_as_float(dh0 & 0xffff0000u);
                    unsigned dl0 = cvtpk(l0, l1);
                    unsigned dh1 = cvtpk(p2, p3);
                    float l2 = p2 - __uint_as_float(dh1 << 16);
                    float l3 = p3 - __uint_as_float(dh1 & 0xffff0000u);
                    unsigned dl1 = cvtpk(l2, l3);
                    int k2 = kg2 * 8 + quad * 2;
                    *(uint2v*)&Pwh[frow * 20 + k2] = (uint2v){dh0, dh1};
                    *(uint2v*)&Pwl[frow * 20 + k2] = (uint2v){dl0, dl1};
                }
                short8 bh = *(const short8*)&Pwh[frow * 20 + quad * 4];
                short8 bl = *(const short8*)&Pwl[frow * 20 + quad * 4];
                __builtin_amdgcn_s_setprio(1);
                #pragma unroll
                for (int df = 0; df < 4; ++df) {
                    oacc[df] = __builtin_amdgcn_mfma_f32_16x16x32_bf16(vreg[kc][df], bh, oacc[df], 0, 0, 0);
                    oacc[df] = __builtin_amdgcn_mfma_f32_16x16x32_bf16(vreg[kc][df], bl, oacc[df], 0, 0, 0);
                }
                __builtin_amdgcn_s_setprio(0);
            }
        }
    }

    // l[q]: reduce partials over the 4 quads (lane bits 4,5)
    lsum += __shfl_xor(lsum, 16);
    lsum += __shfl_xor(lsum, 32);

    // key 2048 (last row): scalar fp32 path, slice 1 only
    if (slice) {
        const size_t ro = (bT + 2048) * 1024 + (size_t)h * 64 + quad * 8;
        float p = 0.f;
        #pragma unroll
        for (int dc = 0; dc < 2; ++dc) {
            union { short8 v; ushort u[8]; } KH, KL, QH, QL;
            KH.v = *(const short8*)(khi + ro + dc * 32);
            KL.v = *(const short8*)(klo + ro + dc * 32);
            QH.v = qh[dc]; QL.v = ql[dc];
            #pragma unroll
            for (int j = 0; j < 8; ++j) {
                float kf = bf2f(KH.u[j]) + bf2f(KL.u[j]);
                float qf = bf2f(QH.u[j]) + bf2f(QL.u[j]);
                p = fmaf(qf, kf, p);
            }
        }
        p += __shfl_xor(p, 16);
        p += __shfl_xor(p, 32);
        float e = exp2raw(p);
        lsum += e;
        const ushort* vr = v2048 + b * 1024 + h * 64 + quad * 4;
        #pragma unroll
        for (int df = 0; df < 4; ++df)
            #pragma unroll
            for (int r = 0; r < 4; ++r)
                oacc[df][r] = fmaf(e, bf2f(vr[df * 16 + r]), oacc[df][r]);
    }

    // epilogue: O^T -> contiguous float4 stores; q = frow
    int q = qwave + frow;
    if (q < Q_) {
        float* dst = pout + (((size_t)(slice * B_ + b)) * Q_ + q) * E_ + h * HD + quad * 4;
        #pragma unroll
        for (int df = 0; df < 4; ++df) {
            float4 o4;
            o4.x = oacc[df][0]; o4.y = oacc[df][1];
            o4.z = oacc[df][2]; o4.w = oacc[df][3];
            *(float4*)(dst + df * 16) = o4;
        }
        if (quad == 0)
            pl[(((size_t)(slice * B_ + b)) * H_ + h) * Q_ + q] = lsum;
    }
}

// ---------------- combine: out = gates * (O0+O1) / (l0+l1) -----------------
__global__ __launch_bounds__(256) void combine_kernel(
    const float* __restrict__ pout, const float* __restrict__ pl,
    const float* __restrict__ gates, float* __restrict__ out) {
    const int q = blockIdx.x, b = blockIdx.y, t = threadIdx.x;
    const int e0 = t * 4, h = e0 >> 6;
    const size_t r0 = ((size_t)b * Q_ + q) * E_ + e0;
    const size_t r1 = ((size_t)(B_ + b) * Q_ + q) * E_ + e0;
    float4 a = *(const float4*)(pout + r0);
    float4 c = *(const float4*)(pout + r1);
    float l = pl[((size_t)b * H_ + h) * Q_ + q]
            + pl[((size_t)(B_ + b) * H_ + h) * Q_ + q];
    float s = gates[0] / l;
    float4 o;
    o.x = (a.x + c.x) * s;
    o.y = (a.y + c.y) * s;
    o.z = (a.z + c.z) * s;
    o.w = (a.w + c.w) * s;
    *(float4*)(out + ((size_t)b * Q_ + q) * E_ + e0) = o;
}

// ---------------- Fallback fp32 path (if workspace too small) --------------
#define SMK 36
__global__ __launch_bounds__(256) void kv_gemm_kernel(
    const float* __restrict__ x_b, const float* __restrict__ pe,
    const float* __restrict__ prompt,
    const float* __restrict__ Wk, const float* __restrict__ Wv,
    float* __restrict__ kout, float* __restrict__ vout) {

    __shared__ float As[64][SMK];
    __shared__ float Bks[64][SMK];
    __shared__ float Bvs[64][SMK];

    const int t = threadIdx.x;
    const int m0 = blockIdx.y * 64;
    const int n0 = blockIdx.x * 64;
    const int tx = t & 15, ty = t >> 4;
    const int rr = t >> 2;
    const int kp = (t & 3) * 8;

    int m = m0 + rr;
    if (m >= MROWS) m = 0;
    const int bb = m / T_;
    const int tt = m - bb * T_;
    const float* aptr; const float* peptr; float pesc;
    if (tt == 0) { aptr = prompt; peptr = pe; pesc = 0.f; }
    else {
        aptr = x_b + ((size_t)bb * TB + (tt - 1)) * 1024;
        peptr = pe + (size_t)(tt - 1) * 1024;
        pesc = 1.f;
    }
    const float* wkp = Wk + (size_t)(n0 + rr) * 1024;
    const float* wvp = Wv + (size_t)(n0 + rr) * 1024;

    float ck[4][4] = {{0.f}}, cv[4][4] = {{0.f}};

    for (int k0 = 0; k0 < 1024; k0 += 32) {
        __syncthreads();
        {
            float4 xa0 = *(const float4*)(aptr + k0 + kp);
            float4 xa1 = *(const float4*)(aptr + k0 + kp + 4);
            float4 pe0 = *(const float4*)(peptr + k0 + kp);
            float4 pe1 = *(const float4*)(peptr + k0 + kp + 4);
            xa0.x = fmaf(pesc, pe0.x, xa0.x);
            xa0.y = fmaf(pesc, pe0.y, xa0.y);
            xa0.z = fmaf(pesc, pe0.z, xa0.z);
            xa0.w = fmaf(pesc, pe0.w, xa0.w);
            xa1.x = fmaf(pesc, pe1.x, xa1.x);
            xa1.y = fmaf(pesc, pe1.y, xa1.y);
            xa1.z = fmaf(pesc, pe1.z, xa1.z);
            xa1.w = fmaf(pesc, pe1.w, xa1.w);
            *(float4*)&As[rr][kp]     = xa0;
            *(float4*)&As[rr][kp + 4] = xa1;
            *(float4*)&Bks[rr][kp]     = *(const float4*)(wkp + k0 + kp);
            *(float4*)&Bks[rr][kp + 4] = *(const float4*)(wkp + k0 + kp + 4);
            *(float4*)&Bvs[rr][kp]     = *(const float4*)(wvp + k0 + kp);
            *(float4*)&Bvs[rr][kp + 4] = *(const float4*)(wvp + k0 + kp + 4);
        }
        __syncthreads();
        for (int k4 = 0; k4 < 8; ++k4) {
            float4 a[4], bk[4], bv[4];
            #pragma unroll
            for (int i = 0; i < 4; ++i) a[i] = *(const float4*)&As[ty * 4 + i][k4 * 4];
            #pragma unroll
            for (int j = 0; j < 4; ++j) {
                bk[j] = *(const float4*)&Bks[tx * 4 + j][k4 * 4];
                bv[j] = *(const float4*)&Bvs[tx * 4 + j][k4 * 4];
            }
            #pragma unroll
            for (int i = 0; i < 4; ++i)
                #pragma unroll
                for (int j = 0; j < 4; ++j) {
                    ck[i][j] = fmaf(a[i].x, bk[j].x, ck[i][j]);
                    ck[i][j] = fmaf(a[i].y, bk[j].y, ck[i][j]);
                    ck[i][j] = fmaf(a[i].z, bk[j].z, ck[i][j]);
                    ck[i][j] = fmaf(a[i].w, bk[j].w, ck[i][j]);
                    cv[i][j] = fmaf(a[i].x, bv[j].x, cv[i][j]);
                    cv[i][j] = fmaf(a[i].y, bv[j].y, cv[i][j]);
                    cv[i][j] = fmaf(a[i].z, bv[j].z, cv[i][j]);
                    cv[i][j] = fmaf(a[i].w, bv[j].w, cv[i][j]);
                }
        }
    }

    #pragma unroll
    for (int i = 0; i < 4; ++i) {
        int mrow = m0 + ty * 4 + i;
        if (mrow < MROWS) {
            float4 kq, vq;
            kq.x = ck[i][0]; kq.y = ck[i][1]; kq.z = ck[i][2]; kq.w = ck[i][3];
            vq.x = cv[i][0]; vq.y = cv[i][1]; vq.z = cv[i][2]; vq.w = cv[i][3];
            *(float4*)(kout + (size_t)mrow * 1024 + n0 + tx * 4) = kq;
            *(float4*)(vout + (size_t)mrow * 1024 + n0 + tx * 4) = vq;
        }
    }
}

#define KSTR 68
__device__ __forceinline__ float dot16(const float (&q)[16], const float* kf) {
    float4 k0 = *(const float4*)(kf);
    float4 k1 = *(const float4*)(kf + 4);
    float4 k2 = *(const float4*)(kf + 8);
    float4 k3 = *(const float4*)(kf + 12);
    float p;
    p = q[0] * k0.x;
    p = fmaf(q[1], k0.y, p);  p = fmaf(q[2], k0.z, p);  p = fmaf(q[3], k0.w, p);
    p = fmaf(q[4], k1.x, p);  p = fmaf(q[5], k1.y, p);  p = fmaf(q[6], k1.z, p);  p = fmaf(q[7], k1.w, p);
    p = fmaf(q[8], k2.x, p);  p = fmaf(q[9], k2.y, p);  p = fmaf(q[10], k2.z, p); p = fmaf(q[11], k2.w, p);
    p = fmaf(q[12], k3.x, p); p = fmaf(q[13], k3.y, p); p = fmaf(q[14], k3.z, p); p = fmaf(q[15], k3.w, p);
    return p;
}
__device__ __forceinline__ void pv16(float (&o)[16], float pk, const float* vf) {
    float4 v0 = *(const float4*)(vf);
    float4 v1 = *(const float4*)(vf + 4);
    float4 v2 = *(const float4*)(vf + 8);
    float4 v3 = *(const float4*)(vf + 12);
    o[0]  = fmaf(pk, v0.x, o[0]);  o[1]  = fmaf(pk, v0.y, o[1]);
    o[2]  = fmaf(pk, v0.z, o[2]);  o[3]  = fmaf(pk, v0.w, o[3]);
    o[4]  = fmaf(pk, v1.x, o[4]);  o[5]  = fmaf(pk, v1.y, o[5]);
    o[6]  = fmaf(pk, v1.z, o[6]);  o[7]  = fmaf(pk, v1.w, o[7]);
    o[8]  = fmaf(pk, v2.x, o[8]);  o[9]  = fmaf(pk, v2.y, o[9]);
    o[10] = fmaf(pk, v2.z, o[10]); o[11] = fmaf(pk, v2.w, o[11]);
    o[12] = fmaf(pk, v3.x, o[12]); o[13] = fmaf(pk, v3.y, o[13]);
    o[14] = fmaf(pk, v3.z, o[14]); o[15] = fmaf(pk, v3.w, o[15]);
}

__global__ __launch_bounds__(256) void attn_kernel(
    const float* __restrict__ debug, const float* __restrict__ proj50,
    const float* __restrict__ kmat, const float* __restrict__ vmat,
    const float* __restrict__ gates, float* __restrict__ out) {

    __shared__ float k_s[64][KSTR];
    __shared__ float v_s[64][KSTR];

    const int t = threadIdx.x;
    const int lane = t & 63;
    const int w = t >> 6;
    const int r = lane >> 2;
    const int g = lane & 3;
    const int qi = blockIdx.x * 64 + w * 16 + r;
    const int h = blockIdx.y, b = blockIdx.z;
    const bool valid = qi < Q_;

    float q[16], o[16];
    {
        int qq = valid ? qi : 0;
        int idx = (qq * 50) / Q_;
        const float* dsrc = debug + (((size_t)(b * H_ + h)) * Q_ + qq) * HD + g * 16;
        const float* psrc = proj50 + (size_t)idx * 1024 + h * HD + g * 16;
        #pragma unroll
        for (int j4 = 0; j4 < 4; ++j4) {
            float4 dv = *(const float4*)(dsrc + j4 * 4);
            float4 pv = *(const float4*)(psrc + j4 * 4);
            q[j4 * 4 + 0] = (dv.x + pv.x) * 0.125f;
            q[j4 * 4 + 1] = (dv.y + pv.y) * 0.125f;
            q[j4 * 4 + 2] = (dv.z + pv.z) * 0.125f;
            q[j4 * 4 + 3] = (dv.w + pv.w) * 0.125f;
        }
    }
    float mrun = -INFINITY, lrun = 0.f;
    #pragma unroll
    for (int j = 0; j < 16; ++j) o[j] = 0.f;

    const int srow = t >> 2;
    const int scol = (t & 3) * 16;
    const float* kbase = kmat + ((size_t)b * T_) * E_ + h * HD + scol;
    const float* vbase = vmat + ((size_t)b * T_) * E_ + h * HD + scol;

    for (int t0 = 0; t0 < 2048; t0 += 64) {
        __syncthreads();
        {
            const float* kr = kbase + (size_t)(t0 + srow) * E_;
            const float* vr = vbase + (size_t)(t0 + srow) * E_;
            #pragma unroll
            for (int j4 = 0; j4 < 4; ++j4) {
                *(float4*)&k_s[srow][scol + j4 * 4] = *(const float4*)(kr + j4 * 4);
                *(float4*)&v_s[srow][scol + j4 * 4] = *(const float4*)(vr + j4 * 4);
            }
        }
        __syncthreads();
        #pragma unroll 1
        for (int kb = 0; kb < 64; kb += 16) {
            float sc[16];
            #pragma unroll
            for (int kk = 0; kk < 16; ++kk) {
                float p = dot16(q, &k_s[kb + kk][g * 16]);
                p += __shfl_xor(p, 1);
                p += __shfl_xor(p, 2);
                sc[kk] = p;
            }
            float mt = sc[0];
            #pragma unroll
            for (int kk = 1; kk < 16; ++kk) mt = fmaxf(mt, sc[kk]);
            float mn = fmaxf(mrun, mt);
            float al = __expf(mrun - mn);
            float ssum = 0.f;
            #pragma unroll
            for (int kk = 0; kk < 16; ++kk) { sc[kk] = __expf(sc[kk] - mn); ssum += sc[kk]; }
            mrun = mn;
            lrun = fmaf(lrun, al, ssum);
            #pragma unroll
            for (int j = 0; j < 16; ++j) o[j] *= al;
            #pragma unroll
            for (int kk = 0; kk < 16; ++kk) pv16(o, sc[kk], &v_s[kb + kk][g * 16]);
        }
    }
    {
        const float* kr = kmat + ((size_t)(b * T_ + 2048)) * E_ + h * HD + g * 16;
        const float* vr = vmat + ((size_t)(b * T_ + 2048)) * E_ + h * HD + g * 16;
        float p = dot16(q, kr);
        p += __shfl_xor(p, 1);
        p += __shfl_xor(p, 2);
        float mn = fmaxf(mrun, p);
        float al = __expf(mrun - mn);
        float pk = __expf(p - mn);
        lrun = fmaf(lrun, al, pk);
        #pragma unroll
        for (int j = 0; j < 16; ++j) o[j] *= al;
        pv16(o, pk, vr);
    }

    if (valid) {
        float s = gates[0] / lrun;
        float* dst = out + ((size_t)b * Q_ + qi) * E_ + h * HD + g * 16;
        #pragma unroll
        for (int j4 = 0; j4 < 4; ++j4) {
            float4 ov;
            ov.x = o[j4 * 4 + 0] * s;
            ov.y = o[j4 * 4 + 1] * s;
            ov.z = o[j4 * 4 + 2] * s;
            ov.w = o[j4 * 4 + 3] * s;
            *(float4*)(dst + j4 * 4) = ov;
        }
    }
}

extern "C" void kernel_launch(void* const* d_in, const int* in_sizes, int n_in,
                              void* d_out, int out_size, void* d_ws, size_t ws_size,
                              hipStream_t stream) {
    // inputs: x_a(0), x_b(1), debug(2), Wk(3), Wv(4), Wpos(5),
    //         prompt(6), gates(7), pe(8), full_b_step(9), full_a_step(10)
    const float* x_b = (const float*)d_in[1];
    const float* debug = (const float*)d_in[2];
    const float* Wk = (const float*)d_in[3];
    const float* Wv = (const float*)d_in[4];
    const float* Wpos = (const float*)d_in[5];
    const float* prompt = (const float*)d_in[6];
    const float* gates = (const float*)d_in[7];
    const float* pe = (const float*)d_in[8];
    float* out = (float*)d_out;

    char* ws = (char*)d_ws;
    const size_t KVH = (size_t)MROWS * 1024 * sizeof(ushort);      // 16,785,408
    const size_t KVF = (size_t)MROWS * 1024 * sizeof(float);       // 33,570,816
    const size_t AF  = (size_t)MT_TILES * 32 * 64 * 8 * sizeof(ushort);  // 16,809,984
    const size_t WF  = (size_t)128 * 32 * 64 * 8 * sizeof(ushort);       //  4,194,304
    const size_t P50 = 256 * 1024;

    float*  proj50 = (float*)ws;                   // 200 KB used of 256 KB
    ushort* v2048u = (ushort*)(ws + 240 * 1024);   // 8 KB spare in P50 slab
    ushort* khi  = (ushort*)(ws + P50);
    ushort* klo  = (ushort*)(ws + P50 + KVH);
    float*  vbuf = (float*)(ws + P50 + 2 * KVH);   // fp32 region (fallback)
    ushort* afhi = (ushort*)(ws + P50 + 2 * KVH + KVF);
    ushort* aflo = (ushort*)(ws + P50 + 2 * KVH + KVF + AF);
    ushort* wfhi = (ushort*)(ws + P50 + 2 * KVH + KVF + 2 * AF);
    ushort* wflo = (ushort*)(ws + P50 + 2 * KVH + KVF + 2 * AF + WF);
    // main path aliasing:
    //  vfrag (17.04 MB) lives in the vbuf region (33.57 MB) — written by
    //    kv_mfma, read by attn (vbuf is fallback-only otherwise)
    //  pout (26.25 MB) + pl (0.41 MB) live in afhi+aflo (33.62 MB), dead
    //    after kv_mfma — attn writes them, combine reads them
    ushort* vfrag = (ushort*)vbuf;
    float* pout = (float*)afhi;
    float* plse = pout + (size_t)2 * B_ * Q_ * E_;
    const size_t needed = P50 + 2 * KVH + KVF + 2 * AF + 2 * WF;  // 109,412,352

    proj50_kernel<<<dim3(50, 4), 256, 0, stream>>>(pe, Wpos, proj50);

    if (ws_size >= needed) {
        split_kv_kernel<<<dim3(MT_TILES), 256, 0, stream>>>(x_b, pe, prompt, afhi, aflo);
        split_w_kernel<<<dim3(128), 256, 0, stream>>>(Wk, Wv, wfhi, wflo);
        kv_mfma_kernel<<<dim3(1040), 256, 0, stream>>>(afhi, aflo, wfhi, wflo,
                                                       khi, klo, vfrag, v2048u);
        attn_mfma_kernel<<<dim3(26, H_, B_), 256, 0, stream>>>(
            debug, proj50, khi, klo, vfrag, v2048u, pout, plse);
        combine_kernel<<<dim3(Q_, B_), 256, 0, stream>>>(pout, plse, gates, out);
    } else {
        float* kbuf = (float*)khi;   // fallback: fp32 K in khi+klo region (same size)
        kv_gemm_kernel<<<dim3(16, 129), 256, 0, stream>>>(x_b, pe, prompt, Wk, Wv, kbuf, vbuf);
        attn_kernel<<<dim3(13, H_, B_), 256, 0, stream>>>(debug, proj50, kbuf, vbuf, gates, out);
    }
}

// Round 7
// 395.189 us; speedup vs baseline: 1.3114x; 1.3114x over previous
//
#include <hip/hip_runtime.h>
#include <hip/hip_bf16.h>
#include <math.h>

#define B_ 4
#define T_ 2049      // keys = prompt + 2048
#define TB 2048
#define Q_ 801
#define H_ 16
#define HD 64
#define E_ 1024
#define MROWS (B_ * T_)   // 8196
#define MT_TILES 513      // ceil(8196/16)

typedef short short8 __attribute__((ext_vector_type(8)));
typedef float floatx4 __attribute__((ext_vector_type(4)));
typedef int int4v __attribute__((ext_vector_type(4)));
typedef unsigned uint2v __attribute__((ext_vector_type(2)));

__device__ __forceinline__ ushort f2bf(float x) {
    unsigned u = __float_as_uint(x);
    unsigned r = (u + 0x7fffu + ((u >> 16) & 1u)) >> 16;
    return (ushort)r;
}
__device__ __forceinline__ float bf2f(ushort h) {
    return __uint_as_float(((unsigned)h) << 16);
}
__device__ __forceinline__ void gload16(const void* g, void* l) {
    __builtin_amdgcn_global_load_lds(
        (const __attribute__((address_space(1))) void*)g,
        (__attribute__((address_space(3))) void*)l, 16, 0, 0);
}
// raw v_exp_f32: computes 2^x (hardware exp2)
__device__ __forceinline__ float exp2raw(float x) {
    float r;
    asm("v_exp_f32 %0, %1" : "=v"(r) : "v"(x));
    return r;
}
// v_cvt_pk_bf16_f32: low16 = bf16(a), high16 = bf16(b)
__device__ __forceinline__ unsigned cvtpk(float a, float b) {
    unsigned r;
    asm("v_cvt_pk_bf16_f32 %0, %1, %2" : "=v"(r) : "v"(a), "v"(b));
    return r;
}

// ---------------- Kernel 1: proj50[r,c] = sum_i pe[r,i] * Wpos[c,i] --------
__global__ __launch_bounds__(256) void proj50_kernel(
    const float* __restrict__ pe, const float* __restrict__ Wpos,
    float* __restrict__ proj50) {
    __shared__ float pes[1024];
    const int r = blockIdx.x;        // 0..49
    const int t = threadIdx.x;       // 256
    for (int p = 0; p < 4; ++p) pes[t + p * 256] = pe[(size_t)r * 1024 + t + p * 256];
    __syncthreads();
    const int c = blockIdx.y * 256 + t;
    const float4* w4 = (const float4*)(Wpos + (size_t)c * 1024);
    float acc = 0.f;
    for (int i = 0; i < 256; ++i) {
        float4 wv = w4[i];
        acc = fmaf(pes[4 * i + 0], wv.x, acc);
        acc = fmaf(pes[4 * i + 1], wv.y, acc);
        acc = fmaf(pes[4 * i + 2], wv.z, acc);
        acc = fmaf(pes[4 * i + 3], wv.w, acc);
    }
    proj50[(size_t)r * 1024 + c] = acc;
}

// ---------------- split_kv: kv rows -> MFMA-A-frag-major bf16 hi/lo --------
__global__ __launch_bounds__(256) void split_kv_kernel(
    const float* __restrict__ x_b, const float* __restrict__ pe,
    const float* __restrict__ prompt,
    ushort* __restrict__ afhi, ushort* __restrict__ aflo) {
    const int mt = blockIdx.x;            // 0..512
    const int t = threadIdx.x;
    const int lane = t & 63, kq = t >> 6;
    const int row_in = lane & 15, quad = lane >> 4;
    int m = mt * 16 + row_in; if (m > MROWS - 1) m = MROWS - 1;
    const int b = m / T_, tt = m - b * T_;
    const float* src; const float* pesrc; float psc;
    if (tt == 0) { src = prompt; pesrc = pe; psc = 0.f; }
    else {
        src = x_b + ((size_t)b * TB + tt - 1) * 1024;
        pesrc = pe + (size_t)(tt - 1) * 1024;
        psc = 1.f;
    }
    #pragma unroll
    for (int rep = 0; rep < 8; ++rep) {
        int kc = rep * 4 + kq;
        int k0 = kc * 32 + quad * 8;
        float4 xa = *(const float4*)(src + k0);
        float4 xb2 = *(const float4*)(src + k0 + 4);
        float4 pa = *(const float4*)(pesrc + k0);
        float4 pb = *(const float4*)(pesrc + k0 + 4);
        float vv[8];
        vv[0] = fmaf(psc, pa.x, xa.x);  vv[1] = fmaf(psc, pa.y, xa.y);
        vv[2] = fmaf(psc, pa.z, xa.z);  vv[3] = fmaf(psc, pa.w, xa.w);
        vv[4] = fmaf(psc, pb.x, xb2.x); vv[5] = fmaf(psc, pb.y, xb2.y);
        vv[6] = fmaf(psc, pb.z, xb2.z); vv[7] = fmaf(psc, pb.w, xb2.w);
        union { ushort u[8]; short8 s; } hu, lu;
        #pragma unroll
        for (int j = 0; j < 8; ++j) {
            ushort h = f2bf(vv[j]);
            hu.u[j] = h;
            lu.u[j] = f2bf(vv[j] - bf2f(h));
        }
        size_t off = ((size_t)(mt * 32 + kc) * 64 + lane) * 8;
        *(short8*)(afhi + off) = hu.s;
        *(short8*)(aflo + off) = lu.s;
    }
}

// ---------------- split_w: [Wk; Wv] rows -> frag-major bf16 hi/lo ----------
__global__ __launch_bounds__(256) void split_w_kernel(
    const float* __restrict__ Wk, const float* __restrict__ Wv,
    ushort* __restrict__ wfhi, ushort* __restrict__ wflo) {
    const int nt = blockIdx.x;            // 0..127 (concat K rows then V rows)
    const int t = threadIdx.x;
    const int lane = t & 63, kq = t >> 6;
    const int row_in = lane & 15, quad = lane >> 4;
    const int n = nt * 16 + row_in;       // 0..2047
    const float* src = (n < 1024) ? Wk + (size_t)n * 1024
                                  : Wv + (size_t)(n - 1024) * 1024;
    #pragma unroll
    for (int rep = 0; rep < 8; ++rep) {
        int kc = rep * 4 + kq;
        int k0 = kc * 32 + quad * 8;
        float4 xa = *(const float4*)(src + k0);
        float4 xb2 = *(const float4*)(src + k0 + 4);
        float vv[8] = {xa.x, xa.y, xa.z, xa.w, xb2.x, xb2.y, xb2.z, xb2.w};
        union { ushort u[8]; short8 s; } hu, lu;
        #pragma unroll
        for (int j = 0; j < 8; ++j) {
            ushort h = f2bf(vv[j]);
            hu.u[j] = h;
            lu.u[j] = f2bf(vv[j] - bf2f(h));
        }
        size_t off = ((size_t)(nt * 32 + kc) * 64 + lane) * 8;
        *(short8*)(wfhi + off) = hu.s;
        *(short8*)(wflo + off) = lu.s;
    }
}

// ---------------- Kernel 2: barrier-free MFMA K/V GEMM, XCD-localized ------
__global__ __launch_bounds__(256) void kv_mfma_kernel(
    const ushort* __restrict__ afhi, const ushort* __restrict__ aflo,
    const ushort* __restrict__ wfhi, const ushort* __restrict__ wflo,
    ushort* __restrict__ khi, ushort* __restrict__ klo,
    ushort* __restrict__ vfrag, ushort* __restrict__ v2048) {

    const int t = threadIdx.x, lane = t & 63, w = t >> 6;
    const int wm = w >> 1, wn = w & 1;
    const int bid = blockIdx.x;
    const int c = bid & 7, jj2 = bid >> 3;
    int xx, yy;
    if (jj2 < 128) { yy = ((jj2 >> 4) << 3) + c; xx = jj2 & 15; }
    else           { yy = 64; xx = c * 2 + (jj2 - 128); }
    const int m0 = yy * 128, n0x = xx * 128;
    const bool isK = (xx < 8);
    const size_t lb = (size_t)lane * 8;

    const ushort* ah_p[4]; const ushort* al_p[4];
    const ushort* bh_p[4]; const ushort* bl_p[4];
    #pragma unroll
    for (int i = 0; i < 4; ++i) {
        size_t mt = (size_t)(yy * 8 + wm * 4 + i);
        ah_p[i] = afhi + mt * 16384 + lb;
        al_p[i] = aflo + mt * 16384 + lb;
        size_t nt = (size_t)(xx * 8 + wn * 4 + i);
        bh_p[i] = wfhi + nt * 16384 + lb;
        bl_p[i] = wflo + nt * 16384 + lb;
    }

    floatx4 acc[4][4];
    #pragma unroll
    for (int i = 0; i < 4; ++i)
        #pragma unroll
        for (int j = 0; j < 4; ++j)
            acc[i][j] = (floatx4){0.f, 0.f, 0.f, 0.f};

    if (isK) {
        short8 a0h[4], a0l[4], b0h[4], b0l[4];
        short8 a1h[4], a1l[4], b1h[4], b1l[4];
        #pragma unroll
        for (int i = 0; i < 4; ++i) {
            a0h[i] = *(const short8*)(ah_p[i]);
            a0l[i] = *(const short8*)(al_p[i]);
            b0h[i] = *(const short8*)(bh_p[i]);
            b0l[i] = *(const short8*)(bl_p[i]);
        }
        #pragma unroll 1
        for (int kc = 0; kc < 32; kc += 2) {
            {
                const int ko = (kc + 1) * 512;
                #pragma unroll
                for (int i = 0; i < 4; ++i) {
                    a1h[i] = *(const short8*)(ah_p[i] + ko);
                    a1l[i] = *(const short8*)(al_p[i] + ko);
                    b1h[i] = *(const short8*)(bh_p[i] + ko);
                    b1l[i] = *(const short8*)(bl_p[i] + ko);
                }
            }
            #pragma unroll
            for (int i = 0; i < 4; ++i)
                #pragma unroll
                for (int j = 0; j < 4; ++j) {
                    acc[i][j] = __builtin_amdgcn_mfma_f32_16x16x32_bf16(a0h[i], b0h[j], acc[i][j], 0, 0, 0);
                    acc[i][j] = __builtin_amdgcn_mfma_f32_16x16x32_bf16(a0h[i], b0l[j], acc[i][j], 0, 0, 0);
                    acc[i][j] = __builtin_amdgcn_mfma_f32_16x16x32_bf16(a0l[i], b0h[j], acc[i][j], 0, 0, 0);
                }
            if (kc + 2 < 32) {
                const int ko = (kc + 2) * 512;
                #pragma unroll
                for (int i = 0; i < 4; ++i) {
                    a0h[i] = *(const short8*)(ah_p[i] + ko);
                    a0l[i] = *(const short8*)(al_p[i] + ko);
                    b0h[i] = *(const short8*)(bh_p[i] + ko);
                    b0l[i] = *(const short8*)(bl_p[i] + ko);
                }
            }
            #pragma unroll
            for (int i = 0; i < 4; ++i)
                #pragma unroll
                for (int j = 0; j < 4; ++j) {
                    acc[i][j] = __builtin_amdgcn_mfma_f32_16x16x32_bf16(a1h[i], b1h[j], acc[i][j], 0, 0, 0);
                    acc[i][j] = __builtin_amdgcn_mfma_f32_16x16x32_bf16(a1h[i], b1l[j], acc[i][j], 0, 0, 0);
                    acc[i][j] = __builtin_amdgcn_mfma_f32_16x16x32_bf16(a1l[i], b1h[j], acc[i][j], 0, 0, 0);
                }
        }
    } else {
        short8 a0h[4], b0h[4], b0l[4];
        short8 a1h[4], b1h[4], b1l[4];
        #pragma unroll
        for (int i = 0; i < 4; ++i) {
            a0h[i] = *(const short8*)(ah_p[i]);
            b0h[i] = *(const short8*)(bh_p[i]);
            b0l[i] = *(const short8*)(bl_p[i]);
        }
        #pragma unroll 1
        for (int kc = 0; kc < 32; kc += 2) {
            {
                const int ko = (kc + 1) * 512;
                #pragma unroll
                for (int i = 0; i < 4; ++i) {
                    a1h[i] = *(const short8*)(ah_p[i] + ko);
                    b1h[i] = *(const short8*)(bh_p[i] + ko);
                    b1l[i] = *(const short8*)(bl_p[i] + ko);
                }
            }
            #pragma unroll
            for (int i = 0; i < 4; ++i)
                #pragma unroll
                for (int j = 0; j < 4; ++j) {
                    acc[i][j] = __builtin_amdgcn_mfma_f32_16x16x32_bf16(a0h[i], b0h[j], acc[i][j], 0, 0, 0);
                    acc[i][j] = __builtin_amdgcn_mfma_f32_16x16x32_bf16(a0h[i], b0l[j], acc[i][j], 0, 0, 0);
                }
            if (kc + 2 < 32) {
                const int ko = (kc + 2) * 512;
                #pragma unroll
                for (int i = 0; i < 4; ++i) {
                    a0h[i] = *(const short8*)(ah_p[i] + ko);
                    b0h[i] = *(const short8*)(bh_p[i] + ko);
                    b0l[i] = *(const short8*)(bl_p[i] + ko);
                }
            }
            #pragma unroll
            for (int i = 0; i < 4; ++i)
                #pragma unroll
                for (int j = 0; j < 4; ++j) {
                    acc[i][j] = __builtin_amdgcn_mfma_f32_16x16x32_bf16(a1h[i], b1h[j], acc[i][j], 0, 0, 0);
                    acc[i][j] = __builtin_amdgcn_mfma_f32_16x16x32_bf16(a1h[i], b1l[j], acc[i][j], 0, 0, 0);
                }
        }
    }

    // epilogue: C layout col = lane&15, row = (lane>>4)*4 + reg
    const int frow = lane & 15, foct = lane >> 4;
    const int ncol = (n0x & 1023) + wn * 64 + frow;
    if (isK) {
        #pragma unroll
        for (int i = 0; i < 4; ++i) {
            #pragma unroll
            for (int r = 0; r < 4; ++r) {
                int row = m0 + wm * 64 + i * 16 + foct * 4 + r;
                if (row < MROWS) {
                    #pragma unroll
                    for (int j = 0; j < 4; ++j) {
                        float v = acc[i][j][r];
                        ushort hv = f2bf(v);
                        ushort lv = f2bf(v - bf2f(hv));
                        khi[(size_t)row * 1024 + ncol + j * 16] = hv;
                        klo[(size_t)row * 1024 + ncol + j * 16] = lv;
                    }
                }
            }
        }
    } else {
        // V: direct V^T fragment-major write (replaces vprep)
        const int hh = ((n0x & 1023) + wn * 64) >> 6;   // head 0..15
        #pragma unroll
        for (int i = 0; i < 4; ++i) {
            #pragma unroll
            for (int r = 0; r < 4; ++r) {
                int row = m0 + wm * 64 + i * 16 + foct * 4 + r;
                if (row < MROWS) {
                    int bb = row / T_;
                    int tt = row - bb * T_;      // key index 0..2048
                    if (tt < 2048) {
                        size_t vb = ((size_t)(bb * 16 + hh) * 65 + (tt >> 5)) * 4;
                        size_t lo_ = (size_t)(((tt >> 3) & 3) * 16 + frow) * 8 + (tt & 7);
                        #pragma unroll
                        for (int j = 0; j < 4; ++j)
                            vfrag[(vb + j) * 512 + lo_] = f2bf(acc[i][j][r]);
                    } else {
                        #pragma unroll
                        for (int j = 0; j < 4; ++j)
                            v2048[bb * 1024 + hh * 64 + j * 16 + frow] = f2bf(acc[i][j][r]);
                    }
                }
            }
        }
    }
}

// ---------------- Kernel 3: 8-wave MFMA flash attention, swapped-QK,
// intra-wave software pipeline (T15): QK^T of tile t interleaves with
// softmax+PV of tile t-1 (independent register streams -> compiler can
// co-schedule MFMA and VALU pipes within one wave). Sync structure is
// EXACTLY R5's (LDS K double-buffer, 1 barrier/tile) — proven correct.
// R6 lesson: only sprev (16 VGPR) carries across tiles; V(t-1) reloaded
// per iteration; launch_bounds(512,3) leaves VGPR headroom (no spill;
// WRITE_SIZE is the spill canary).
__global__ __launch_bounds__(512, 3) void attn_mfma_kernel(
    const float* __restrict__ debug, const float* __restrict__ proj50,
    const ushort* __restrict__ khi, const ushort* __restrict__ klo,
    const ushort* __restrict__ vfrag, const ushort* __restrict__ v2048,
    float* __restrict__ pout, float* __restrict__ pl) {

    __shared__ __align__(16) ushort Ksh[2][16 * 512];    // 32 KB
    __shared__ __align__(16) unsigned Pshh[8][16][20];   // 10 KB
    __shared__ __align__(16) unsigned Pshl[8][16][20];   // 10 KB

    const int t = threadIdx.x, lane = t & 63, w = t >> 6;   // 8 waves
    const int frow = lane & 15, quad = lane >> 4;
    const int h = blockIdx.y, b = blockIdx.z;
    const int qt = blockIdx.x >> 1, slice = blockIdx.x & 1;
    const int qwave = qt * 128 + w * 16;
    const int tstart = slice ? 1088 : 0;
    const int ntiles = slice ? 15 : 17;     // keys [0,1088) / [1088,2048)

    // staging role: wave w stages key-group kg = w>>1, planes s = (w&1)*2+{0,1}
    const int skg = w >> 1, ssb = (w & 1) * 2;

    // Q in exp2 domain: scale = 0.125 * log2(e)
    const float qscale = 0.1803368801111244f;
    short8 qh[2], ql[2];
    {
        int qrow = qwave + frow; if (qrow > Q_ - 1) qrow = Q_ - 1;
        int idx = (qrow * 50) / Q_;
        const float* dsrc = debug + (((size_t)(b * H_ + h)) * Q_ + qrow) * HD;
        const float* psrc = proj50 + (size_t)idx * 1024 + h * HD;
        #pragma unroll
        for (int dc = 0; dc < 2; ++dc) {
            int d0 = dc * 32 + quad * 8;
            union { ushort u[8]; short8 v; } hh, ll;
            #pragma unroll
            for (int j = 0; j < 8; ++j) {
                float v = (dsrc[d0 + j] + psrc[d0 + j]) * qscale;
                ushort hv = f2bf(v);
                hh.u[j] = hv;
                ll.u[j] = f2bf(v - bf2f(hv));
            }
            qh[dc] = hh.v; ql[dc] = ll.v;
        }
    }

    floatx4 oacc[4];    // O^T: oacc[df][r] = O[q=frow][dim=df*16+quad*4+r]
    #pragma unroll
    for (int d = 0; d < 4; ++d) oacc[d] = (floatx4){0.f, 0.f, 0.f, 0.f};
    float lsum = 0.f;

    unsigned* Pwh = &Pshh[w][0][0];
    unsigned* Pwl = &Pshl[w][0][0];
    const size_t bT = (size_t)b * T_;
    const size_t vbh = (size_t)(b * 16 + h) * 65;

    // prologue: stage K tile 0 into Ksh[0]
    {
        int key = tstart + skg * 16 + frow;
        const size_t rowoff = (bT + key) * 1024 + h * 64 + quad * 8;
        #pragma unroll
        for (int j = 0; j < 2; ++j) {
            int s = ssb + j;
            int dc = s >> 1, pl2 = s & 1;
            const ushort* src = (pl2 ? klo : khi) + rowoff + dc * 32;
            gload16(src, &Ksh[0][(skg * 4 + s) * 512]);
        }
    }
    __syncthreads();   // drains vmcnt(0): K[0] landed

    // peeled iteration 0: stage tile 1, QK(tile 0) -> sprev, barrier
    floatx4 sprev[4];
    {
        if (1 < ntiles) {
            int key = tstart + 64 + skg * 16 + frow;
            const size_t rowoff = (bT + key) * 1024 + h * 64 + quad * 8;
            #pragma unroll
            for (int j = 0; j < 2; ++j) {
                int s = ssb + j;
                int dc = s >> 1, pl2 = s & 1;
                const ushort* src = (pl2 ? klo : khi) + rowoff + dc * 32;
                gload16(src, &Ksh[1][(skg * 4 + s) * 512]);
            }
        }
        __builtin_amdgcn_s_setprio(1);
        #pragma unroll
        for (int kg = 0; kg < 4; ++kg) {
            floatx4 s = (floatx4){0.f, 0.f, 0.f, 0.f};
            #pragma unroll
            for (int dc = 0; dc < 2; ++dc) {
                short8 kh = *(const short8*)&Ksh[0][(kg * 4 + dc * 2 + 0) * 512 + lane * 8];
                short8 kl = *(const short8*)&Ksh[0][(kg * 4 + dc * 2 + 1) * 512 + lane * 8];
                s = __builtin_amdgcn_mfma_f32_16x16x32_bf16(kh, qh[dc], s, 0, 0, 0);
                s = __builtin_amdgcn_mfma_f32_16x16x32_bf16(kl, qh[dc], s, 0, 0, 0);
                s = __builtin_amdgcn_mfma_f32_16x16x32_bf16(kh, ql[dc], s, 0, 0, 0);
            }
            sprev[kg] = s;
        }
        __builtin_amdgcn_s_setprio(0);
        __syncthreads();
    }

    // steady state: QK(ti) interleaved with SM+PV(ti-1)
    #pragma unroll 1
    for (int ti = 1; ti < ntiles; ++ti) {
        const int t0 = tstart + ti * 64;
        const int cur = ti & 1;
        const int tp = t0 - 64;   // previous tile base

        // V reg-loads for PREVIOUS tile (consumed by PV below)
        short8 vreg[2][4];
        #pragma unroll
        for (int kc = 0; kc < 2; ++kc) {
            int kcg = (tp >> 5) + kc;
            const ushort* vsrc = vfrag + ((vbh + kcg) * 4) * 512 + lane * 8;
            #pragma unroll
            for (int df = 0; df < 4; ++df)
                vreg[kc][df] = *(const short8*)(vsrc + df * 512);
        }

        // issue NEXT tile's K stage into the other buffer (no wait here)
        if (ti + 1 < ntiles) {
            int key = t0 + 64 + skg * 16 + frow;
            const size_t rowoff = (bT + key) * 1024 + h * 64 + quad * 8;
            #pragma unroll
            for (int j = 0; j < 2; ++j) {
                int s = ssb + j;
                int dc = s >> 1, pl2 = s & 1;
                const ushort* src = (pl2 ? klo : khi) + rowoff + dc * 32;
                gload16(src, &Ksh[cur ^ 1][(skg * 4 + s) * 512]);
            }
        }

        floatx4 scur[4];
        // ---- QK kg0,kg1 (tile ti) ----
        __builtin_amdgcn_s_setprio(1);
        #pragma unroll
        for (int kg = 0; kg < 2; ++kg) {
            floatx4 s = (floatx4){0.f, 0.f, 0.f, 0.f};
            #pragma unroll
            for (int dc = 0; dc < 2; ++dc) {
                short8 kh = *(const short8*)&Ksh[cur][(kg * 4 + dc * 2 + 0) * 512 + lane * 8];
                short8 kl = *(const short8*)&Ksh[cur][(kg * 4 + dc * 2 + 1) * 512 + lane * 8];
                s = __builtin_amdgcn_mfma_f32_16x16x32_bf16(kh, qh[dc], s, 0, 0, 0);
                s = __builtin_amdgcn_mfma_f32_16x16x32_bf16(kl, qh[dc], s, 0, 0, 0);
                s = __builtin_amdgcn_mfma_f32_16x16x32_bf16(kh, ql[dc], s, 0, 0, 0);
            }
            scur[kg] = s;
        }
        __builtin_amdgcn_s_setprio(0);
        // ---- SM+PV kc0 (tile ti-1, from sprev kg0,kg1) ----
        {
            #pragma unroll
            for (int kg2 = 0; kg2 < 2; ++kg2) {
                float p0 = exp2raw(sprev[kg2][0]);
                float p1 = exp2raw(sprev[kg2][1]);
                float p2 = exp2raw(sprev[kg2][2]);
                float p3 = exp2raw(sprev[kg2][3]);
                lsum += (p0 + p1) + (p2 + p3);
                unsigned dh0 = cvtpk(p0, p1);
                float l0 = p0 - __uint_as_float(dh0 << 16);
                float l1 = p1 - __uint_as_float(dh0 & 0xffff0000u);
                unsigned dl0 = cvtpk(l0, l1);
                unsigned dh1 = cvtpk(p2, p3);
                float l2 = p2 - __uint_as_float(dh1 << 16);
                float l3 = p3 - __uint_as_float(dh1 & 0xffff0000u);
                unsigned dl1 = cvtpk(l2, l3);
                int k2 = kg2 * 8 + quad * 2;
                *(uint2v*)&Pwh[frow * 20 + k2] = (uint2v){dh0, dh1};
                *(uint2v*)&Pwl[frow * 20 + k2] = (uint2v){dl0, dl1};
            }
            short8 bh = *(const short8*)&Pwh[frow * 20 + quad * 4];
            short8 bl = *(const short8*)&Pwl[frow * 20 + quad * 4];
            __builtin_amdgcn_s_setprio(1);
            #pragma unroll
            for (int df = 0; df < 4; ++df) {
                oacc[df] = __builtin_amdgcn_mfma_f32_16x16x32_bf16(vreg[0][df], bh, oacc[df], 0, 0, 0);
                oacc[df] = __builtin_amdgcn_mfma_f32_16x16x32_bf16(vreg[0][df], bl, oacc[df], 0, 0, 0);
            }
            __builtin_amdgcn_s_setprio(0);
        }
        // ---- QK kg2,kg3 (tile ti) ----
        __builtin_amdgcn_s_setprio(1);
        #pragma unroll
        for (int kg = 2; kg < 4; ++kg) {
            floatx4 s = (floatx4){0.f, 0.f, 0.f, 0.f};
            #pragma unroll
            for (int dc = 0; dc < 2; ++dc) {
                short8 kh = *(const short8*)&Ksh[cur][(kg * 4 + dc * 2 + 0) * 512 + lane * 8];
                short8 kl = *(const short8*)&Ksh[cur][(kg * 4 + dc * 2 + 1) * 512 + lane * 8];
                s = __builtin_amdgcn_mfma_f32_16x16x32_bf16(kh, qh[dc], s, 0, 0, 0);
                s = __builtin_amdgcn_mfma_f32_16x16x32_bf16(kl, qh[dc], s, 0, 0, 0);
                s = __builtin_amdgcn_mfma_f32_16x16x32_bf16(kh, ql[dc], s, 0, 0, 0);
            }
            scur[kg] = s;
        }
        __builtin_amdgcn_s_setprio(0);
        // ---- SM+PV kc1 (tile ti-1, from sprev kg2,kg3) ----
        {
            #pragma unroll
            for (int kg2 = 0; kg2 < 2; ++kg2) {
                int kg = 2 + kg2;
                float p0 = exp2raw(sprev[kg][0]);
                float p1 = exp2raw(sprev[kg][1]);
                float p2 = exp2raw(sprev[kg][2]);
                float p3 = exp2raw(sprev[kg][3]);
                lsum += (p0 + p1) + (p2 + p3);
                unsigned dh0 = cvtpk(p0, p1);
                float l0 = p0 - __uint_as_float(dh0 << 16);
                float l1 = p1 - __uint_as_float(dh0 & 0xffff0000u);
                unsigned dl0 = cvtpk(l0, l1);
                unsigned dh1 = cvtpk(p2, p3);
                float l2 = p2 - __uint_as_float(dh1 << 16);
                float l3 = p3 - __uint_as_float(dh1 & 0xffff0000u);
                unsigned dl1 = cvtpk(l2, l3);
                int k2 = kg2 * 8 + quad * 2;
                *(uint2v*)&Pwh[frow * 20 + k2] = (uint2v){dh0, dh1};
                *(uint2v*)&Pwl[frow * 20 + k2] = (uint2v){dl0, dl1};
            }
            short8 bh = *(const short8*)&Pwh[frow * 20 + quad * 4];
            short8 bl = *(const short8*)&Pwl[frow * 20 + quad * 4];
            __builtin_amdgcn_s_setprio(1);
            #pragma unroll
            for (int df = 0; df < 4; ++df) {
                oacc[df] = __builtin_amdgcn_mfma_f32_16x16x32_bf16(vreg[1][df], bh, oacc[df], 0, 0, 0);
                oacc[df] = __builtin_amdgcn_mfma_f32_16x16x32_bf16(vreg[1][df], bl, oacc[df], 0, 0, 0);
            }
            __builtin_amdgcn_s_setprio(0);
        }

        #pragma unroll
        for (int kg = 0; kg < 4; ++kg) sprev[kg] = scur[kg];

        __syncthreads();   // drains vmcnt (next K landed); Ksh rotation safe
    }

    // tail: SM+PV for the last tile (ntiles-1) from sprev
    {
        const int tl = tstart + (ntiles - 1) * 64;
        short8 vreg[2][4];
        #pragma unroll
        for (int kc = 0; kc < 2; ++kc) {
            int kcg = (tl >> 5) + kc;
            const ushort* vsrc = vfrag + ((vbh + kcg) * 4) * 512 + lane * 8;
            #pragma unroll
            for (int df = 0; df < 4; ++df)
                vreg[kc][df] = *(const short8*)(vsrc + df * 512);
        }
        #pragma unroll
        for (int kc = 0; kc < 2; ++kc) {
            #pragma unroll
            for (int kg2 = 0; kg2 < 2; ++kg2) {
                int kg = kc * 2 + kg2;
                float p0 = exp2raw(sprev[kg][0]);
                float p1 = exp2raw(sprev[kg][1]);
                float p2 = exp2raw(sprev[kg][2]);
                float p3 = exp2raw(sprev[kg][3]);
                lsum += (p0 + p1) + (p2 + p3);
                unsigned dh0 = cvtpk(p0, p1);
                float l0 = p0 - __uint_as_float(dh0 << 16);
                float l1 = p1 - __uint_as_float(dh0 & 0xffff0000u);
                unsigned dl0 = cvtpk(l0, l1);
                unsigned dh1 = cvtpk(p2, p3);
                float l2 = p2 - __uint_as_float(dh1 << 16);
                float l3 = p3 - __uint_as_float(dh1 & 0xffff0000u);
                unsigned dl1 = cvtpk(l2, l3);
                int k2 = kg2 * 8 + quad * 2;
                *(uint2v*)&Pwh[frow * 20 + k2] = (uint2v){dh0, dh1};
                *(uint2v*)&Pwl[frow * 20 + k2] = (uint2v){dl0, dl1};
            }
            short8 bh = *(const short8*)&Pwh[frow * 20 + quad * 4];
            short8 bl = *(const short8*)&Pwl[frow * 20 + quad * 4];
            #pragma unroll
            for (int df = 0; df < 4; ++df) {
                oacc[df] = __builtin_amdgcn_mfma_f32_16x16x32_bf16(vreg[kc][df], bh, oacc[df], 0, 0, 0);
                oacc[df] = __builtin_amdgcn_mfma_f32_16x16x32_bf16(vreg[kc][df], bl, oacc[df], 0, 0, 0);
            }
        }
    }

    // l[q]: reduce partials over the 4 quads (lane bits 4,5)
    lsum += __shfl_xor(lsum, 16);
    lsum += __shfl_xor(lsum, 32);

    // key 2048 (last row): scalar fp32 path, slice 1 only
    if (slice) {
        const size_t ro = (bT + 2048) * 1024 + (size_t)h * 64 + quad * 8;
        float p = 0.f;
        #pragma unroll
        for (int dc = 0; dc < 2; ++dc) {
            union { short8 v; ushort u[8]; } KH, KL, QH, QL;
            KH.v = *(const short8*)(khi + ro + dc * 32);
            KL.v = *(const short8*)(klo + ro + dc * 32);
            QH.v = qh[dc]; QL.v = ql[dc];
            #pragma unroll
            for (int j = 0; j < 8; ++j) {
                float kf = bf2f(KH.u[j]) + bf2f(KL.u[j]);
                float qf = bf2f(QH.u[j]) + bf2f(QL.u[j]);
                p = fmaf(qf, kf, p);
            }
        }
        p += __shfl_xor(p, 16);
        p += __shfl_xor(p, 32);
        float e = exp2raw(p);
        lsum += e;
        const ushort* vr = v2048 + b * 1024 + h * 64 + quad * 4;
        #pragma unroll
        for (int df = 0; df < 4; ++df)
            #pragma unroll
            for (int r = 0; r < 4; ++r)
                oacc[df][r] = fmaf(e, bf2f(vr[df * 16 + r]), oacc[df][r]);
    }

    // epilogue: O^T -> contiguous float4 stores; q = frow
    int q = qwave + frow;
    if (q < Q_) {
        float* dst = pout + (((size_t)(slice * B_ + b)) * Q_ + q) * E_ + h * HD + quad * 4;
        #pragma unroll
        for (int df = 0; df < 4; ++df) {
            float4 o4;
            o4.x = oacc[df][0]; o4.y = oacc[df][1];
            o4.z = oacc[df][2]; o4.w = oacc[df][3];
            *(float4*)(dst + df * 16) = o4;
        }
        if (quad == 0)
            pl[(((size_t)(slice * B_ + b)) * H_ + h) * Q_ + q] = lsum;
    }
}

// ---------------- combine: out = gates * (O0+O1) / (l0+l1) -----------------
__global__ __launch_bounds__(256) void combine_kernel(
    const float* __restrict__ pout, const float* __restrict__ pl,
    const float* __restrict__ gates, float* __restrict__ out) {
    const int q = blockIdx.x, b = blockIdx.y, t = threadIdx.x;
    const int e0 = t * 4, h = e0 >> 6;
    const size_t r0 = ((size_t)b * Q_ + q) * E_ + e0;
    const size_t r1 = ((size_t)(B_ + b) * Q_ + q) * E_ + e0;
    float4 a = *(const float4*)(pout + r0);
    float4 c = *(const float4*)(pout + r1);
    float l = pl[((size_t)b * H_ + h) * Q_ + q]
            + pl[((size_t)(B_ + b) * H_ + h) * Q_ + q];
    float s = gates[0] / l;
    float4 o;
    o.x = (a.x + c.x) * s;
    o.y = (a.y + c.y) * s;
    o.z = (a.z + c.z) * s;
    o.w = (a.w + c.w) * s;
    *(float4*)(out + ((size_t)b * Q_ + q) * E_ + e0) = o;
}

// ---------------- Fallback fp32 path (if workspace too small) --------------
#define SMK 36
__global__ __launch_bounds__(256) void kv_gemm_kernel(
    const float* __restrict__ x_b, const float* __restrict__ pe,
    const float* __restrict__ prompt,
    const float* __restrict__ Wk, const float* __restrict__ Wv,
    float* __restrict__ kout, float* __restrict__ vout) {

    __shared__ float As[64][SMK];
    __shared__ float Bks[64][SMK];
    __shared__ float Bvs[64][SMK];

    const int t = threadIdx.x;
    const int m0 = blockIdx.y * 64;
    const int n0 = blockIdx.x * 64;
    const int tx = t & 15, ty = t >> 4;
    const int rr = t >> 2;
    const int kp = (t & 3) * 8;

    int m = m0 + rr;
    if (m >= MROWS) m = 0;
    const int bb = m / T_;
    const int tt = m - bb * T_;
    const float* aptr; const float* peptr; float pesc;
    if (tt == 0) { aptr = prompt; peptr = pe; pesc = 0.f; }
    else {
        aptr = x_b + ((size_t)bb * TB + (tt - 1)) * 1024;
        peptr = pe + (size_t)(tt - 1) * 1024;
        pesc = 1.f;
    }
    const float* wkp = Wk + (size_t)(n0 + rr) * 1024;
    const float* wvp = Wv + (size_t)(n0 + rr) * 1024;

    float ck[4][4] = {{0.f}}, cv[4][4] = {{0.f}};

    for (int k0 = 0; k0 < 1024; k0 += 32) {
        __syncthreads();
        {
            float4 xa0 = *(const float4*)(aptr + k0 + kp);
            float4 xa1 = *(const float4*)(aptr + k0 + kp + 4);
            float4 pe0 = *(const float4*)(peptr + k0 + kp);
            float4 pe1 = *(const float4*)(peptr + k0 + kp + 4);
            xa0.x = fmaf(pesc, pe0.x, xa0.x);
            xa0.y = fmaf(pesc, pe0.y, xa0.y);
            xa0.z = fmaf(pesc, pe0.z, xa0.z);
            xa0.w = fmaf(pesc, pe0.w, xa0.w);
            xa1.x = fmaf(pesc, pe1.x, xa1.x);
            xa1.y = fmaf(pesc, pe1.y, xa1.y);
            xa1.z = fmaf(pesc, pe1.z, xa1.z);
            xa1.w = fmaf(pesc, pe1.w, xa1.w);
            *(float4*)&As[rr][kp]     = xa0;
            *(float4*)&As[rr][kp + 4] = xa1;
            *(float4*)&Bks[rr][kp]     = *(const float4*)(wkp + k0 + kp);
            *(float4*)&Bks[rr][kp + 4] = *(const float4*)(wkp + k0 + kp + 4);
            *(float4*)&Bvs[rr][kp]     = *(const float4*)(wvp + k0 + kp);
            *(float4*)&Bvs[rr][kp + 4] = *(const float4*)(wvp + k0 + kp + 4);
        }
        __syncthreads();
        for (int k4 = 0; k4 < 8; ++k4) {
            float4 a[4], bk[4], bv[4];
            #pragma unroll
            for (int i = 0; i < 4; ++i) a[i] = *(const float4*)&As[ty * 4 + i][k4 * 4];
            #pragma unroll
            for (int j = 0; j < 4; ++j) {
                bk[j] = *(const float4*)&Bks[tx * 4 + j][k4 * 4];
                bv[j] = *(const float4*)&Bvs[tx * 4 + j][k4 * 4];
            }
            #pragma unroll
            for (int i = 0; i < 4; ++i)
                #pragma unroll
                for (int j = 0; j < 4; ++j) {
                    ck[i][j] = fmaf(a[i].x, bk[j].x, ck[i][j]);
                    ck[i][j] = fmaf(a[i].y, bk[j].y, ck[i][j]);
                    ck[i][j] = fmaf(a[i].z, bk[j].z, ck[i][j]);
                    ck[i][j] = fmaf(a[i].w, bk[j].w, ck[i][j]);
                    cv[i][j] = fmaf(a[i].x, bv[j].x, cv[i][j]);
                    cv[i][j] = fmaf(a[i].y, bv[j].y, cv[i][j]);
                    cv[i][j] = fmaf(a[i].z, bv[j].z, cv[i][j]);
                    cv[i][j] = fmaf(a[i].w, bv[j].w, cv[i][j]);
                }
        }
    }

    #pragma unroll
    for (int i = 0; i < 4; ++i) {
        int mrow = m0 + ty * 4 + i;
        if (mrow < MROWS) {
            float4 kq, vq;
            kq.x = ck[i][0]; kq.y = ck[i][1]; kq.z = ck[i][2]; kq.w = ck[i][3];
            vq.x = cv[i][0]; vq.y = cv[i][1]; vq.z = cv[i][2]; vq.w = cv[i][3];
            *(float4*)(kout + (size_t)mrow * 1024 + n0 + tx * 4) = kq;
            *(float4*)(vout + (size_t)mrow * 1024 + n0 + tx * 4) = vq;
        }
    }
}

#define KSTR 68
__device__ __forceinline__ float dot16(const float (&q)[16], const float* kf) {
    float4 k0 = *(const float4*)(kf);
    float4 k1 = *(const float4*)(kf + 4);
    float4 k2 = *(const float4*)(kf + 8);
    float4 k3 = *(const float4*)(kf + 12);
    float p;
    p = q[0] * k0.x;
    p = fmaf(q[1], k0.y, p);  p = fmaf(q[2], k0.z, p);  p = fmaf(q[3], k0.w, p);
    p = fmaf(q[4], k1.x, p);  p = fmaf(q[5], k1.y, p);  p = fmaf(q[6], k1.z, p);  p = fmaf(q[7], k1.w, p);
    p = fmaf(q[8], k2.x, p);  p = fmaf(q[9], k2.y, p);  p = fmaf(q[10], k2.z, p); p = fmaf(q[11], k2.w, p);
    p = fmaf(q[12], k3.x, p); p = fmaf(q[13], k3.y, p); p = fmaf(q[14], k3.z, p); p = fmaf(q[15], k3.w, p);
    return p;
}
__device__ __forceinline__ void pv16(float (&o)[16], float pk, const float* vf) {
    float4 v0 = *(const float4*)(vf);
    float4 v1 = *(const float4*)(vf + 4);
    float4 v2 = *(const float4*)(vf + 8);
    float4 v3 = *(const float4*)(vf + 12);
    o[0]  = fmaf(pk, v0.x, o[0]);  o[1]  = fmaf(pk, v0.y, o[1]);
    o[2]  = fmaf(pk, v0.z, o[2]);  o[3]  = fmaf(pk, v0.w, o[3]);
    o[4]  = fmaf(pk, v1.x, o[4]);  o[5]  = fmaf(pk, v1.y, o[5]);
    o[6]  = fmaf(pk, v1.z, o[6]);  o[7]  = fmaf(pk, v1.w, o[7]);
    o[8]  = fmaf(pk, v2.x, o[8]);  o[9]  = fmaf(pk, v2.y, o[9]);
    o[10] = fmaf(pk, v2.z, o[10]); o[11] = fmaf(pk, v2.w, o[11]);
    o[12] = fmaf(pk, v3.x, o[12]); o[13] = fmaf(pk, v3.y, o[13]);
    o[14] = fmaf(pk, v3.z, o[14]); o[15] = fmaf(pk, v3.w, o[15]);
}

__global__ __launch_bounds__(256) void attn_kernel(
    const float* __restrict__ debug, const float* __restrict__ proj50,
    const float* __restrict__ kmat, const float* __restrict__ vmat,
    const float* __restrict__ gates, float* __restrict__ out) {

    __shared__ float k_s[64][KSTR];
    __shared__ float v_s[64][KSTR];

    const int t = threadIdx.x;
    const int lane = t & 63;
    const int w = t >> 6;
    const int r = lane >> 2;
    const int g = lane & 3;
    const int qi = blockIdx.x * 64 + w * 16 + r;
    const int h = blockIdx.y, b = blockIdx.z;
    const bool valid = qi < Q_;

    float q[16], o[16];
    {
        int qq = valid ? qi : 0;
        int idx = (qq * 50) / Q_;
        const float* dsrc = debug + (((size_t)(b * H_ + h)) * Q_ + qq) * HD + g * 16;
        const float* psrc = proj50 + (size_t)idx * 1024 + h * HD + g * 16;
        #pragma unroll
        for (int j4 = 0; j4 < 4; ++j4) {
            float4 dv = *(const float4*)(dsrc + j4 * 4);
            float4 pv = *(const float4*)(psrc + j4 * 4);
            q[j4 * 4 + 0] = (dv.x + pv.x) * 0.125f;
            q[j4 * 4 + 1] = (dv.y + pv.y) * 0.125f;
            q[j4 * 4 + 2] = (dv.z + pv.z) * 0.125f;
            q[j4 * 4 + 3] = (dv.w + pv.w) * 0.125f;
        }
    }
    float mrun = -INFINITY, lrun = 0.f;
    #pragma unroll
    for (int j = 0; j < 16; ++j) o[j] = 0.f;

    const int srow = t >> 2;
    const int scol = (t & 3) * 16;
    const float* kbase = kmat + ((size_t)b * T_) * E_ + h * HD + scol;
    const float* vbase = vmat + ((size_t)b * T_) * E_ + h * HD + scol;

    for (int t0 = 0; t0 < 2048; t0 += 64) {
        __syncthreads();
        {
            const float* kr = kbase + (size_t)(t0 + srow) * E_;
            const float* vr = vbase + (size_t)(t0 + srow) * E_;
            #pragma unroll
            for (int j4 = 0; j4 < 4; ++j4) {
                *(float4*)&k_s[srow][scol + j4 * 4] = *(const float4*)(kr + j4 * 4);
                *(float4*)&v_s[srow][scol + j4 * 4] = *(const float4*)(vr + j4 * 4);
            }
        }
        __syncthreads();
        #pragma unroll 1
        for (int kb = 0; kb < 64; kb += 16) {
            float sc[16];
            #pragma unroll
            for (int kk = 0; kk < 16; ++kk) {
                float p = dot16(q, &k_s[kb + kk][g * 16]);
                p += __shfl_xor(p, 1);
                p += __shfl_xor(p, 2);
                sc[kk] = p;
            }
            float mt = sc[0];
            #pragma unroll
            for (int kk = 1; kk < 16; ++kk) mt = fmaxf(mt, sc[kk]);
            float mn = fmaxf(mrun, mt);
            float al = __expf(mrun - mn);
            float ssum = 0.f;
            #pragma unroll
            for (int kk = 0; kk < 16; ++kk) { sc[kk] = __expf(sc[kk] - mn); ssum += sc[kk]; }
            mrun = mn;
            lrun = fmaf(lrun, al, ssum);
            #pragma unroll
            for (int j = 0; j < 16; ++j) o[j] *= al;
            #pragma unroll
            for (int kk = 0; kk < 16; ++kk) pv16(o, sc[kk], &v_s[kb + kk][g * 16]);
        }
    }
    {
        const float* kr = kmat + ((size_t)(b * T_ + 2048)) * E_ + h * HD + g * 16;
        const float* vr = vmat + ((size_t)(b * T_ + 2048)) * E_ + h * HD + g * 16;
        float p = dot16(q, kr);
        p += __shfl_xor(p, 1);
        p += __shfl_xor(p, 2);
        float mn = fmaxf(mrun, p);
        float al = __expf(mrun - mn);
        float pk = __expf(p - mn);
        lrun = fmaf(lrun, al, pk);
        #pragma unroll
        for (int j = 0; j < 16; ++j) o[j] *= al;
        pv16(o, pk, vr);
    }

    if (valid) {
        float s = gates[0] / lrun;
        float* dst = out + ((size_t)b * Q_ + qi) * E_ + h * HD + g * 16;
        #pragma unroll
        for (int j4 = 0; j4 < 4; ++j4) {
            float4 ov;
            ov.x = o[j4 * 4 + 0] * s;
            ov.y = o[j4 * 4 + 1] * s;
            ov.z = o[j4 * 4 + 2] * s;
            ov.w = o[j4 * 4 + 3] * s;
            *(float4*)(dst + j4 * 4) = ov;
        }
    }
}

extern "C" void kernel_launch(void* const* d_in, const int* in_sizes, int n_in,
                              void* d_out, int out_size, void* d_ws, size_t ws_size,
                              hipStream_t stream) {
    // inputs: x_a(0), x_b(1), debug(2), Wk(3), Wv(4), Wpos(5),
    //         prompt(6), gates(7), pe(8), full_b_step(9), full_a_step(10)
    const float* x_b = (const float*)d_in[1];
    const float* debug = (const float*)d_in[2];
    const float* Wk = (const float*)d_in[3];
    const float* Wv = (const float*)d_in[4];
    const float* Wpos = (const float*)d_in[5];
    const float* prompt = (const float*)d_in[6];
    const float* gates = (const float*)d_in[7];
    const float* pe = (const float*)d_in[8];
    float* out = (float*)d_out;

    char* ws = (char*)d_ws;
    const size_t KVH = (size_t)MROWS * 1024 * sizeof(ushort);      // 16,785,408
    const size_t KVF = (size_t)MROWS * 1024 * sizeof(float);       // 33,570,816
    const size_t AF  = (size_t)MT_TILES * 32 * 64 * 8 * sizeof(ushort);  // 16,809,984
    const size_t WF  = (size_t)128 * 32 * 64 * 8 * sizeof(ushort);       //  4,194,304
    const size_t P50 = 256 * 1024;

    float*  proj50 = (float*)ws;                   // 200 KB used of 256 KB
    ushort* v2048u = (ushort*)(ws + 240 * 1024);   // 8 KB spare in P50 slab
    ushort* khi  = (ushort*)(ws + P50);
    ushort* klo  = (ushort*)(ws + P50 + KVH);
    float*  vbuf = (float*)(ws + P50 + 2 * KVH);   // fp32 region (fallback)
    ushort* afhi = (ushort*)(ws + P50 + 2 * KVH + KVF);
    ushort* aflo = (ushort*)(ws + P50 + 2 * KVH + KVF + AF);
    ushort* wfhi = (ushort*)(ws + P50 + 2 * KVH + KVF + 2 * AF);
    ushort* wflo = (ushort*)(ws + P50 + 2 * KVH + KVF + 2 * AF + WF);
    // main path aliasing:
    //  vfrag (17.04 MB) lives in the vbuf region (33.57 MB) — written by
    //    kv_mfma, read by attn (vbuf is fallback-only otherwise)
    //  pout (26.25 MB) + pl (0.41 MB) live in afhi+aflo (33.62 MB), dead
    //    after kv_mfma — attn writes them, combine reads them
    ushort* vfrag = (ushort*)vbuf;
    float* pout = (float*)afhi;
    float* plse = pout + (size_t)2 * B_ * Q_ * E_;
    const size_t needed = P50 + 2 * KVH + KVF + 2 * AF + 2 * WF;  // 109,412,352

    proj50_kernel<<<dim3(50, 4), 256, 0, stream>>>(pe, Wpos, proj50);

    if (ws_size >= needed) {
        split_kv_kernel<<<dim3(MT_TILES), 256, 0, stream>>>(x_b, pe, prompt, afhi, aflo);
        split_w_kernel<<<dim3(128), 256, 0, stream>>>(Wk, Wv, wfhi, wflo);
        kv_mfma_kernel<<<dim3(1040), 256, 0, stream>>>(afhi, aflo, wfhi, wflo,
                                                       khi, klo, vfrag, v2048u);
        attn_mfma_kernel<<<dim3(14, H_, B_), 512, 0, stream>>>(
            debug, proj50, khi, klo, vfrag, v2048u, pout, plse);
        combine_kernel<<<dim3(Q_, B_), 256, 0, stream>>>(pout, plse, gates, out);
    } else {
        float* kbuf = (float*)khi;   // fallback: fp32 K in khi+klo region (same size)
        kv_gemm_kernel<<<dim3(16, 129), 256, 0, stream>>>(x_b, pe, prompt, Wk, Wv, kbuf, vbuf);
        attn_kernel<<<dim3(13, H_, B_), 256, 0, stream>>>(debug, proj50, kbuf, vbuf, gates, out);
    }
}

// Round 8
// 356.105 us; speedup vs baseline: 1.4553x; 1.1098x over previous
//
#include <hip/hip_runtime.h>
#include <hip/hip_bf16.h>
#include <math.h>

#define B_ 4
#define T_ 2049      // keys = prompt + 2048
#define TB 2048
#define Q_ 801
#define H_ 16
#define HD 64
#define E_ 1024
#define MROWS (B_ * T_)   // 8196
#define MT_TILES 513      // ceil(8196/16)

typedef short short8 __attribute__((ext_vector_type(8)));
typedef float floatx4 __attribute__((ext_vector_type(4)));
typedef int int4v __attribute__((ext_vector_type(4)));
typedef unsigned uint2v __attribute__((ext_vector_type(2)));

__device__ __forceinline__ ushort f2bf(float x) {
    unsigned u = __float_as_uint(x);
    unsigned r = (u + 0x7fffu + ((u >> 16) & 1u)) >> 16;
    return (ushort)r;
}
__device__ __forceinline__ float bf2f(ushort h) {
    return __uint_as_float(((unsigned)h) << 16);
}
__device__ __forceinline__ void gload16(const void* g, void* l) {
    __builtin_amdgcn_global_load_lds(
        (const __attribute__((address_space(1))) void*)g,
        (__attribute__((address_space(3))) void*)l, 16, 0, 0);
}
// raw v_exp_f32: computes 2^x (hardware exp2)
__device__ __forceinline__ float exp2raw(float x) {
    float r;
    asm("v_exp_f32 %0, %1" : "=v"(r) : "v"(x));
    return r;
}
// v_cvt_pk_bf16_f32: low16 = bf16(a), high16 = bf16(b)
__device__ __forceinline__ unsigned cvtpk(float a, float b) {
    unsigned r;
    asm("v_cvt_pk_bf16_f32 %0, %1, %2" : "=v"(r) : "v"(a), "v"(b));
    return r;
}

// ---------------- Kernel 1: proj50[r,c] = sum_i pe[r,i] * Wpos[c,i] --------
__global__ __launch_bounds__(256) void proj50_kernel(
    const float* __restrict__ pe, const float* __restrict__ Wpos,
    float* __restrict__ proj50) {
    __shared__ float pes[1024];
    const int r = blockIdx.x;        // 0..49
    const int t = threadIdx.x;       // 256
    for (int p = 0; p < 4; ++p) pes[t + p * 256] = pe[(size_t)r * 1024 + t + p * 256];
    __syncthreads();
    const int c = blockIdx.y * 256 + t;
    const float4* w4 = (const float4*)(Wpos + (size_t)c * 1024);
    float acc = 0.f;
    for (int i = 0; i < 256; ++i) {
        float4 wv = w4[i];
        acc = fmaf(pes[4 * i + 0], wv.x, acc);
        acc = fmaf(pes[4 * i + 1], wv.y, acc);
        acc = fmaf(pes[4 * i + 2], wv.z, acc);
        acc = fmaf(pes[4 * i + 3], wv.w, acc);
    }
    proj50[(size_t)r * 1024 + c] = acc;
}

// ---------------- split_all: kv rows AND [Wk;Wv] rows -> frag-major hi/lo --
// Merged split_kv (blocks 0..512) + split_w (blocks 513..640): one dispatch.
__global__ __launch_bounds__(256) void split_all_kernel(
    const float* __restrict__ x_b, const float* __restrict__ pe,
    const float* __restrict__ prompt,
    const float* __restrict__ Wk, const float* __restrict__ Wv,
    ushort* __restrict__ afhi, ushort* __restrict__ aflo,
    ushort* __restrict__ wfhi, ushort* __restrict__ wflo) {
    const int bid = blockIdx.x;
    const int t = threadIdx.x;
    const int lane = t & 63, kq = t >> 6;
    const int row_in = lane & 15, quad = lane >> 4;
    if (bid < MT_TILES) {
        const int mt = bid;
        int m = mt * 16 + row_in; if (m > MROWS - 1) m = MROWS - 1;
        const int b = m / T_, tt = m - b * T_;
        const float* src; const float* pesrc; float psc;
        if (tt == 0) { src = prompt; pesrc = pe; psc = 0.f; }
        else {
            src = x_b + ((size_t)b * TB + tt - 1) * 1024;
            pesrc = pe + (size_t)(tt - 1) * 1024;
            psc = 1.f;
        }
        #pragma unroll
        for (int rep = 0; rep < 8; ++rep) {
            int kc = rep * 4 + kq;
            int k0 = kc * 32 + quad * 8;
            float4 xa = *(const float4*)(src + k0);
            float4 xb2 = *(const float4*)(src + k0 + 4);
            float4 pa = *(const float4*)(pesrc + k0);
            float4 pb = *(const float4*)(pesrc + k0 + 4);
            float vv[8];
            vv[0] = fmaf(psc, pa.x, xa.x);  vv[1] = fmaf(psc, pa.y, xa.y);
            vv[2] = fmaf(psc, pa.z, xa.z);  vv[3] = fmaf(psc, pa.w, xa.w);
            vv[4] = fmaf(psc, pb.x, xb2.x); vv[5] = fmaf(psc, pb.y, xb2.y);
            vv[6] = fmaf(psc, pb.z, xb2.z); vv[7] = fmaf(psc, pb.w, xb2.w);
            union { ushort u[8]; short8 s; } hu, lu;
            #pragma unroll
            for (int j = 0; j < 8; ++j) {
                ushort h = f2bf(vv[j]);
                hu.u[j] = h;
                lu.u[j] = f2bf(vv[j] - bf2f(h));
            }
            size_t off = ((size_t)(mt * 32 + kc) * 64 + lane) * 8;
            *(short8*)(afhi + off) = hu.s;
            *(short8*)(aflo + off) = lu.s;
        }
    } else {
        const int nt = bid - MT_TILES;        // 0..127
        const int n = nt * 16 + row_in;       // 0..2047
        const float* src = (n < 1024) ? Wk + (size_t)n * 1024
                                      : Wv + (size_t)(n - 1024) * 1024;
        #pragma unroll
        for (int rep = 0; rep < 8; ++rep) {
            int kc = rep * 4 + kq;
            int k0 = kc * 32 + quad * 8;
            float4 xa = *(const float4*)(src + k0);
            float4 xb2 = *(const float4*)(src + k0 + 4);
            float vv[8] = {xa.x, xa.y, xa.z, xa.w, xb2.x, xb2.y, xb2.z, xb2.w};
            union { ushort u[8]; short8 s; } hu, lu;
            #pragma unroll
            for (int j = 0; j < 8; ++j) {
                ushort h = f2bf(vv[j]);
                hu.u[j] = h;
                lu.u[j] = f2bf(vv[j] - bf2f(h));
            }
            size_t off = ((size_t)(nt * 32 + kc) * 64 + lane) * 8;
            *(short8*)(wfhi + off) = hu.s;
            *(short8*)(wflo + off) = lu.s;
        }
    }
}

// ---------------- Kernel 2: barrier-free MFMA K/V GEMM, XCD-localized ------
__global__ __launch_bounds__(256) void kv_mfma_kernel(
    const ushort* __restrict__ afhi, const ushort* __restrict__ aflo,
    const ushort* __restrict__ wfhi, const ushort* __restrict__ wflo,
    ushort* __restrict__ khi, ushort* __restrict__ klo,
    ushort* __restrict__ vfrag, ushort* __restrict__ v2048) {

    const int t = threadIdx.x, lane = t & 63, w = t >> 6;
    const int wm = w >> 1, wn = w & 1;
    const int bid = blockIdx.x;
    const int c = bid & 7, jj2 = bid >> 3;
    int xx, yy;
    if (jj2 < 128) { yy = ((jj2 >> 4) << 3) + c; xx = jj2 & 15; }
    else           { yy = 64; xx = c * 2 + (jj2 - 128); }
    const int m0 = yy * 128, n0x = xx * 128;
    const bool isK = (xx < 8);
    const size_t lb = (size_t)lane * 8;

    const ushort* ah_p[4]; const ushort* al_p[4];
    const ushort* bh_p[4]; const ushort* bl_p[4];
    #pragma unroll
    for (int i = 0; i < 4; ++i) {
        size_t mt = (size_t)(yy * 8 + wm * 4 + i);
        ah_p[i] = afhi + mt * 16384 + lb;
        al_p[i] = aflo + mt * 16384 + lb;
        size_t nt = (size_t)(xx * 8 + wn * 4 + i);
        bh_p[i] = wfhi + nt * 16384 + lb;
        bl_p[i] = wflo + nt * 16384 + lb;
    }

    floatx4 acc[4][4];
    #pragma unroll
    for (int i = 0; i < 4; ++i)
        #pragma unroll
        for (int j = 0; j < 4; ++j)
            acc[i][j] = (floatx4){0.f, 0.f, 0.f, 0.f};

    if (isK) {
        short8 a0h[4], a0l[4], b0h[4], b0l[4];
        short8 a1h[4], a1l[4], b1h[4], b1l[4];
        #pragma unroll
        for (int i = 0; i < 4; ++i) {
            a0h[i] = *(const short8*)(ah_p[i]);
            a0l[i] = *(const short8*)(al_p[i]);
            b0h[i] = *(const short8*)(bh_p[i]);
            b0l[i] = *(const short8*)(bl_p[i]);
        }
        #pragma unroll 1
        for (int kc = 0; kc < 32; kc += 2) {
            {
                const int ko = (kc + 1) * 512;
                #pragma unroll
                for (int i = 0; i < 4; ++i) {
                    a1h[i] = *(const short8*)(ah_p[i] + ko);
                    a1l[i] = *(const short8*)(al_p[i] + ko);
                    b1h[i] = *(const short8*)(bh_p[i] + ko);
                    b1l[i] = *(const short8*)(bl_p[i] + ko);
                }
            }
            #pragma unroll
            for (int i = 0; i < 4; ++i)
                #pragma unroll
                for (int j = 0; j < 4; ++j) {
                    acc[i][j] = __builtin_amdgcn_mfma_f32_16x16x32_bf16(a0h[i], b0h[j], acc[i][j], 0, 0, 0);
                    acc[i][j] = __builtin_amdgcn_mfma_f32_16x16x32_bf16(a0h[i], b0l[j], acc[i][j], 0, 0, 0);
                    acc[i][j] = __builtin_amdgcn_mfma_f32_16x16x32_bf16(a0l[i], b0h[j], acc[i][j], 0, 0, 0);
                }
            if (kc + 2 < 32) {
                const int ko = (kc + 2) * 512;
                #pragma unroll
                for (int i = 0; i < 4; ++i) {
                    a0h[i] = *(const short8*)(ah_p[i] + ko);
                    a0l[i] = *(const short8*)(al_p[i] + ko);
                    b0h[i] = *(const short8*)(bh_p[i] + ko);
                    b0l[i] = *(const short8*)(bl_p[i] + ko);
                }
            }
            #pragma unroll
            for (int i = 0; i < 4; ++i)
                #pragma unroll
                for (int j = 0; j < 4; ++j) {
                    acc[i][j] = __builtin_amdgcn_mfma_f32_16x16x32_bf16(a1h[i], b1h[j], acc[i][j], 0, 0, 0);
                    acc[i][j] = __builtin_amdgcn_mfma_f32_16x16x32_bf16(a1h[i], b1l[j], acc[i][j], 0, 0, 0);
                    acc[i][j] = __builtin_amdgcn_mfma_f32_16x16x32_bf16(a1l[i], b1h[j], acc[i][j], 0, 0, 0);
                }
        }
    } else {
        short8 a0h[4], b0h[4], b0l[4];
        short8 a1h[4], b1h[4], b1l[4];
        #pragma unroll
        for (int i = 0; i < 4; ++i) {
            a0h[i] = *(const short8*)(ah_p[i]);
            b0h[i] = *(const short8*)(bh_p[i]);
            b0l[i] = *(const short8*)(bl_p[i]);
        }
        #pragma unroll 1
        for (int kc = 0; kc < 32; kc += 2) {
            {
                const int ko = (kc + 1) * 512;
                #pragma unroll
                for (int i = 0; i < 4; ++i) {
                    a1h[i] = *(const short8*)(ah_p[i] + ko);
                    b1h[i] = *(const short8*)(bh_p[i] + ko);
                    b1l[i] = *(const short8*)(bl_p[i] + ko);
                }
            }
            #pragma unroll
            for (int i = 0; i < 4; ++i)
                #pragma unroll
                for (int j = 0; j < 4; ++j) {
                    acc[i][j] = __builtin_amdgcn_mfma_f32_16x16x32_bf16(a0h[i], b0h[j], acc[i][j], 0, 0, 0);
                    acc[i][j] = __builtin_amdgcn_mfma_f32_16x16x32_bf16(a0h[i], b0l[j], acc[i][j], 0, 0, 0);
                }
            if (kc + 2 < 32) {
                const int ko = (kc + 2) * 512;
                #pragma unroll
                for (int i = 0; i < 4; ++i) {
                    a0h[i] = *(const short8*)(ah_p[i] + ko);
                    b0h[i] = *(const short8*)(bh_p[i] + ko);
                    b0l[i] = *(const short8*)(bl_p[i] + ko);
                }
            }
            #pragma unroll
            for (int i = 0; i < 4; ++i)
                #pragma unroll
                for (int j = 0; j < 4; ++j) {
                    acc[i][j] = __builtin_amdgcn_mfma_f32_16x16x32_bf16(a1h[i], b1h[j], acc[i][j], 0, 0, 0);
                    acc[i][j] = __builtin_amdgcn_mfma_f32_16x16x32_bf16(a1h[i], b1l[j], acc[i][j], 0, 0, 0);
                }
        }
    }

    // epilogue: C layout col = lane&15, row = (lane>>4)*4 + reg
    const int frow = lane & 15, foct = lane >> 4;
    const int ncol = (n0x & 1023) + wn * 64 + frow;
    if (isK) {
        #pragma unroll
        for (int i = 0; i < 4; ++i) {
            #pragma unroll
            for (int r = 0; r < 4; ++r) {
                int row = m0 + wm * 64 + i * 16 + foct * 4 + r;
                if (row < MROWS) {
                    #pragma unroll
                    for (int j = 0; j < 4; ++j) {
                        float v = acc[i][j][r];
                        ushort hv = f2bf(v);
                        ushort lv = f2bf(v - bf2f(hv));
                        khi[(size_t)row * 1024 + ncol + j * 16] = hv;
                        klo[(size_t)row * 1024 + ncol + j * 16] = lv;
                    }
                }
            }
        }
    } else {
        // V: direct V^T fragment-major write (replaces vprep)
        const int hh = ((n0x & 1023) + wn * 64) >> 6;   // head 0..15
        #pragma unroll
        for (int i = 0; i < 4; ++i) {
            #pragma unroll
            for (int r = 0; r < 4; ++r) {
                int row = m0 + wm * 64 + i * 16 + foct * 4 + r;
                if (row < MROWS) {
                    int bb = row / T_;
                    int tt = row - bb * T_;      // key index 0..2048
                    if (tt < 2048) {
                        size_t vb = ((size_t)(bb * 16 + hh) * 65 + (tt >> 5)) * 4;
                        size_t lo_ = (size_t)(((tt >> 3) & 3) * 16 + frow) * 8 + (tt & 7);
                        #pragma unroll
                        for (int j = 0; j < 4; ++j)
                            vfrag[(vb + j) * 512 + lo_] = f2bf(acc[i][j][r]);
                    } else {
                        #pragma unroll
                        for (int j = 0; j < 4; ++j)
                            v2048[bb * 1024 + hh * 64 + j * 16 + frow] = f2bf(acc[i][j][r]);
                    }
                }
            }
        }
    }
}

// ---------------- Kernel 3: 8-wave MFMA flash attention, swapped-QK --------
// EXACT R5 loop structure (best measured: 112 us) — locked per R6/R7
// pre-commits (occupancy x2 / barrier-free / intra-wave SWP all failed).
// Changes vs R5: split-K removed (one block does all 32 tiles + key-2048
// tail) and the gated, normalized output is written DIRECTLY to `out` —
// combine kernel + 65 MB of fp32 partial round-trip deleted.
__global__ __launch_bounds__(512, 4) void attn_mfma_kernel(
    const float* __restrict__ debug, const float* __restrict__ proj50,
    const ushort* __restrict__ khi, const ushort* __restrict__ klo,
    const ushort* __restrict__ vfrag, const ushort* __restrict__ v2048,
    const float* __restrict__ gates, float* __restrict__ out) {

    __shared__ __align__(16) ushort Ksh[2][16 * 512];    // 32 KB
    __shared__ __align__(16) unsigned Pshh[8][16][20];   // 10 KB
    __shared__ __align__(16) unsigned Pshl[8][16][20];   // 10 KB

    const int t = threadIdx.x, lane = t & 63, w = t >> 6;   // 8 waves
    const int frow = lane & 15, quad = lane >> 4;
    const int h = blockIdx.y, b = blockIdx.z;
    const int qt = blockIdx.x;              // 0..6
    const int qwave = qt * 128 + w * 16;
    const int ntiles = 32;                  // keys [0, 2048)

    // staging role: wave w stages key-group kg = w>>1, planes s = (w&1)*2+{0,1}
    const int skg = w >> 1, ssb = (w & 1) * 2;

    // Q in exp2 domain: scale = 0.125 * log2(e)
    const float qscale = 0.1803368801111244f;
    short8 qh[2], ql[2];
    {
        int qrow = qwave + frow; if (qrow > Q_ - 1) qrow = Q_ - 1;
        int idx = (qrow * 50) / Q_;
        const float* dsrc = debug + (((size_t)(b * H_ + h)) * Q_ + qrow) * HD;
        const float* psrc = proj50 + (size_t)idx * 1024 + h * HD;
        #pragma unroll
        for (int dc = 0; dc < 2; ++dc) {
            int d0 = dc * 32 + quad * 8;
            union { ushort u[8]; short8 v; } hh, ll;
            #pragma unroll
            for (int j = 0; j < 8; ++j) {
                float v = (dsrc[d0 + j] + psrc[d0 + j]) * qscale;
                ushort hv = f2bf(v);
                hh.u[j] = hv;
                ll.u[j] = f2bf(v - bf2f(hv));
            }
            qh[dc] = hh.v; ql[dc] = ll.v;
        }
    }

    floatx4 oacc[4];    // O^T: oacc[df][r] = O[q=frow][dim=df*16+quad*4+r]
    #pragma unroll
    for (int d = 0; d < 4; ++d) oacc[d] = (floatx4){0.f, 0.f, 0.f, 0.f};
    float lsum = 0.f;   // per-lane partial of l[q=frow] over this quad's keys

    unsigned* Pwh = &Pshh[w][0][0];
    unsigned* Pwl = &Pshl[w][0][0];
    const size_t bT = (size_t)b * T_;
    const size_t vbh = (size_t)(b * 16 + h) * 65;

    // prologue: stage K tile 0 into Ksh[0]
    {
        int key = skg * 16 + frow;
        const size_t rowoff = (bT + key) * 1024 + h * 64 + quad * 8;
        #pragma unroll
        for (int j = 0; j < 2; ++j) {
            int s = ssb + j;
            int dc = s >> 1, pl2 = s & 1;
            const ushort* src = (pl2 ? klo : khi) + rowoff + dc * 32;
            gload16(src, &Ksh[0][(skg * 4 + s) * 512]);
        }
    }
    __syncthreads();   // drains vmcnt(0): K[0] landed

    for (int ti = 0; ti < ntiles; ++ti) {
        const int t0 = ti * 64;
        const int cur = ti & 1;

        // V reg-loads (oldest VMEM, keeps K prefetch in flight)
        short8 vreg[2][4];
        #pragma unroll
        for (int kc = 0; kc < 2; ++kc) {
            int kcg = (t0 >> 5) + kc;
            const ushort* vsrc = vfrag + ((vbh + kcg) * 4) * 512 + lane * 8;
            #pragma unroll
            for (int df = 0; df < 4; ++df)
                vreg[kc][df] = *(const short8*)(vsrc + df * 512);
        }

        // issue NEXT tile's K stage into the other buffer (no wait here)
        if (ti + 1 < ntiles) {
            int key = t0 + 64 + skg * 16 + frow;
            const size_t rowoff = (bT + key) * 1024 + h * 64 + quad * 8;
            #pragma unroll
            for (int j = 0; j < 2; ++j) {
                int s = ssb + j;
                int dc = s >> 1, pl2 = s & 1;
                const ushort* src = (pl2 ? klo : khi) + rowoff + dc * 32;
                gload16(src, &Ksh[cur ^ 1][(skg * 4 + s) * 512]);
            }
        }

        // swapped QK^T: sacc[kg] = C[key_local=quad*4+r][q=frow]
        floatx4 sacc[4];
        __builtin_amdgcn_s_setprio(1);
        #pragma unroll
        for (int kg = 0; kg < 4; ++kg) {
            sacc[kg] = (floatx4){0.f, 0.f, 0.f, 0.f};
            #pragma unroll
            for (int dc = 0; dc < 2; ++dc) {
                short8 kh = *(const short8*)&Ksh[cur][(kg * 4 + dc * 2 + 0) * 512 + lane * 8];
                short8 kl = *(const short8*)&Ksh[cur][(kg * 4 + dc * 2 + 1) * 512 + lane * 8];
                sacc[kg] = __builtin_amdgcn_mfma_f32_16x16x32_bf16(kh, qh[dc], sacc[kg], 0, 0, 0);
                sacc[kg] = __builtin_amdgcn_mfma_f32_16x16x32_bf16(kl, qh[dc], sacc[kg], 0, 0, 0);
                sacc[kg] = __builtin_amdgcn_mfma_f32_16x16x32_bf16(kh, ql[dc], sacc[kg], 0, 0, 0);
            }
        }
        __builtin_amdgcn_s_setprio(0);

        // per-kc: exp + cvt_pk pack -> Psh(b64) -> b128 read = B-frag, PV
        #pragma unroll
        for (int kc = 0; kc < 2; ++kc) {
            #pragma unroll
            for (int kg2 = 0; kg2 < 2; ++kg2) {
                int kg = kc * 2 + kg2;
                float p0 = exp2raw(sacc[kg][0]);
                float p1 = exp2raw(sacc[kg][1]);
                float p2 = exp2raw(sacc[kg][2]);
                float p3 = exp2raw(sacc[kg][3]);
                lsum += (p0 + p1) + (p2 + p3);
                unsigned dh0 = cvtpk(p0, p1);
                float l0 = p0 - __uint_as_float(dh0 << 16);
                float l1 = p1 - __uint_as_float(dh0 & 0xffff0000u);
                unsigned dl0 = cvtpk(l0, l1);
                unsigned dh1 = cvtpk(p2, p3);
                float l2 = p2 - __uint_as_float(dh1 << 16);
                float l3 = p3 - __uint_as_float(dh1 & 0xffff0000u);
                unsigned dl1 = cvtpk(l2, l3);
                int k2 = kg2 * 8 + quad * 2;   // dword index within kc
                *(uint2v*)&Pwh[frow * 20 + k2] = (uint2v){dh0, dh1};
                *(uint2v*)&Pwl[frow * 20 + k2] = (uint2v){dl0, dl1};
            }
            // reader lane (q=frow, dq=quad): b128 = keys dq*8+{0..7} packed
            short8 bh = *(const short8*)&Pwh[frow * 20 + quad * 4];
            short8 bl = *(const short8*)&Pwl[frow * 20 + quad * 4];
            __builtin_amdgcn_s_setprio(1);
            #pragma unroll
            for (int df = 0; df < 4; ++df) {
                oacc[df] = __builtin_amdgcn_mfma_f32_16x16x32_bf16(vreg[kc][df], bh, oacc[df], 0, 0, 0);
                oacc[df] = __builtin_amdgcn_mfma_f32_16x16x32_bf16(vreg[kc][df], bl, oacc[df], 0, 0, 0);
            }
            __builtin_amdgcn_s_setprio(0);
        }

        __syncthreads();   // drains vmcnt (next K landed); Ksh rotation safe
    }

    // l[q]: reduce partials over the 4 quads (lane bits 4,5)
    lsum += __shfl_xor(lsum, 16);
    lsum += __shfl_xor(lsum, 32);

    // key 2048 (last row): scalar fp32 path
    {
        const size_t ro = (bT + 2048) * 1024 + (size_t)h * 64 + quad * 8;
        float p = 0.f;
        #pragma unroll
        for (int dc = 0; dc < 2; ++dc) {
            union { short8 v; ushort u[8]; } KH, KL, QH, QL;
            KH.v = *(const short8*)(khi + ro + dc * 32);
            KL.v = *(const short8*)(klo + ro + dc * 32);
            QH.v = qh[dc]; QL.v = ql[dc];
            #pragma unroll
            for (int j = 0; j < 8; ++j) {
                float kf = bf2f(KH.u[j]) + bf2f(KL.u[j]);
                float qf = bf2f(QH.u[j]) + bf2f(QL.u[j]);
                p = fmaf(qf, kf, p);
            }
        }
        p += __shfl_xor(p, 16);
        p += __shfl_xor(p, 32);
        float e = exp2raw(p);
        lsum += e;
        const ushort* vr = v2048 + b * 1024 + h * 64 + quad * 4;
        #pragma unroll
        for (int df = 0; df < 4; ++df)
            #pragma unroll
            for (int r = 0; r < 4; ++r)
                oacc[df][r] = fmaf(e, bf2f(vr[df * 16 + r]), oacc[df][r]);
    }

    // epilogue: gated, normalized O^T -> contiguous float4 stores; q = frow
    int q = qwave + frow;
    if (q < Q_) {
        float s = gates[0] / lsum;
        float* dst = out + ((size_t)b * Q_ + q) * E_ + h * HD + quad * 4;
        #pragma unroll
        for (int df = 0; df < 4; ++df) {
            float4 o4;
            o4.x = oacc[df][0] * s; o4.y = oacc[df][1] * s;
            o4.z = oacc[df][2] * s; o4.w = oacc[df][3] * s;
            *(float4*)(dst + df * 16) = o4;
        }
    }
}

// ---------------- Fallback fp32 path (if workspace too small) --------------
#define SMK 36
__global__ __launch_bounds__(256) void kv_gemm_kernel(
    const float* __restrict__ x_b, const float* __restrict__ pe,
    const float* __restrict__ prompt,
    const float* __restrict__ Wk, const float* __restrict__ Wv,
    float* __restrict__ kout, float* __restrict__ vout) {

    __shared__ float As[64][SMK];
    __shared__ float Bks[64][SMK];
    __shared__ float Bvs[64][SMK];

    const int t = threadIdx.x;
    const int m0 = blockIdx.y * 64;
    const int n0 = blockIdx.x * 64;
    const int tx = t & 15, ty = t >> 4;
    const int rr = t >> 2;
    const int kp = (t & 3) * 8;

    int m = m0 + rr;
    if (m >= MROWS) m = 0;
    const int bb = m / T_;
    const int tt = m - bb * T_;
    const float* aptr; const float* peptr; float pesc;
    if (tt == 0) { aptr = prompt; peptr = pe; pesc = 0.f; }
    else {
        aptr = x_b + ((size_t)bb * TB + (tt - 1)) * 1024;
        peptr = pe + (size_t)(tt - 1) * 1024;
        pesc = 1.f;
    }
    const float* wkp = Wk + (size_t)(n0 + rr) * 1024;
    const float* wvp = Wv + (size_t)(n0 + rr) * 1024;

    float ck[4][4] = {{0.f}}, cv[4][4] = {{0.f}};

    for (int k0 = 0; k0 < 1024; k0 += 32) {
        __syncthreads();
        {
            float4 xa0 = *(const float4*)(aptr + k0 + kp);
            float4 xa1 = *(const float4*)(aptr + k0 + kp + 4);
            float4 pe0 = *(const float4*)(peptr + k0 + kp);
            float4 pe1 = *(const float4*)(peptr + k0 + kp + 4);
            xa0.x = fmaf(pesc, pe0.x, xa0.x);
            xa0.y = fmaf(pesc, pe0.y, xa0.y);
            xa0.z = fmaf(pesc, pe0.z, xa0.z);
            xa0.w = fmaf(pesc, pe0.w, xa0.w);
            xa1.x = fmaf(pesc, pe1.x, xa1.x);
            xa1.y = fmaf(pesc, pe1.y, xa1.y);
            xa1.z = fmaf(pesc, pe1.z, xa1.z);
            xa1.w = fmaf(pesc, pe1.w, xa1.w);
            *(float4*)&As[rr][kp]     = xa0;
            *(float4*)&As[rr][kp + 4] = xa1;
            *(float4*)&Bks[rr][kp]     = *(const float4*)(wkp + k0 + kp);
            *(float4*)&Bks[rr][kp + 4] = *(const float4*)(wkp + k0 + kp + 4);
            *(float4*)&Bvs[rr][kp]     = *(const float4*)(wvp + k0 + kp);
            *(float4*)&Bvs[rr][kp + 4] = *(const float4*)(wvp + k0 + kp + 4);
        }
        __syncthreads();
        for (int k4 = 0; k4 < 8; ++k4) {
            float4 a[4], bk[4], bv[4];
            #pragma unroll
            for (int i = 0; i < 4; ++i) a[i] = *(const float4*)&As[ty * 4 + i][k4 * 4];
            #pragma unroll
            for (int j = 0; j < 4; ++j) {
                bk[j] = *(const float4*)&Bks[tx * 4 + j][k4 * 4];
                bv[j] = *(const float4*)&Bvs[tx * 4 + j][k4 * 4];
            }
            #pragma unroll
            for (int i = 0; i < 4; ++i)
                #pragma unroll
                for (int j = 0; j < 4; ++j) {
                    ck[i][j] = fmaf(a[i].x, bk[j].x, ck[i][j]);
                    ck[i][j] = fmaf(a[i].y, bk[j].y, ck[i][j]);
                    ck[i][j] = fmaf(a[i].z, bk[j].z, ck[i][j]);
                    ck[i][j] = fmaf(a[i].w, bk[j].w, ck[i][j]);
                    cv[i][j] = fmaf(a[i].x, bv[j].x, cv[i][j]);
                    cv[i][j] = fmaf(a[i].y, bv[j].y, cv[i][j]);
                    cv[i][j] = fmaf(a[i].z, bv[j].z, cv[i][j]);
                    cv[i][j] = fmaf(a[i].w, bv[j].w, cv[i][j]);
                }
        }
    }

    #pragma unroll
    for (int i = 0; i < 4; ++i) {
        int mrow = m0 + ty * 4 + i;
        if (mrow < MROWS) {
            float4 kq, vq;
            kq.x = ck[i][0]; kq.y = ck[i][1]; kq.z = ck[i][2]; kq.w = ck[i][3];
            vq.x = cv[i][0]; vq.y = cv[i][1]; vq.z = cv[i][2]; vq.w = cv[i][3];
            *(float4*)(kout + (size_t)mrow * 1024 + n0 + tx * 4) = kq;
            *(float4*)(vout + (size_t)mrow * 1024 + n0 + tx * 4) = vq;
        }
    }
}

#define KSTR 68
__device__ __forceinline__ float dot16(const float (&q)[16], const float* kf) {
    float4 k0 = *(const float4*)(kf);
    float4 k1 = *(const float4*)(kf + 4);
    float4 k2 = *(const float4*)(kf + 8);
    float4 k3 = *(const float4*)(kf + 12);
    float p;
    p = q[0] * k0.x;
    p = fmaf(q[1], k0.y, p);  p = fmaf(q[2], k0.z, p);  p = fmaf(q[3], k0.w, p);
    p = fmaf(q[4], k1.x, p);  p = fmaf(q[5], k1.y, p);  p = fmaf(q[6], k1.z, p);  p = fmaf(q[7], k1.w, p);
    p = fmaf(q[8], k2.x, p);  p = fmaf(q[9], k2.y, p);  p = fmaf(q[10], k2.z, p); p = fmaf(q[11], k2.w, p);
    p = fmaf(q[12], k3.x, p); p = fmaf(q[13], k3.y, p); p = fmaf(q[14], k3.z, p); p = fmaf(q[15], k3.w, p);
    return p;
}
__device__ __forceinline__ void pv16(float (&o)[16], float pk, const float* vf) {
    float4 v0 = *(const float4*)(vf);
    float4 v1 = *(const float4*)(vf + 4);
    float4 v2 = *(const float4*)(vf + 8);
    float4 v3 = *(const float4*)(vf + 12);
    o[0]  = fmaf(pk, v0.x, o[0]);  o[1]  = fmaf(pk, v0.y, o[1]);
    o[2]  = fmaf(pk, v0.z, o[2]);  o[3]  = fmaf(pk, v0.w, o[3]);
    o[4]  = fmaf(pk, v1.x, o[4]);  o[5]  = fmaf(pk, v1.y, o[5]);
    o[6]  = fmaf(pk, v1.z, o[6]);  o[7]  = fmaf(pk, v1.w, o[7]);
    o[8]  = fmaf(pk, v2.x, o[8]);  o[9]  = fmaf(pk, v2.y, o[9]);
    o[10] = fmaf(pk, v2.z, o[10]); o[11] = fmaf(pk, v2.w, o[11]);
    o[12] = fmaf(pk, v3.x, o[12]); o[13] = fmaf(pk, v3.y, o[13]);
    o[14] = fmaf(pk, v3.z, o[14]); o[15] = fmaf(pk, v3.w, o[15]);
}

__global__ __launch_bounds__(256) void attn_kernel(
    const float* __restrict__ debug, const float* __restrict__ proj50,
    const float* __restrict__ kmat, const float* __restrict__ vmat,
    const float* __restrict__ gates, float* __restrict__ out) {

    __shared__ float k_s[64][KSTR];
    __shared__ float v_s[64][KSTR];

    const int t = threadIdx.x;
    const int lane = t & 63;
    const int w = t >> 6;
    const int r = lane >> 2;
    const int g = lane & 3;
    const int qi = blockIdx.x * 64 + w * 16 + r;
    const int h = blockIdx.y, b = blockIdx.z;
    const bool valid = qi < Q_;

    float q[16], o[16];
    {
        int qq = valid ? qi : 0;
        int idx = (qq * 50) / Q_;
        const float* dsrc = debug + (((size_t)(b * H_ + h)) * Q_ + qq) * HD + g * 16;
        const float* psrc = proj50 + (size_t)idx * 1024 + h * HD + g * 16;
        #pragma unroll
        for (int j4 = 0; j4 < 4; ++j4) {
            float4 dv = *(const float4*)(dsrc + j4 * 4);
            float4 pv = *(const float4*)(psrc + j4 * 4);
            q[j4 * 4 + 0] = (dv.x + pv.x) * 0.125f;
            q[j4 * 4 + 1] = (dv.y + pv.y) * 0.125f;
            q[j4 * 4 + 2] = (dv.z + pv.z) * 0.125f;
            q[j4 * 4 + 3] = (dv.w + pv.w) * 0.125f;
        }
    }
    float mrun = -INFINITY, lrun = 0.f;
    #pragma unroll
    for (int j = 0; j < 16; ++j) o[j] = 0.f;

    const int srow = t >> 2;
    const int scol = (t & 3) * 16;
    const float* kbase = kmat + ((size_t)b * T_) * E_ + h * HD + scol;
    const float* vbase = vmat + ((size_t)b * T_) * E_ + h * HD + scol;

    for (int t0 = 0; t0 < 2048; t0 += 64) {
        __syncthreads();
        {
            const float* kr = kbase + (size_t)(t0 + srow) * E_;
            const float* vr = vbase + (size_t)(t0 + srow) * E_;
            #pragma unroll
            for (int j4 = 0; j4 < 4; ++j4) {
                *(float4*)&k_s[srow][scol + j4 * 4] = *(const float4*)(kr + j4 * 4);
                *(float4*)&v_s[srow][scol + j4 * 4] = *(const float4*)(vr + j4 * 4);
            }
        }
        __syncthreads();
        #pragma unroll 1
        for (int kb = 0; kb < 64; kb += 16) {
            float sc[16];
            #pragma unroll
            for (int kk = 0; kk < 16; ++kk) {
                float p = dot16(q, &k_s[kb + kk][g * 16]);
                p += __shfl_xor(p, 1);
                p += __shfl_xor(p, 2);
                sc[kk] = p;
            }
            float mt = sc[0];
            #pragma unroll
            for (int kk = 1; kk < 16; ++kk) mt = fmaxf(mt, sc[kk]);
            float mn = fmaxf(mrun, mt);
            float al = __expf(mrun - mn);
            float ssum = 0.f;
            #pragma unroll
            for (int kk = 0; kk < 16; ++kk) { sc[kk] = __expf(sc[kk] - mn); ssum += sc[kk]; }
            mrun = mn;
            lrun = fmaf(lrun, al, ssum);
            #pragma unroll
            for (int j = 0; j < 16; ++j) o[j] *= al;
            #pragma unroll
            for (int kk = 0; kk < 16; ++kk) pv16(o, sc[kk], &v_s[kb + kk][g * 16]);
        }
    }
    {
        const float* kr = kmat + ((size_t)(b * T_ + 2048)) * E_ + h * HD + g * 16;
        const float* vr = vmat + ((size_t)(b * T_ + 2048)) * E_ + h * HD + g * 16;
        float p = dot16(q, kr);
        p += __shfl_xor(p, 1);
        p += __shfl_xor(p, 2);
        float mn = fmaxf(mrun, p);
        float al = __expf(mrun - mn);
        float pk = __expf(p - mn);
        lrun = fmaf(lrun, al, pk);
        #pragma unroll
        for (int j = 0; j < 16; ++j) o[j] *= al;
        pv16(o, pk, vr);
    }

    if (valid) {
        float s = gates[0] / lrun;
        float* dst = out + ((size_t)b * Q_ + qi) * E_ + h * HD + g * 16;
        #pragma unroll
        for (int j4 = 0; j4 < 4; ++j4) {
            float4 ov;
            ov.x = o[j4 * 4 + 0] * s;
            ov.y = o[j4 * 4 + 1] * s;
            ov.z = o[j4 * 4 + 2] * s;
            ov.w = o[j4 * 4 + 3] * s;
            *(float4*)(dst + j4 * 4) = ov;
        }
    }
}

extern "C" void kernel_launch(void* const* d_in, const int* in_sizes, int n_in,
                              void* d_out, int out_size, void* d_ws, size_t ws_size,
                              hipStream_t stream) {
    // inputs: x_a(0), x_b(1), debug(2), Wk(3), Wv(4), Wpos(5),
    //         prompt(6), gates(7), pe(8), full_b_step(9), full_a_step(10)
    const float* x_b = (const float*)d_in[1];
    const float* debug = (const float*)d_in[2];
    const float* Wk = (const float*)d_in[3];
    const float* Wv = (const float*)d_in[4];
    const float* Wpos = (const float*)d_in[5];
    const float* prompt = (const float*)d_in[6];
    const float* gates = (const float*)d_in[7];
    const float* pe = (const float*)d_in[8];
    float* out = (float*)d_out;

    char* ws = (char*)d_ws;
    const size_t KVH = (size_t)MROWS * 1024 * sizeof(ushort);      // 16,785,408
    const size_t KVF = (size_t)MROWS * 1024 * sizeof(float);       // 33,570,816
    const size_t AF  = (size_t)MT_TILES * 32 * 64 * 8 * sizeof(ushort);  // 16,809,984
    const size_t WF  = (size_t)128 * 32 * 64 * 8 * sizeof(ushort);       //  4,194,304
    const size_t P50 = 256 * 1024;

    float*  proj50 = (float*)ws;                   // 200 KB used of 256 KB
    ushort* v2048u = (ushort*)(ws + 240 * 1024);   // 8 KB spare in P50 slab
    ushort* khi  = (ushort*)(ws + P50);
    ushort* klo  = (ushort*)(ws + P50 + KVH);
    float*  vbuf = (float*)(ws + P50 + 2 * KVH);   // fp32 region (fallback)
    ushort* afhi = (ushort*)(ws + P50 + 2 * KVH + KVF);
    ushort* aflo = (ushort*)(ws + P50 + 2 * KVH + KVF + AF);
    ushort* wfhi = (ushort*)(ws + P50 + 2 * KVH + KVF + 2 * AF);
    ushort* wflo = (ushort*)(ws + P50 + 2 * KVH + KVF + 2 * AF + WF);
    // main path aliasing: vfrag (17.04 MB) lives in the vbuf region
    // (33.57 MB) — written by kv_mfma, read by attn.
    ushort* vfrag = (ushort*)vbuf;
    const size_t needed = P50 + 2 * KVH + KVF + 2 * AF + 2 * WF;  // 109,412,352

    proj50_kernel<<<dim3(50, 4), 256, 0, stream>>>(pe, Wpos, proj50);

    if (ws_size >= needed) {
        split_all_kernel<<<dim3(MT_TILES + 128), 256, 0, stream>>>(
            x_b, pe, prompt, Wk, Wv, afhi, aflo, wfhi, wflo);
        kv_mfma_kernel<<<dim3(1040), 256, 0, stream>>>(afhi, aflo, wfhi, wflo,
                                                       khi, klo, vfrag, v2048u);
        attn_mfma_kernel<<<dim3(7, H_, B_), 512, 0, stream>>>(
            debug, proj50, khi, klo, vfrag, v2048u, gates, out);
    } else {
        float* kbuf = (float*)khi;   // fallback: fp32 K in khi+klo region (same size)
        kv_gemm_kernel<<<dim3(16, 129), 256, 0, stream>>>(x_b, pe, prompt, Wk, Wv, kbuf, vbuf);
        attn_kernel<<<dim3(13, H_, B_), 256, 0, stream>>>(debug, proj50, kbuf, vbuf, gates, out);
    }
}

// Round 9
// 335.989 us; speedup vs baseline: 1.5424x; 1.0599x over previous
//
#include <hip/hip_runtime.h>
#include <hip/hip_bf16.h>
#include <math.h>

#define B_ 4
#define T_ 2049      // keys = prompt + 2048
#define TB 2048
#define Q_ 801
#define H_ 16
#define HD 64
#define E_ 1024
#define MROWS (B_ * T_)   // 8196
#define MT_TILES 513      // ceil(8196/16)

typedef short short8 __attribute__((ext_vector_type(8)));
typedef float floatx4 __attribute__((ext_vector_type(4)));
typedef int int4v __attribute__((ext_vector_type(4)));
typedef unsigned uint2v __attribute__((ext_vector_type(2)));

__device__ __forceinline__ ushort f2bf(float x) {
    unsigned u = __float_as_uint(x);
    unsigned r = (u + 0x7fffu + ((u >> 16) & 1u)) >> 16;
    return (ushort)r;
}
__device__ __forceinline__ float bf2f(ushort h) {
    return __uint_as_float(((unsigned)h) << 16);
}
__device__ __forceinline__ void gload16(const void* g, void* l) {
    __builtin_amdgcn_global_load_lds(
        (const __attribute__((address_space(1))) void*)g,
        (__attribute__((address_space(3))) void*)l, 16, 0, 0);
}
// raw v_exp_f32: computes 2^x (hardware exp2)
__device__ __forceinline__ float exp2raw(float x) {
    float r;
    asm("v_exp_f32 %0, %1" : "=v"(r) : "v"(x));
    return r;
}
// v_cvt_pk_bf16_f32: low16 = bf16(a), high16 = bf16(b)
__device__ __forceinline__ unsigned cvtpk(float a, float b) {
    unsigned r;
    asm("v_cvt_pk_bf16_f32 %0, %1, %2" : "=v"(r) : "v"(a), "v"(b));
    return r;
}

// ---------------- proj50 (fallback-path standalone) ------------------------
__global__ __launch_bounds__(256) void proj50_kernel(
    const float* __restrict__ pe, const float* __restrict__ Wpos,
    float* __restrict__ proj50) {
    __shared__ float pes[1024];
    const int r = blockIdx.x;        // 0..49
    const int t = threadIdx.x;       // 256
    for (int p = 0; p < 4; ++p) pes[t + p * 256] = pe[(size_t)r * 1024 + t + p * 256];
    __syncthreads();
    const int c = blockIdx.y * 256 + t;
    const float4* w4 = (const float4*)(Wpos + (size_t)c * 1024);
    float acc = 0.f;
    for (int i = 0; i < 256; ++i) {
        float4 wv = w4[i];
        acc = fmaf(pes[4 * i + 0], wv.x, acc);
        acc = fmaf(pes[4 * i + 1], wv.y, acc);
        acc = fmaf(pes[4 * i + 2], wv.z, acc);
        acc = fmaf(pes[4 * i + 3], wv.w, acc);
    }
    proj50[(size_t)r * 1024 + c] = acc;
}

// ---------------- split_all: kv rows + [Wk;Wv] rows + proj50 in ONE dispatch
// blocks [0,513): kv split; [513,641): W split; [641,841): proj50 (r,cy).
__global__ __launch_bounds__(256) void split_all_kernel(
    const float* __restrict__ x_b, const float* __restrict__ pe,
    const float* __restrict__ prompt,
    const float* __restrict__ Wk, const float* __restrict__ Wv,
    const float* __restrict__ Wpos, float* __restrict__ proj50,
    ushort* __restrict__ afhi, ushort* __restrict__ aflo,
    ushort* __restrict__ wfhi, ushort* __restrict__ wflo) {
    const int bid = blockIdx.x;
    const int t = threadIdx.x;
    const int lane = t & 63, kq = t >> 6;
    const int row_in = lane & 15, quad = lane >> 4;
    if (bid < MT_TILES) {
        const int mt = bid;
        int m = mt * 16 + row_in; if (m > MROWS - 1) m = MROWS - 1;
        const int b = m / T_, tt = m - b * T_;
        const float* src; const float* pesrc; float psc;
        if (tt == 0) { src = prompt; pesrc = pe; psc = 0.f; }
        else {
            src = x_b + ((size_t)b * TB + tt - 1) * 1024;
            pesrc = pe + (size_t)(tt - 1) * 1024;
            psc = 1.f;
        }
        #pragma unroll
        for (int rep = 0; rep < 8; ++rep) {
            int kc = rep * 4 + kq;
            int k0 = kc * 32 + quad * 8;
            float4 xa = *(const float4*)(src + k0);
            float4 xb2 = *(const float4*)(src + k0 + 4);
            float4 pa = *(const float4*)(pesrc + k0);
            float4 pb = *(const float4*)(pesrc + k0 + 4);
            float vv[8];
            vv[0] = fmaf(psc, pa.x, xa.x);  vv[1] = fmaf(psc, pa.y, xa.y);
            vv[2] = fmaf(psc, pa.z, xa.z);  vv[3] = fmaf(psc, pa.w, xa.w);
            vv[4] = fmaf(psc, pb.x, xb2.x); vv[5] = fmaf(psc, pb.y, xb2.y);
            vv[6] = fmaf(psc, pb.z, xb2.z); vv[7] = fmaf(psc, pb.w, xb2.w);
            union { ushort u[8]; short8 s; } hu, lu;
            #pragma unroll
            for (int j = 0; j < 8; ++j) {
                ushort h = f2bf(vv[j]);
                hu.u[j] = h;
                lu.u[j] = f2bf(vv[j] - bf2f(h));
            }
            size_t off = ((size_t)(mt * 32 + kc) * 64 + lane) * 8;
            *(short8*)(afhi + off) = hu.s;
            *(short8*)(aflo + off) = lu.s;
        }
    } else if (bid < MT_TILES + 128) {
        const int nt = bid - MT_TILES;        // 0..127
        const int n = nt * 16 + row_in;       // 0..2047
        const float* src = (n < 1024) ? Wk + (size_t)n * 1024
                                      : Wv + (size_t)(n - 1024) * 1024;
        #pragma unroll
        for (int rep = 0; rep < 8; ++rep) {
            int kc = rep * 4 + kq;
            int k0 = kc * 32 + quad * 8;
            float4 xa = *(const float4*)(src + k0);
            float4 xb2 = *(const float4*)(src + k0 + 4);
            float vv[8] = {xa.x, xa.y, xa.z, xa.w, xb2.x, xb2.y, xb2.z, xb2.w};
            union { ushort u[8]; short8 s; } hu, lu;
            #pragma unroll
            for (int j = 0; j < 8; ++j) {
                ushort h = f2bf(vv[j]);
                hu.u[j] = h;
                lu.u[j] = f2bf(vv[j] - bf2f(h));
            }
            size_t off = ((size_t)(nt * 32 + kc) * 64 + lane) * 8;
            *(short8*)(wfhi + off) = hu.s;
            *(short8*)(wflo + off) = lu.s;
        }
    } else {
        // proj50: pid in [0,200): r = pid%50, cy = pid/50
        __shared__ float pes[1024];
        const int pid = bid - (MT_TILES + 128);
        const int r = pid % 50, cy = pid / 50;
        for (int p = 0; p < 4; ++p) pes[t + p * 256] = pe[(size_t)r * 1024 + t + p * 256];
        __syncthreads();
        const int c = cy * 256 + t;
        const float4* w4 = (const float4*)(Wpos + (size_t)c * 1024);
        float acc = 0.f;
        for (int i = 0; i < 256; ++i) {
            float4 wv = w4[i];
            acc = fmaf(pes[4 * i + 0], wv.x, acc);
            acc = fmaf(pes[4 * i + 1], wv.y, acc);
            acc = fmaf(pes[4 * i + 2], wv.z, acc);
            acc = fmaf(pes[4 * i + 3], wv.w, acc);
        }
        proj50[(size_t)r * 1024 + c] = acc;
    }
}

// ---------------- Kernel 2: barrier-free MFMA K/V GEMM, XCD-localized ------
// R8 counters: 108 us, MfmaUtil 34 (= this structure's ~36% ceiling).
// V-path change: drop the W-lo term (Ahi*Wlo) — V output is immediately
// bf16-quantized and the path already omits Alo*W of the same magnitude,
// so the term is below the output's own rounding floor. V-blocks: 2->1
// MFMA per acc per chunk (-19% of kernel MFMA ops), -8 loads/chunk.
__global__ __launch_bounds__(256) void kv_mfma_kernel(
    const ushort* __restrict__ afhi, const ushort* __restrict__ aflo,
    const ushort* __restrict__ wfhi, const ushort* __restrict__ wflo,
    ushort* __restrict__ khi, ushort* __restrict__ klo,
    ushort* __restrict__ vfrag, ushort* __restrict__ v2048) {

    const int t = threadIdx.x, lane = t & 63, w = t >> 6;
    const int wm = w >> 1, wn = w & 1;
    const int bid = blockIdx.x;
    const int c = bid & 7, jj2 = bid >> 3;
    int xx, yy;
    if (jj2 < 128) { yy = ((jj2 >> 4) << 3) + c; xx = jj2 & 15; }
    else           { yy = 64; xx = c * 2 + (jj2 - 128); }
    const int m0 = yy * 128, n0x = xx * 128;
    const bool isK = (xx < 8);
    const size_t lb = (size_t)lane * 8;

    const ushort* ah_p[4]; const ushort* al_p[4];
    const ushort* bh_p[4]; const ushort* bl_p[4];
    #pragma unroll
    for (int i = 0; i < 4; ++i) {
        size_t mt = (size_t)(yy * 8 + wm * 4 + i);
        ah_p[i] = afhi + mt * 16384 + lb;
        al_p[i] = aflo + mt * 16384 + lb;
        size_t nt = (size_t)(xx * 8 + wn * 4 + i);
        bh_p[i] = wfhi + nt * 16384 + lb;
        bl_p[i] = wflo + nt * 16384 + lb;
    }

    floatx4 acc[4][4];
    #pragma unroll
    for (int i = 0; i < 4; ++i)
        #pragma unroll
        for (int j = 0; j < 4; ++j)
            acc[i][j] = (floatx4){0.f, 0.f, 0.f, 0.f};

    if (isK) {
        short8 a0h[4], a0l[4], b0h[4], b0l[4];
        short8 a1h[4], a1l[4], b1h[4], b1l[4];
        #pragma unroll
        for (int i = 0; i < 4; ++i) {
            a0h[i] = *(const short8*)(ah_p[i]);
            a0l[i] = *(const short8*)(al_p[i]);
            b0h[i] = *(const short8*)(bh_p[i]);
            b0l[i] = *(const short8*)(bl_p[i]);
        }
        #pragma unroll 1
        for (int kc = 0; kc < 32; kc += 2) {
            {
                const int ko = (kc + 1) * 512;
                #pragma unroll
                for (int i = 0; i < 4; ++i) {
                    a1h[i] = *(const short8*)(ah_p[i] + ko);
                    a1l[i] = *(const short8*)(al_p[i] + ko);
                    b1h[i] = *(const short8*)(bh_p[i] + ko);
                    b1l[i] = *(const short8*)(bl_p[i] + ko);
                }
            }
            #pragma unroll
            for (int i = 0; i < 4; ++i)
                #pragma unroll
                for (int j = 0; j < 4; ++j) {
                    acc[i][j] = __builtin_amdgcn_mfma_f32_16x16x32_bf16(a0h[i], b0h[j], acc[i][j], 0, 0, 0);
                    acc[i][j] = __builtin_amdgcn_mfma_f32_16x16x32_bf16(a0h[i], b0l[j], acc[i][j], 0, 0, 0);
                    acc[i][j] = __builtin_amdgcn_mfma_f32_16x16x32_bf16(a0l[i], b0h[j], acc[i][j], 0, 0, 0);
                }
            if (kc + 2 < 32) {
                const int ko = (kc + 2) * 512;
                #pragma unroll
                for (int i = 0; i < 4; ++i) {
                    a0h[i] = *(const short8*)(ah_p[i] + ko);
                    a0l[i] = *(const short8*)(al_p[i] + ko);
                    b0h[i] = *(const short8*)(bh_p[i] + ko);
                    b0l[i] = *(const short8*)(bl_p[i] + ko);
                }
            }
            #pragma unroll
            for (int i = 0; i < 4; ++i)
                #pragma unroll
                for (int j = 0; j < 4; ++j) {
                    acc[i][j] = __builtin_amdgcn_mfma_f32_16x16x32_bf16(a1h[i], b1h[j], acc[i][j], 0, 0, 0);
                    acc[i][j] = __builtin_amdgcn_mfma_f32_16x16x32_bf16(a1h[i], b1l[j], acc[i][j], 0, 0, 0);
                    acc[i][j] = __builtin_amdgcn_mfma_f32_16x16x32_bf16(a1l[i], b1h[j], acc[i][j], 0, 0, 0);
                }
        }
    } else {
        short8 a0h[4], b0h[4];
        short8 a1h[4], b1h[4];
        #pragma unroll
        for (int i = 0; i < 4; ++i) {
            a0h[i] = *(const short8*)(ah_p[i]);
            b0h[i] = *(const short8*)(bh_p[i]);
        }
        #pragma unroll 1
        for (int kc = 0; kc < 32; kc += 2) {
            {
                const int ko = (kc + 1) * 512;
                #pragma unroll
                for (int i = 0; i < 4; ++i) {
                    a1h[i] = *(const short8*)(ah_p[i] + ko);
                    b1h[i] = *(const short8*)(bh_p[i] + ko);
                }
            }
            #pragma unroll
            for (int i = 0; i < 4; ++i)
                #pragma unroll
                for (int j = 0; j < 4; ++j)
                    acc[i][j] = __builtin_amdgcn_mfma_f32_16x16x32_bf16(a0h[i], b0h[j], acc[i][j], 0, 0, 0);
            if (kc + 2 < 32) {
                const int ko = (kc + 2) * 512;
                #pragma unroll
                for (int i = 0; i < 4; ++i) {
                    a0h[i] = *(const short8*)(ah_p[i] + ko);
                    b0h[i] = *(const short8*)(bh_p[i] + ko);
                }
            }
            #pragma unroll
            for (int i = 0; i < 4; ++i)
                #pragma unroll
                for (int j = 0; j < 4; ++j)
                    acc[i][j] = __builtin_amdgcn_mfma_f32_16x16x32_bf16(a1h[i], b1h[j], acc[i][j], 0, 0, 0);
        }
    }

    // epilogue: C layout col = lane&15, row = (lane>>4)*4 + reg
    const int frow = lane & 15, foct = lane >> 4;
    const int ncol = (n0x & 1023) + wn * 64 + frow;
    if (isK) {
        #pragma unroll
        for (int i = 0; i < 4; ++i) {
            #pragma unroll
            for (int r = 0; r < 4; ++r) {
                int row = m0 + wm * 64 + i * 16 + foct * 4 + r;
                if (row < MROWS) {
                    #pragma unroll
                    for (int j = 0; j < 4; ++j) {
                        float v = acc[i][j][r];
                        ushort hv = f2bf(v);
                        ushort lv = f2bf(v - bf2f(hv));
                        khi[(size_t)row * 1024 + ncol + j * 16] = hv;
                        klo[(size_t)row * 1024 + ncol + j * 16] = lv;
                    }
                }
            }
        }
    } else {
        // V: direct V^T fragment-major write (replaces vprep)
        const int hh = ((n0x & 1023) + wn * 64) >> 6;   // head 0..15
        #pragma unroll
        for (int i = 0; i < 4; ++i) {
            #pragma unroll
            for (int r = 0; r < 4; ++r) {
                int row = m0 + wm * 64 + i * 16 + foct * 4 + r;
                if (row < MROWS) {
                    int bb = row / T_;
                    int tt = row - bb * T_;      // key index 0..2048
                    if (tt < 2048) {
                        size_t vb = ((size_t)(bb * 16 + hh) * 65 + (tt >> 5)) * 4;
                        size_t lo_ = (size_t)(((tt >> 3) & 3) * 16 + frow) * 8 + (tt & 7);
                        #pragma unroll
                        for (int j = 0; j < 4; ++j)
                            vfrag[(vb + j) * 512 + lo_] = f2bf(acc[i][j][r]);
                    } else {
                        #pragma unroll
                        for (int j = 0; j < 4; ++j)
                            v2048[bb * 1024 + hh * 64 + j * 16 + frow] = f2bf(acc[i][j][r]);
                    }
                }
            }
        }
    }
}

// ---------------- Kernel 3: 8-wave MFMA flash attention, swapped-QK --------
// EXACT R5 loop structure (best measured) — locked per R6/R7 pre-commits.
// One block does all 32 tiles + key-2048 tail; gated, normalized output
// written directly to `out`.
__global__ __launch_bounds__(512, 4) void attn_mfma_kernel(
    const float* __restrict__ debug, const float* __restrict__ proj50,
    const ushort* __restrict__ khi, const ushort* __restrict__ klo,
    const ushort* __restrict__ vfrag, const ushort* __restrict__ v2048,
    const float* __restrict__ gates, float* __restrict__ out) {

    __shared__ __align__(16) ushort Ksh[2][16 * 512];    // 32 KB
    __shared__ __align__(16) unsigned Pshh[8][16][20];   // 10 KB
    __shared__ __align__(16) unsigned Pshl[8][16][20];   // 10 KB

    const int t = threadIdx.x, lane = t & 63, w = t >> 6;   // 8 waves
    const int frow = lane & 15, quad = lane >> 4;
    const int h = blockIdx.y, b = blockIdx.z;
    const int qt = blockIdx.x;              // 0..6
    const int qwave = qt * 128 + w * 16;
    const int ntiles = 32;                  // keys [0, 2048)

    // staging role: wave w stages key-group kg = w>>1, planes s = (w&1)*2+{0,1}
    const int skg = w >> 1, ssb = (w & 1) * 2;

    // Q in exp2 domain: scale = 0.125 * log2(e)
    const float qscale = 0.1803368801111244f;
    short8 qh[2], ql[2];
    {
        int qrow = qwave + frow; if (qrow > Q_ - 1) qrow = Q_ - 1;
        int idx = (qrow * 50) / Q_;
        const float* dsrc = debug + (((size_t)(b * H_ + h)) * Q_ + qrow) * HD;
        const float* psrc = proj50 + (size_t)idx * 1024 + h * HD;
        #pragma unroll
        for (int dc = 0; dc < 2; ++dc) {
            int d0 = dc * 32 + quad * 8;
            union { ushort u[8]; short8 v; } hh, ll;
            #pragma unroll
            for (int j = 0; j < 8; ++j) {
                float v = (dsrc[d0 + j] + psrc[d0 + j]) * qscale;
                ushort hv = f2bf(v);
                hh.u[j] = hv;
                ll.u[j] = f2bf(v - bf2f(hv));
            }
            qh[dc] = hh.v; ql[dc] = ll.v;
        }
    }

    floatx4 oacc[4];    // O^T: oacc[df][r] = O[q=frow][dim=df*16+quad*4+r]
    #pragma unroll
    for (int d = 0; d < 4; ++d) oacc[d] = (floatx4){0.f, 0.f, 0.f, 0.f};
    float lsum = 0.f;   // per-lane partial of l[q=frow] over this quad's keys

    unsigned* Pwh = &Pshh[w][0][0];
    unsigned* Pwl = &Pshl[w][0][0];
    const size_t bT = (size_t)b * T_;
    const size_t vbh = (size_t)(b * 16 + h) * 65;

    // prologue: stage K tile 0 into Ksh[0]
    {
        int key = skg * 16 + frow;
        const size_t rowoff = (bT + key) * 1024 + h * 64 + quad * 8;
        #pragma unroll
        for (int j = 0; j < 2; ++j) {
            int s = ssb + j;
            int dc = s >> 1, pl2 = s & 1;
            const ushort* src = (pl2 ? klo : khi) + rowoff + dc * 32;
            gload16(src, &Ksh[0][(skg * 4 + s) * 512]);
        }
    }
    __syncthreads();   // drains vmcnt(0): K[0] landed

    for (int ti = 0; ti < ntiles; ++ti) {
        const int t0 = ti * 64;
        const int cur = ti & 1;

        // V reg-loads (oldest VMEM, keeps K prefetch in flight)
        short8 vreg[2][4];
        #pragma unroll
        for (int kc = 0; kc < 2; ++kc) {
            int kcg = (t0 >> 5) + kc;
            const ushort* vsrc = vfrag + ((vbh + kcg) * 4) * 512 + lane * 8;
            #pragma unroll
            for (int df = 0; df < 4; ++df)
                vreg[kc][df] = *(const short8*)(vsrc + df * 512);
        }

        // issue NEXT tile's K stage into the other buffer (no wait here)
        if (ti + 1 < ntiles) {
            int key = t0 + 64 + skg * 16 + frow;
            const size_t rowoff = (bT + key) * 1024 + h * 64 + quad * 8;
            #pragma unroll
            for (int j = 0; j < 2; ++j) {
                int s = ssb + j;
                int dc = s >> 1, pl2 = s & 1;
                const ushort* src = (pl2 ? klo : khi) + rowoff + dc * 32;
                gload16(src, &Ksh[cur ^ 1][(skg * 4 + s) * 512]);
            }
        }

        // swapped QK^T: sacc[kg] = C[key_local=quad*4+r][q=frow]
        floatx4 sacc[4];
        __builtin_amdgcn_s_setprio(1);
        #pragma unroll
        for (int kg = 0; kg < 4; ++kg) {
            sacc[kg] = (floatx4){0.f, 0.f, 0.f, 0.f};
            #pragma unroll
            for (int dc = 0; dc < 2; ++dc) {
                short8 kh = *(const short8*)&Ksh[cur][(kg * 4 + dc * 2 + 0) * 512 + lane * 8];
                short8 kl = *(const short8*)&Ksh[cur][(kg * 4 + dc * 2 + 1) * 512 + lane * 8];
                sacc[kg] = __builtin_amdgcn_mfma_f32_16x16x32_bf16(kh, qh[dc], sacc[kg], 0, 0, 0);
                sacc[kg] = __builtin_amdgcn_mfma_f32_16x16x32_bf16(kl, qh[dc], sacc[kg], 0, 0, 0);
                sacc[kg] = __builtin_amdgcn_mfma_f32_16x16x32_bf16(kh, ql[dc], sacc[kg], 0, 0, 0);
            }
        }
        __builtin_amdgcn_s_setprio(0);

        // per-kc: exp + cvt_pk pack -> Psh(b64) -> b128 read = B-frag, PV
        #pragma unroll
        for (int kc = 0; kc < 2; ++kc) {
            #pragma unroll
            for (int kg2 = 0; kg2 < 2; ++kg2) {
                int kg = kc * 2 + kg2;
                float p0 = exp2raw(sacc[kg][0]);
                float p1 = exp2raw(sacc[kg][1]);
                float p2 = exp2raw(sacc[kg][2]);
                float p3 = exp2raw(sacc[kg][3]);
                lsum += (p0 + p1) + (p2 + p3);
                unsigned dh0 = cvtpk(p0, p1);
                float l0 = p0 - __uint_as_float(dh0 << 16);
                float l1 = p1 - __uint_as_float(dh0 & 0xffff0000u);
                unsigned dl0 = cvtpk(l0, l1);
                unsigned dh1 = cvtpk(p2, p3);
                float l2 = p2 - __uint_as_float(dh1 << 16);
                float l3 = p3 - __uint_as_float(dh1 & 0xffff0000u);
                unsigned dl1 = cvtpk(l2, l3);
                int k2 = kg2 * 8 + quad * 2;   // dword index within kc
                *(uint2v*)&Pwh[frow * 20 + k2] = (uint2v){dh0, dh1};
                *(uint2v*)&Pwl[frow * 20 + k2] = (uint2v){dl0, dl1};
            }
            // reader lane (q=frow, dq=quad): b128 = keys dq*8+{0..7} packed
            short8 bh = *(const short8*)&Pwh[frow * 20 + quad * 4];
            short8 bl = *(const short8*)&Pwl[frow * 20 + quad * 4];
            __builtin_amdgcn_s_setprio(1);
            #pragma unroll
            for (int df = 0; df < 4; ++df) {
                oacc[df] = __builtin_amdgcn_mfma_f32_16x16x32_bf16(vreg[kc][df], bh, oacc[df], 0, 0, 0);
                oacc[df] = __builtin_amdgcn_mfma_f32_16x16x32_bf16(vreg[kc][df], bl, oacc[df], 0, 0, 0);
            }
            __builtin_amdgcn_s_setprio(0);
        }

        __syncthreads();   // drains vmcnt (next K landed); Ksh rotation safe
    }

    // l[q]: reduce partials over the 4 quads (lane bits 4,5)
    lsum += __shfl_xor(lsum, 16);
    lsum += __shfl_xor(lsum, 32);

    // key 2048 (last row): scalar fp32 path
    {
        const size_t ro = (bT + 2048) * 1024 + (size_t)h * 64 + quad * 8;
        float p = 0.f;
        #pragma unroll
        for (int dc = 0; dc < 2; ++dc) {
            union { short8 v; ushort u[8]; } KH, KL, QH, QL;
            KH.v = *(const short8*)(khi + ro + dc * 32);
            KL.v = *(const short8*)(klo + ro + dc * 32);
            QH.v = qh[dc]; QL.v = ql[dc];
            #pragma unroll
            for (int j = 0; j < 8; ++j) {
                float kf = bf2f(KH.u[j]) + bf2f(KL.u[j]);
                float qf = bf2f(QH.u[j]) + bf2f(QL.u[j]);
                p = fmaf(qf, kf, p);
            }
        }
        p += __shfl_xor(p, 16);
        p += __shfl_xor(p, 32);
        float e = exp2raw(p);
        lsum += e;
        const ushort* vr = v2048 + b * 1024 + h * 64 + quad * 4;
        #pragma unroll
        for (int df = 0; df < 4; ++df)
            #pragma unroll
            for (int r = 0; r < 4; ++r)
                oacc[df][r] = fmaf(e, bf2f(vr[df * 16 + r]), oacc[df][r]);
    }

    // epilogue: gated, normalized O^T -> contiguous float4 stores; q = frow
    int q = qwave + frow;
    if (q < Q_) {
        float s = gates[0] / lsum;
        float* dst = out + ((size_t)b * Q_ + q) * E_ + h * HD + quad * 4;
        #pragma unroll
        for (int df = 0; df < 4; ++df) {
            float4 o4;
            o4.x = oacc[df][0] * s; o4.y = oacc[df][1] * s;
            o4.z = oacc[df][2] * s; o4.w = oacc[df][3] * s;
            *(float4*)(dst + df * 16) = o4;
        }
    }
}

// ---------------- Fallback fp32 path (if workspace too small) --------------
#define SMK 36
__global__ __launch_bounds__(256) void kv_gemm_kernel(
    const float* __restrict__ x_b, const float* __restrict__ pe,
    const float* __restrict__ prompt,
    const float* __restrict__ Wk, const float* __restrict__ Wv,
    float* __restrict__ kout, float* __restrict__ vout) {

    __shared__ float As[64][SMK];
    __shared__ float Bks[64][SMK];
    __shared__ float Bvs[64][SMK];

    const int t = threadIdx.x;
    const int m0 = blockIdx.y * 64;
    const int n0 = blockIdx.x * 64;
    const int tx = t & 15, ty = t >> 4;
    const int rr = t >> 2;
    const int kp = (t & 3) * 8;

    int m = m0 + rr;
    if (m >= MROWS) m = 0;
    const int bb = m / T_;
    const int tt = m - bb * T_;
    const float* aptr; const float* peptr; float pesc;
    if (tt == 0) { aptr = prompt; peptr = pe; pesc = 0.f; }
    else {
        aptr = x_b + ((size_t)bb * TB + (tt - 1)) * 1024;
        peptr = pe + (size_t)(tt - 1) * 1024;
        pesc = 1.f;
    }
    const float* wkp = Wk + (size_t)(n0 + rr) * 1024;
    const float* wvp = Wv + (size_t)(n0 + rr) * 1024;

    float ck[4][4] = {{0.f}}, cv[4][4] = {{0.f}};

    for (int k0 = 0; k0 < 1024; k0 += 32) {
        __syncthreads();
        {
            float4 xa0 = *(const float4*)(aptr + k0 + kp);
            float4 xa1 = *(const float4*)(aptr + k0 + kp + 4);
            float4 pe0 = *(const float4*)(peptr + k0 + kp);
            float4 pe1 = *(const float4*)(peptr + k0 + kp + 4);
            xa0.x = fmaf(pesc, pe0.x, xa0.x);
            xa0.y = fmaf(pesc, pe0.y, xa0.y);
            xa0.z = fmaf(pesc, pe0.z, xa0.z);
            xa0.w = fmaf(pesc, pe0.w, xa0.w);
            xa1.x = fmaf(pesc, pe1.x, xa1.x);
            xa1.y = fmaf(pesc, pe1.y, xa1.y);
            xa1.z = fmaf(pesc, pe1.z, xa1.z);
            xa1.w = fmaf(pesc, pe1.w, xa1.w);
            *(float4*)&As[rr][kp]     = xa0;
            *(float4*)&As[rr][kp + 4] = xa1;
            *(float4*)&Bks[rr][kp]     = *(const float4*)(wkp + k0 + kp);
            *(float4*)&Bks[rr][kp + 4] = *(const float4*)(wkp + k0 + kp + 4);
            *(float4*)&Bvs[rr][kp]     = *(const float4*)(wvp + k0 + kp);
            *(float4*)&Bvs[rr][kp + 4] = *(const float4*)(wvp + k0 + kp + 4);
        }
        __syncthreads();
        for (int k4 = 0; k4 < 8; ++k4) {
            float4 a[4], bk[4], bv[4];
            #pragma unroll
            for (int i = 0; i < 4; ++i) a[i] = *(const float4*)&As[ty * 4 + i][k4 * 4];
            #pragma unroll
            for (int j = 0; j < 4; ++j) {
                bk[j] = *(const float4*)&Bks[tx * 4 + j][k4 * 4];
                bv[j] = *(const float4*)&Bvs[tx * 4 + j][k4 * 4];
            }
            #pragma unroll
            for (int i = 0; i < 4; ++i)
                #pragma unroll
                for (int j = 0; j < 4; ++j) {
                    ck[i][j] = fmaf(a[i].x, bk[j].x, ck[i][j]);
                    ck[i][j] = fmaf(a[i].y, bk[j].y, ck[i][j]);
                    ck[i][j] = fmaf(a[i].z, bk[j].z, ck[i][j]);
                    ck[i][j] = fmaf(a[i].w, bk[j].w, ck[i][j]);
                    cv[i][j] = fmaf(a[i].x, bv[j].x, cv[i][j]);
                    cv[i][j] = fmaf(a[i].y, bv[j].y, cv[i][j]);
                    cv[i][j] = fmaf(a[i].z, bv[j].z, cv[i][j]);
                    cv[i][j] = fmaf(a[i].w, bv[j].w, cv[i][j]);
                }
        }
    }

    #pragma unroll
    for (int i = 0; i < 4; ++i) {
        int mrow = m0 + ty * 4 + i;
        if (mrow < MROWS) {
            float4 kq, vq;
            kq.x = ck[i][0]; kq.y = ck[i][1]; kq.z = ck[i][2]; kq.w = ck[i][3];
            vq.x = cv[i][0]; vq.y = cv[i][1]; vq.z = cv[i][2]; vq.w = cv[i][3];
            *(float4*)(kout + (size_t)mrow * 1024 + n0 + tx * 4) = kq;
            *(float4*)(vout + (size_t)mrow * 1024 + n0 + tx * 4) = vq;
        }
    }
}

#define KSTR 68
__device__ __forceinline__ float dot16(const float (&q)[16], const float* kf) {
    float4 k0 = *(const float4*)(kf);
    float4 k1 = *(const float4*)(kf + 4);
    float4 k2 = *(const float4*)(kf + 8);
    float4 k3 = *(const float4*)(kf + 12);
    float p;
    p = q[0] * k0.x;
    p = fmaf(q[1], k0.y, p);  p = fmaf(q[2], k0.z, p);  p = fmaf(q[3], k0.w, p);
    p = fmaf(q[4], k1.x, p);  p = fmaf(q[5], k1.y, p);  p = fmaf(q[6], k1.z, p);  p = fmaf(q[7], k1.w, p);
    p = fmaf(q[8], k2.x, p);  p = fmaf(q[9], k2.y, p);  p = fmaf(q[10], k2.z, p); p = fmaf(q[11], k2.w, p);
    p = fmaf(q[12], k3.x, p); p = fmaf(q[13], k3.y, p); p = fmaf(q[14], k3.z, p); p = fmaf(q[15], k3.w, p);
    return p;
}
__device__ __forceinline__ void pv16(float (&o)[16], float pk, const float* vf) {
    float4 v0 = *(const float4*)(vf);
    float4 v1 = *(const float4*)(vf + 4);
    float4 v2 = *(const float4*)(vf + 8);
    float4 v3 = *(const float4*)(vf + 12);
    o[0]  = fmaf(pk, v0.x, o[0]);  o[1]  = fmaf(pk, v0.y, o[1]);
    o[2]  = fmaf(pk, v0.z, o[2]);  o[3]  = fmaf(pk, v0.w, o[3]);
    o[4]  = fmaf(pk, v1.x, o[4]);  o[5]  = fmaf(pk, v1.y, o[5]);
    o[6]  = fmaf(pk, v1.z, o[6]);  o[7]  = fmaf(pk, v1.w, o[7]);
    o[8]  = fmaf(pk, v2.x, o[8]);  o[9]  = fmaf(pk, v2.y, o[9]);
    o[10] = fmaf(pk, v2.z, o[10]); o[11] = fmaf(pk, v2.w, o[11]);
    o[12] = fmaf(pk, v3.x, o[12]); o[13] = fmaf(pk, v3.y, o[13]);
    o[14] = fmaf(pk, v3.z, o[14]); o[15] = fmaf(pk, v3.w, o[15]);
}

__global__ __launch_bounds__(256) void attn_kernel(
    const float* __restrict__ debug, const float* __restrict__ proj50,
    const float* __restrict__ kmat, const float* __restrict__ vmat,
    const float* __restrict__ gates, float* __restrict__ out) {

    __shared__ float k_s[64][KSTR];
    __shared__ float v_s[64][KSTR];

    const int t = threadIdx.x;
    const int lane = t & 63;
    const int w = t >> 6;
    const int r = lane >> 2;
    const int g = lane & 3;
    const int qi = blockIdx.x * 64 + w * 16 + r;
    const int h = blockIdx.y, b = blockIdx.z;
    const bool valid = qi < Q_;

    float q[16], o[16];
    {
        int qq = valid ? qi : 0;
        int idx = (qq * 50) / Q_;
        const float* dsrc = debug + (((size_t)(b * H_ + h)) * Q_ + qq) * HD + g * 16;
        const float* psrc = proj50 + (size_t)idx * 1024 + h * HD + g * 16;
        #pragma unroll
        for (int j4 = 0; j4 < 4; ++j4) {
            float4 dv = *(const float4*)(dsrc + j4 * 4);
            float4 pv = *(const float4*)(psrc + j4 * 4);
            q[j4 * 4 + 0] = (dv.x + pv.x) * 0.125f;
            q[j4 * 4 + 1] = (dv.y + pv.y) * 0.125f;
            q[j4 * 4 + 2] = (dv.z + pv.z) * 0.125f;
            q[j4 * 4 + 3] = (dv.w + pv.w) * 0.125f;
        }
    }
    float mrun = -INFINITY, lrun = 0.f;
    #pragma unroll
    for (int j = 0; j < 16; ++j) o[j] = 0.f;

    const int srow = t >> 2;
    const int scol = (t & 3) * 16;
    const float* kbase = kmat + ((size_t)b * T_) * E_ + h * HD + scol;
    const float* vbase = vmat + ((size_t)b * T_) * E_ + h * HD + scol;

    for (int t0 = 0; t0 < 2048; t0 += 64) {
        __syncthreads();
        {
            const float* kr = kbase + (size_t)(t0 + srow) * E_;
            const float* vr = vbase + (size_t)(t0 + srow) * E_;
            #pragma unroll
            for (int j4 = 0; j4 < 4; ++j4) {
                *(float4*)&k_s[srow][scol + j4 * 4] = *(const float4*)(kr + j4 * 4);
                *(float4*)&v_s[srow][scol + j4 * 4] = *(const float4*)(vr + j4 * 4);
            }
        }
        __syncthreads();
        #pragma unroll 1
        for (int kb = 0; kb < 64; kb += 16) {
            float sc[16];
            #pragma unroll
            for (int kk = 0; kk < 16; ++kk) {
                float p = dot16(q, &k_s[kb + kk][g * 16]);
                p += __shfl_xor(p, 1);
                p += __shfl_xor(p, 2);
                sc[kk] = p;
            }
            float mt = sc[0];
            #pragma unroll
            for (int kk = 1; kk < 16; ++kk) mt = fmaxf(mt, sc[kk]);
            float mn = fmaxf(mrun, mt);
            float al = __expf(mrun - mn);
            float ssum = 0.f;
            #pragma unroll
            for (int kk = 0; kk < 16; ++kk) { sc[kk] = __expf(sc[kk] - mn); ssum += sc[kk]; }
            mrun = mn;
            lrun = fmaf(lrun, al, ssum);
            #pragma unroll
            for (int j = 0; j < 16; ++j) o[j] *= al;
            #pragma unroll
            for (int kk = 0; kk < 16; ++kk) pv16(o, sc[kk], &v_s[kb + kk][g * 16]);
        }
    }
    {
        const float* kr = kmat + ((size_t)(b * T_ + 2048)) * E_ + h * HD + g * 16;
        const float* vr = vmat + ((size_t)(b * T_ + 2048)) * E_ + h * HD + g * 16;
        float p = dot16(q, kr);
        p += __shfl_xor(p, 1);
        p += __shfl_xor(p, 2);
        float mn = fmaxf(mrun, p);
        float al = __expf(mrun - mn);
        float pk = __expf(p - mn);
        lrun = fmaf(lrun, al, pk);
        #pragma unroll
        for (int j = 0; j < 16; ++j) o[j] *= al;
        pv16(o, pk, vr);
    }

    if (valid) {
        float s = gates[0] / lrun;
        float* dst = out + ((size_t)b * Q_ + qi) * E_ + h * HD + g * 16;
        #pragma unroll
        for (int j4 = 0; j4 < 4; ++j4) {
            float4 ov;
            ov.x = o[j4 * 4 + 0] * s;
            ov.y = o[j4 * 4 + 1] * s;
            ov.z = o[j4 * 4 + 2] * s;
            ov.w = o[j4 * 4 + 3] * s;
            *(float4*)(dst + j4 * 4) = ov;
        }
    }
}

extern "C" void kernel_launch(void* const* d_in, const int* in_sizes, int n_in,
                              void* d_out, int out_size, void* d_ws, size_t ws_size,
                              hipStream_t stream) {
    // inputs: x_a(0), x_b(1), debug(2), Wk(3), Wv(4), Wpos(5),
    //         prompt(6), gates(7), pe(8), full_b_step(9), full_a_step(10)
    const float* x_b = (const float*)d_in[1];
    const float* debug = (const float*)d_in[2];
    const float* Wk = (const float*)d_in[3];
    const float* Wv = (const float*)d_in[4];
    const float* Wpos = (const float*)d_in[5];
    const float* prompt = (const float*)d_in[6];
    const float* gates = (const float*)d_in[7];
    const float* pe = (const float*)d_in[8];
    float* out = (float*)d_out;

    char* ws = (char*)d_ws;
    const size_t KVH = (size_t)MROWS * 1024 * sizeof(ushort);      // 16,785,408
    const size_t KVF = (size_t)MROWS * 1024 * sizeof(float);       // 33,570,816
    const size_t AF  = (size_t)MT_TILES * 32 * 64 * 8 * sizeof(ushort);  // 16,809,984
    const size_t WF  = (size_t)128 * 32 * 64 * 8 * sizeof(ushort);       //  4,194,304
    const size_t P50 = 256 * 1024;

    float*  proj50 = (float*)ws;                   // 200 KB used of 256 KB
    ushort* v2048u = (ushort*)(ws + 240 * 1024);   // 8 KB spare in P50 slab
    ushort* khi  = (ushort*)(ws + P50);
    ushort* klo  = (ushort*)(ws + P50 + KVH);
    float*  vbuf = (float*)(ws + P50 + 2 * KVH);   // fp32 region (fallback)
    ushort* afhi = (ushort*)(ws + P50 + 2 * KVH + KVF);
    ushort* aflo = (ushort*)(ws + P50 + 2 * KVH + KVF + AF);
    ushort* wfhi = (ushort*)(ws + P50 + 2 * KVH + KVF + 2 * AF);
    ushort* wflo = (ushort*)(ws + P50 + 2 * KVH + KVF + 2 * AF + WF);
    // main path aliasing: vfrag (17.04 MB) lives in the vbuf region
    // (33.57 MB) — written by kv_mfma, read by attn.
    ushort* vfrag = (ushort*)vbuf;
    const size_t needed = P50 + 2 * KVH + KVF + 2 * AF + 2 * WF;  // 109,412,352

    if (ws_size >= needed) {
        split_all_kernel<<<dim3(MT_TILES + 128 + 200), 256, 0, stream>>>(
            x_b, pe, prompt, Wk, Wv, Wpos, proj50, afhi, aflo, wfhi, wflo);
        kv_mfma_kernel<<<dim3(1040), 256, 0, stream>>>(afhi, aflo, wfhi, wflo,
                                                       khi, klo, vfrag, v2048u);
        attn_mfma_kernel<<<dim3(7, H_, B_), 512, 0, stream>>>(
            debug, proj50, khi, klo, vfrag, v2048u, gates, out);
    } else {
        proj50_kernel<<<dim3(50, 4), 256, 0, stream>>>(pe, Wpos, proj50);
        float* kbuf = (float*)khi;   // fallback: fp32 K in khi+klo region (same size)
        kv_gemm_kernel<<<dim3(16, 129), 256, 0, stream>>>(x_b, pe, prompt, Wk, Wv, kbuf, vbuf);
        attn_kernel<<<dim3(13, H_, B_), 256, 0, stream>>>(debug, proj50, kbuf, vbuf, gates, out);
    }
}

// Round 10
// 335.099 us; speedup vs baseline: 1.5465x; 1.0027x over previous
//
#include <hip/hip_runtime.h>
#include <hip/hip_bf16.h>
#include <math.h>

#define B_ 4
#define T_ 2049      // keys = prompt + 2048
#define TB 2048
#define Q_ 801
#define H_ 16
#define HD 64
#define E_ 1024
#define MROWS (B_ * T_)   // 8196
#define MT_TILES 513      // ceil(8196/16)

typedef short short8 __attribute__((ext_vector_type(8)));
typedef float floatx4 __attribute__((ext_vector_type(4)));
typedef int int4v __attribute__((ext_vector_type(4)));
typedef unsigned uint2v __attribute__((ext_vector_type(2)));

__device__ __forceinline__ ushort f2bf(float x) {
    unsigned u = __float_as_uint(x);
    unsigned r = (u + 0x7fffu + ((u >> 16) & 1u)) >> 16;
    return (ushort)r;
}
__device__ __forceinline__ float bf2f(ushort h) {
    return __uint_as_float(((unsigned)h) << 16);
}
__device__ __forceinline__ void gload16(const void* g, void* l) {
    __builtin_amdgcn_global_load_lds(
        (const __attribute__((address_space(1))) void*)g,
        (__attribute__((address_space(3))) void*)l, 16, 0, 0);
}
// raw v_exp_f32: computes 2^x (hardware exp2)
__device__ __forceinline__ float exp2raw(float x) {
    float r;
    asm("v_exp_f32 %0, %1" : "=v"(r) : "v"(x));
    return r;
}
// v_cvt_pk_bf16_f32: low16 = bf16(a), high16 = bf16(b)
__device__ __forceinline__ unsigned cvtpk(float a, float b) {
    unsigned r;
    asm("v_cvt_pk_bf16_f32 %0, %1, %2" : "=v"(r) : "v"(a), "v"(b));
    return r;
}

// ---------------- proj50 (fallback-path standalone) ------------------------
__global__ __launch_bounds__(256) void proj50_kernel(
    const float* __restrict__ pe, const float* __restrict__ Wpos,
    float* __restrict__ proj50) {
    __shared__ float pes[1024];
    const int r = blockIdx.x;        // 0..49
    const int t = threadIdx.x;       // 256
    for (int p = 0; p < 4; ++p) pes[t + p * 256] = pe[(size_t)r * 1024 + t + p * 256];
    __syncthreads();
    const int c = blockIdx.y * 256 + t;
    const float4* w4 = (const float4*)(Wpos + (size_t)c * 1024);
    float acc = 0.f;
    for (int i = 0; i < 256; ++i) {
        float4 wv = w4[i];
        acc = fmaf(pes[4 * i + 0], wv.x, acc);
        acc = fmaf(pes[4 * i + 1], wv.y, acc);
        acc = fmaf(pes[4 * i + 2], wv.z, acc);
        acc = fmaf(pes[4 * i + 3], wv.w, acc);
    }
    proj50[(size_t)r * 1024 + c] = acc;
}

// ---------------- split_all: kv rows + [Wk;Wv] rows + proj50 in ONE dispatch
// blocks [0,513): kv split; [513,641): W split; [641,841): proj50 (r,cy).
__global__ __launch_bounds__(256) void split_all_kernel(
    const float* __restrict__ x_b, const float* __restrict__ pe,
    const float* __restrict__ prompt,
    const float* __restrict__ Wk, const float* __restrict__ Wv,
    const float* __restrict__ Wpos, float* __restrict__ proj50,
    ushort* __restrict__ afhi, ushort* __restrict__ aflo,
    ushort* __restrict__ wfhi, ushort* __restrict__ wflo) {
    const int bid = blockIdx.x;
    const int t = threadIdx.x;
    const int lane = t & 63, kq = t >> 6;
    const int row_in = lane & 15, quad = lane >> 4;
    if (bid < MT_TILES) {
        const int mt = bid;
        int m = mt * 16 + row_in; if (m > MROWS - 1) m = MROWS - 1;
        const int b = m / T_, tt = m - b * T_;
        const float* src; const float* pesrc; float psc;
        if (tt == 0) { src = prompt; pesrc = pe; psc = 0.f; }
        else {
            src = x_b + ((size_t)b * TB + tt - 1) * 1024;
            pesrc = pe + (size_t)(tt - 1) * 1024;
            psc = 1.f;
        }
        #pragma unroll
        for (int rep = 0; rep < 8; ++rep) {
            int kc = rep * 4 + kq;
            int k0 = kc * 32 + quad * 8;
            float4 xa = *(const float4*)(src + k0);
            float4 xb2 = *(const float4*)(src + k0 + 4);
            float4 pa = *(const float4*)(pesrc + k0);
            float4 pb = *(const float4*)(pesrc + k0 + 4);
            float vv[8];
            vv[0] = fmaf(psc, pa.x, xa.x);  vv[1] = fmaf(psc, pa.y, xa.y);
            vv[2] = fmaf(psc, pa.z, xa.z);  vv[3] = fmaf(psc, pa.w, xa.w);
            vv[4] = fmaf(psc, pb.x, xb2.x); vv[5] = fmaf(psc, pb.y, xb2.y);
            vv[6] = fmaf(psc, pb.z, xb2.z); vv[7] = fmaf(psc, pb.w, xb2.w);
            union { ushort u[8]; short8 s; } hu, lu;
            #pragma unroll
            for (int j = 0; j < 8; ++j) {
                ushort h = f2bf(vv[j]);
                hu.u[j] = h;
                lu.u[j] = f2bf(vv[j] - bf2f(h));
            }
            size_t off = ((size_t)(mt * 32 + kc) * 64 + lane) * 8;
            *(short8*)(afhi + off) = hu.s;
            *(short8*)(aflo + off) = lu.s;
        }
    } else if (bid < MT_TILES + 128) {
        const int nt = bid - MT_TILES;        // 0..127
        const int n = nt * 16 + row_in;       // 0..2047
        const float* src = (n < 1024) ? Wk + (size_t)n * 1024
                                      : Wv + (size_t)(n - 1024) * 1024;
        #pragma unroll
        for (int rep = 0; rep < 8; ++rep) {
            int kc = rep * 4 + kq;
            int k0 = kc * 32 + quad * 8;
            float4 xa = *(const float4*)(src + k0);
            float4 xb2 = *(const float4*)(src + k0 + 4);
            float vv[8] = {xa.x, xa.y, xa.z, xa.w, xb2.x, xb2.y, xb2.z, xb2.w};
            union { ushort u[8]; short8 s; } hu, lu;
            #pragma unroll
            for (int j = 0; j < 8; ++j) {
                ushort h = f2bf(vv[j]);
                hu.u[j] = h;
                lu.u[j] = f2bf(vv[j] - bf2f(h));
            }
            size_t off = ((size_t)(nt * 32 + kc) * 64 + lane) * 8;
            *(short8*)(wfhi + off) = hu.s;
            *(short8*)(wflo + off) = lu.s;
        }
    } else {
        // proj50: pid in [0,200): r = pid%50, cy = pid/50
        __shared__ float pes[1024];
        const int pid = bid - (MT_TILES + 128);
        const int r = pid % 50, cy = pid / 50;
        for (int p = 0; p < 4; ++p) pes[t + p * 256] = pe[(size_t)r * 1024 + t + p * 256];
        __syncthreads();
        const int c = cy * 256 + t;
        const float4* w4 = (const float4*)(Wpos + (size_t)c * 1024);
        float acc = 0.f;
        for (int i = 0; i < 256; ++i) {
            float4 wv = w4[i];
            acc = fmaf(pes[4 * i + 0], wv.x, acc);
            acc = fmaf(pes[4 * i + 1], wv.y, acc);
            acc = fmaf(pes[4 * i + 2], wv.z, acc);
            acc = fmaf(pes[4 * i + 3], wv.w, acc);
        }
        proj50[(size_t)r * 1024 + c] = acc;
    }
}

// ---------------- Kernel 2: barrier-free MFMA K/V GEMM, XCD-localized ------
// V-path: single-plane (Ahi*Whi) — R9-verified below the bf16-V rounding
// floor (absmax unchanged).
__global__ __launch_bounds__(256) void kv_mfma_kernel(
    const ushort* __restrict__ afhi, const ushort* __restrict__ aflo,
    const ushort* __restrict__ wfhi, const ushort* __restrict__ wflo,
    ushort* __restrict__ khi, ushort* __restrict__ klo,
    ushort* __restrict__ vfrag, ushort* __restrict__ v2048) {

    const int t = threadIdx.x, lane = t & 63, w = t >> 6;
    const int wm = w >> 1, wn = w & 1;
    const int bid = blockIdx.x;
    const int c = bid & 7, jj2 = bid >> 3;
    int xx, yy;
    if (jj2 < 128) { yy = ((jj2 >> 4) << 3) + c; xx = jj2 & 15; }
    else           { yy = 64; xx = c * 2 + (jj2 - 128); }
    const int m0 = yy * 128, n0x = xx * 128;
    const bool isK = (xx < 8);
    const size_t lb = (size_t)lane * 8;

    const ushort* ah_p[4]; const ushort* al_p[4];
    const ushort* bh_p[4]; const ushort* bl_p[4];
    #pragma unroll
    for (int i = 0; i < 4; ++i) {
        size_t mt = (size_t)(yy * 8 + wm * 4 + i);
        ah_p[i] = afhi + mt * 16384 + lb;
        al_p[i] = aflo + mt * 16384 + lb;
        size_t nt = (size_t)(xx * 8 + wn * 4 + i);
        bh_p[i] = wfhi + nt * 16384 + lb;
        bl_p[i] = wflo + nt * 16384 + lb;
    }

    floatx4 acc[4][4];
    #pragma unroll
    for (int i = 0; i < 4; ++i)
        #pragma unroll
        for (int j = 0; j < 4; ++j)
            acc[i][j] = (floatx4){0.f, 0.f, 0.f, 0.f};

    if (isK) {
        short8 a0h[4], a0l[4], b0h[4], b0l[4];
        short8 a1h[4], a1l[4], b1h[4], b1l[4];
        #pragma unroll
        for (int i = 0; i < 4; ++i) {
            a0h[i] = *(const short8*)(ah_p[i]);
            a0l[i] = *(const short8*)(al_p[i]);
            b0h[i] = *(const short8*)(bh_p[i]);
            b0l[i] = *(const short8*)(bl_p[i]);
        }
        #pragma unroll 1
        for (int kc = 0; kc < 32; kc += 2) {
            {
                const int ko = (kc + 1) * 512;
                #pragma unroll
                for (int i = 0; i < 4; ++i) {
                    a1h[i] = *(const short8*)(ah_p[i] + ko);
                    a1l[i] = *(const short8*)(al_p[i] + ko);
                    b1h[i] = *(const short8*)(bh_p[i] + ko);
                    b1l[i] = *(const short8*)(bl_p[i] + ko);
                }
            }
            #pragma unroll
            for (int i = 0; i < 4; ++i)
                #pragma unroll
                for (int j = 0; j < 4; ++j) {
                    acc[i][j] = __builtin_amdgcn_mfma_f32_16x16x32_bf16(a0h[i], b0h[j], acc[i][j], 0, 0, 0);
                    acc[i][j] = __builtin_amdgcn_mfma_f32_16x16x32_bf16(a0h[i], b0l[j], acc[i][j], 0, 0, 0);
                    acc[i][j] = __builtin_amdgcn_mfma_f32_16x16x32_bf16(a0l[i], b0h[j], acc[i][j], 0, 0, 0);
                }
            if (kc + 2 < 32) {
                const int ko = (kc + 2) * 512;
                #pragma unroll
                for (int i = 0; i < 4; ++i) {
                    a0h[i] = *(const short8*)(ah_p[i] + ko);
                    a0l[i] = *(const short8*)(al_p[i] + ko);
                    b0h[i] = *(const short8*)(bh_p[i] + ko);
                    b0l[i] = *(const short8*)(bl_p[i] + ko);
                }
            }
            #pragma unroll
            for (int i = 0; i < 4; ++i)
                #pragma unroll
                for (int j = 0; j < 4; ++j) {
                    acc[i][j] = __builtin_amdgcn_mfma_f32_16x16x32_bf16(a1h[i], b1h[j], acc[i][j], 0, 0, 0);
                    acc[i][j] = __builtin_amdgcn_mfma_f32_16x16x32_bf16(a1h[i], b1l[j], acc[i][j], 0, 0, 0);
                    acc[i][j] = __builtin_amdgcn_mfma_f32_16x16x32_bf16(a1l[i], b1h[j], acc[i][j], 0, 0, 0);
                }
        }
    } else {
        short8 a0h[4], b0h[4];
        short8 a1h[4], b1h[4];
        #pragma unroll
        for (int i = 0; i < 4; ++i) {
            a0h[i] = *(const short8*)(ah_p[i]);
            b0h[i] = *(const short8*)(bh_p[i]);
        }
        #pragma unroll 1
        for (int kc = 0; kc < 32; kc += 2) {
            {
                const int ko = (kc + 1) * 512;
                #pragma unroll
                for (int i = 0; i < 4; ++i) {
                    a1h[i] = *(const short8*)(ah_p[i] + ko);
                    b1h[i] = *(const short8*)(bh_p[i] + ko);
                }
            }
            #pragma unroll
            for (int i = 0; i < 4; ++i)
                #pragma unroll
                for (int j = 0; j < 4; ++j)
                    acc[i][j] = __builtin_amdgcn_mfma_f32_16x16x32_bf16(a0h[i], b0h[j], acc[i][j], 0, 0, 0);
            if (kc + 2 < 32) {
                const int ko = (kc + 2) * 512;
                #pragma unroll
                for (int i = 0; i < 4; ++i) {
                    a0h[i] = *(const short8*)(ah_p[i] + ko);
                    b0h[i] = *(const short8*)(bh_p[i] + ko);
                }
            }
            #pragma unroll
            for (int i = 0; i < 4; ++i)
                #pragma unroll
                for (int j = 0; j < 4; ++j)
                    acc[i][j] = __builtin_amdgcn_mfma_f32_16x16x32_bf16(a1h[i], b1h[j], acc[i][j], 0, 0, 0);
        }
    }

    // epilogue: C layout col = lane&15, row = (lane>>4)*4 + reg
    const int frow = lane & 15, foct = lane >> 4;
    const int ncol = (n0x & 1023) + wn * 64 + frow;
    if (isK) {
        #pragma unroll
        for (int i = 0; i < 4; ++i) {
            #pragma unroll
            for (int r = 0; r < 4; ++r) {
                int row = m0 + wm * 64 + i * 16 + foct * 4 + r;
                if (row < MROWS) {
                    #pragma unroll
                    for (int j = 0; j < 4; ++j) {
                        float v = acc[i][j][r];
                        ushort hv = f2bf(v);
                        ushort lv = f2bf(v - bf2f(hv));
                        khi[(size_t)row * 1024 + ncol + j * 16] = hv;
                        klo[(size_t)row * 1024 + ncol + j * 16] = lv;
                    }
                }
            }
        }
    } else {
        // V: direct V^T fragment-major write (replaces vprep)
        const int hh = ((n0x & 1023) + wn * 64) >> 6;   // head 0..15
        #pragma unroll
        for (int i = 0; i < 4; ++i) {
            #pragma unroll
            for (int r = 0; r < 4; ++r) {
                int row = m0 + wm * 64 + i * 16 + foct * 4 + r;
                if (row < MROWS) {
                    int bb = row / T_;
                    int tt = row - bb * T_;      // key index 0..2048
                    if (tt < 2048) {
                        size_t vb = ((size_t)(bb * 16 + hh) * 65 + (tt >> 5)) * 4;
                        size_t lo_ = (size_t)(((tt >> 3) & 3) * 16 + frow) * 8 + (tt & 7);
                        #pragma unroll
                        for (int j = 0; j < 4; ++j)
                            vfrag[(vb + j) * 512 + lo_] = f2bf(acc[i][j][r]);
                    } else {
                        #pragma unroll
                        for (int j = 0; j < 4; ++j)
                            v2048[bb * 1024 + hh * 64 + j * 16 + frow] = f2bf(acc[i][j][r]);
                    }
                }
            }
        }
    }
}

// ---------------- Kernel 3: 8-wave MFMA flash attention, swapped-QK --------
// EXACT R5 loop structure (best measured) — locked per R6/R7 pre-commits.
// One block per (b,h,q-tile) does all 32 tiles + key-2048 tail; gated,
// normalized output written directly to `out`.
// R10: 1-D grid with bijective XCD swizzle — the 7 q-tiles of each (b,h)
// share bid%8 so (under round-robin dispatch) they land on one XCD and
// share the 640 KB K/V panel in that XCD's L2 (R9 FETCH showed 7x re-read).
__global__ __launch_bounds__(512, 4) void attn_mfma_kernel(
    const float* __restrict__ debug, const float* __restrict__ proj50,
    const ushort* __restrict__ khi, const ushort* __restrict__ klo,
    const ushort* __restrict__ vfrag, const ushort* __restrict__ v2048,
    const float* __restrict__ gates, float* __restrict__ out) {

    __shared__ __align__(16) ushort Ksh[2][16 * 512];    // 32 KB
    __shared__ __align__(16) unsigned Pshh[8][16][20];   // 10 KB
    __shared__ __align__(16) unsigned Pshl[8][16][20];   // 10 KB

    const int t = threadIdx.x, lane = t & 63, w = t >> 6;   // 8 waves
    const int frow = lane & 15, quad = lane >> 4;
    // XCD swizzle: bid -> (b,h,qt); 448 = 8 XCD-residues x 8 groups x 7 tiles
    const int bid = blockIdx.x;
    const int cxcd = bid & 7, j = bid >> 3;       // j in [0,56)
    const int gg = j / 7, qt = j - gg * 7;        // gg in [0,8), qt in [0,7)
    const int g = gg * 8 + cxcd;                  // group in [0,64)
    const int h = g & 15, b = g >> 4;
    const int qwave = qt * 128 + w * 16;
    const int ntiles = 32;                  // keys [0, 2048)

    // staging role: wave w stages key-group kg = w>>1, planes s = (w&1)*2+{0,1}
    const int skg = w >> 1, ssb = (w & 1) * 2;

    // Q in exp2 domain: scale = 0.125 * log2(e)
    const float qscale = 0.1803368801111244f;
    short8 qh[2], ql[2];
    {
        int qrow = qwave + frow; if (qrow > Q_ - 1) qrow = Q_ - 1;
        int idx = (qrow * 50) / Q_;
        const float* dsrc = debug + (((size_t)(b * H_ + h)) * Q_ + qrow) * HD;
        const float* psrc = proj50 + (size_t)idx * 1024 + h * HD;
        #pragma unroll
        for (int dc = 0; dc < 2; ++dc) {
            int d0 = dc * 32 + quad * 8;
            union { ushort u[8]; short8 v; } hh, ll;
            #pragma unroll
            for (int j2 = 0; j2 < 8; ++j2) {
                float v = (dsrc[d0 + j2] + psrc[d0 + j2]) * qscale;
                ushort hv = f2bf(v);
                hh.u[j2] = hv;
                ll.u[j2] = f2bf(v - bf2f(hv));
            }
            qh[dc] = hh.v; ql[dc] = ll.v;
        }
    }

    floatx4 oacc[4];    // O^T: oacc[df][r] = O[q=frow][dim=df*16+quad*4+r]
    #pragma unroll
    for (int d = 0; d < 4; ++d) oacc[d] = (floatx4){0.f, 0.f, 0.f, 0.f};
    float lsum = 0.f;   // per-lane partial of l[q=frow] over this quad's keys

    unsigned* Pwh = &Pshh[w][0][0];
    unsigned* Pwl = &Pshl[w][0][0];
    const size_t bT = (size_t)b * T_;
    const size_t vbh = (size_t)(b * 16 + h) * 65;

    // prologue: stage K tile 0 into Ksh[0]
    {
        int key = skg * 16 + frow;
        const size_t rowoff = (bT + key) * 1024 + h * 64 + quad * 8;
        #pragma unroll
        for (int j2 = 0; j2 < 2; ++j2) {
            int s = ssb + j2;
            int dc = s >> 1, pl2 = s & 1;
            const ushort* src = (pl2 ? klo : khi) + rowoff + dc * 32;
            gload16(src, &Ksh[0][(skg * 4 + s) * 512]);
        }
    }
    __syncthreads();   // drains vmcnt(0): K[0] landed

    for (int ti = 0; ti < ntiles; ++ti) {
        const int t0 = ti * 64;
        const int cur = ti & 1;

        // V reg-loads (oldest VMEM, keeps K prefetch in flight)
        short8 vreg[2][4];
        #pragma unroll
        for (int kc = 0; kc < 2; ++kc) {
            int kcg = (t0 >> 5) + kc;
            const ushort* vsrc = vfrag + ((vbh + kcg) * 4) * 512 + lane * 8;
            #pragma unroll
            for (int df = 0; df < 4; ++df)
                vreg[kc][df] = *(const short8*)(vsrc + df * 512);
        }

        // issue NEXT tile's K stage into the other buffer (no wait here)
        if (ti + 1 < ntiles) {
            int key = t0 + 64 + skg * 16 + frow;
            const size_t rowoff = (bT + key) * 1024 + h * 64 + quad * 8;
            #pragma unroll
            for (int j2 = 0; j2 < 2; ++j2) {
                int s = ssb + j2;
                int dc = s >> 1, pl2 = s & 1;
                const ushort* src = (pl2 ? klo : khi) + rowoff + dc * 32;
                gload16(src, &Ksh[cur ^ 1][(skg * 4 + s) * 512]);
            }
        }

        // swapped QK^T: sacc[kg] = C[key_local=quad*4+r][q=frow]
        floatx4 sacc[4];
        __builtin_amdgcn_s_setprio(1);
        #pragma unroll
        for (int kg = 0; kg < 4; ++kg) {
            sacc[kg] = (floatx4){0.f, 0.f, 0.f, 0.f};
            #pragma unroll
            for (int dc = 0; dc < 2; ++dc) {
                short8 kh = *(const short8*)&Ksh[cur][(kg * 4 + dc * 2 + 0) * 512 + lane * 8];
                short8 kl = *(const short8*)&Ksh[cur][(kg * 4 + dc * 2 + 1) * 512 + lane * 8];
                sacc[kg] = __builtin_amdgcn_mfma_f32_16x16x32_bf16(kh, qh[dc], sacc[kg], 0, 0, 0);
                sacc[kg] = __builtin_amdgcn_mfma_f32_16x16x32_bf16(kl, qh[dc], sacc[kg], 0, 0, 0);
                sacc[kg] = __builtin_amdgcn_mfma_f32_16x16x32_bf16(kh, ql[dc], sacc[kg], 0, 0, 0);
            }
        }
        __builtin_amdgcn_s_setprio(0);

        // per-kc: exp + cvt_pk pack -> Psh(b64) -> b128 read = B-frag, PV
        #pragma unroll
        for (int kc = 0; kc < 2; ++kc) {
            #pragma unroll
            for (int kg2 = 0; kg2 < 2; ++kg2) {
                int kg = kc * 2 + kg2;
                float p0 = exp2raw(sacc[kg][0]);
                float p1 = exp2raw(sacc[kg][1]);
                float p2 = exp2raw(sacc[kg][2]);
                float p3 = exp2raw(sacc[kg][3]);
                lsum += (p0 + p1) + (p2 + p3);
                unsigned dh0 = cvtpk(p0, p1);
                float l0 = p0 - __uint_as_float(dh0 << 16);
                float l1 = p1 - __uint_as_float(dh0 & 0xffff0000u);
                unsigned dl0 = cvtpk(l0, l1);
                unsigned dh1 = cvtpk(p2, p3);
                float l2 = p2 - __uint_as_float(dh1 << 16);
                float l3 = p3 - __uint_as_float(dh1 & 0xffff0000u);
                unsigned dl1 = cvtpk(l2, l3);
                int k2 = kg2 * 8 + quad * 2;   // dword index within kc
                *(uint2v*)&Pwh[frow * 20 + k2] = (uint2v){dh0, dh1};
                *(uint2v*)&Pwl[frow * 20 + k2] = (uint2v){dl0, dl1};
            }
            // reader lane (q=frow, dq=quad): b128 = keys dq*8+{0..7} packed
            short8 bh = *(const short8*)&Pwh[frow * 20 + quad * 4];
            short8 bl = *(const short8*)&Pwl[frow * 20 + quad * 4];
            __builtin_amdgcn_s_setprio(1);
            #pragma unroll
            for (int df = 0; df < 4; ++df) {
                oacc[df] = __builtin_amdgcn_mfma_f32_16x16x32_bf16(vreg[kc][df], bh, oacc[df], 0, 0, 0);
                oacc[df] = __builtin_amdgcn_mfma_f32_16x16x32_bf16(vreg[kc][df], bl, oacc[df], 0, 0, 0);
            }
            __builtin_amdgcn_s_setprio(0);
        }

        __syncthreads();   // drains vmcnt (next K landed); Ksh rotation safe
    }

    // l[q]: reduce partials over the 4 quads (lane bits 4,5)
    lsum += __shfl_xor(lsum, 16);
    lsum += __shfl_xor(lsum, 32);

    // key 2048 (last row): scalar fp32 path
    {
        const size_t ro = (bT + 2048) * 1024 + (size_t)h * 64 + quad * 8;
        float p = 0.f;
        #pragma unroll
        for (int dc = 0; dc < 2; ++dc) {
            union { short8 v; ushort u[8]; } KH, KL, QH, QL;
            KH.v = *(const short8*)(khi + ro + dc * 32);
            KL.v = *(const short8*)(klo + ro + dc * 32);
            QH.v = qh[dc]; QL.v = ql[dc];
            #pragma unroll
            for (int j2 = 0; j2 < 8; ++j2) {
                float kf = bf2f(KH.u[j2]) + bf2f(KL.u[j2]);
                float qf = bf2f(QH.u[j2]) + bf2f(QL.u[j2]);
                p = fmaf(qf, kf, p);
            }
        }
        p += __shfl_xor(p, 16);
        p += __shfl_xor(p, 32);
        float e = exp2raw(p);
        lsum += e;
        const ushort* vr = v2048 + b * 1024 + h * 64 + quad * 4;
        #pragma unroll
        for (int df = 0; df < 4; ++df)
            #pragma unroll
            for (int r = 0; r < 4; ++r)
                oacc[df][r] = fmaf(e, bf2f(vr[df * 16 + r]), oacc[df][r]);
    }

    // epilogue: gated, normalized O^T -> contiguous float4 stores; q = frow
    int q = qwave + frow;
    if (q < Q_) {
        float s = gates[0] / lsum;
        float* dst = out + ((size_t)b * Q_ + q) * E_ + h * HD + quad * 4;
        #pragma unroll
        for (int df = 0; df < 4; ++df) {
            float4 o4;
            o4.x = oacc[df][0] * s; o4.y = oacc[df][1] * s;
            o4.z = oacc[df][2] * s; o4.w = oacc[df][3] * s;
            *(float4*)(dst + df * 16) = o4;
        }
    }
}

// ---------------- Fallback fp32 path (if workspace too small) --------------
#define SMK 36
__global__ __launch_bounds__(256) void kv_gemm_kernel(
    const float* __restrict__ x_b, const float* __restrict__ pe,
    const float* __restrict__ prompt,
    const float* __restrict__ Wk, const float* __restrict__ Wv,
    float* __restrict__ kout, float* __restrict__ vout) {

    __shared__ float As[64][SMK];
    __shared__ float Bks[64][SMK];
    __shared__ float Bvs[64][SMK];

    const int t = threadIdx.x;
    const int m0 = blockIdx.y * 64;
    const int n0 = blockIdx.x * 64;
    const int tx = t & 15, ty = t >> 4;
    const int rr = t >> 2;
    const int kp = (t & 3) * 8;

    int m = m0 + rr;
    if (m >= MROWS) m = 0;
    const int bb = m / T_;
    const int tt = m - bb * T_;
    const float* aptr; const float* peptr; float pesc;
    if (tt == 0) { aptr = prompt; peptr = pe; pesc = 0.f; }
    else {
        aptr = x_b + ((size_t)bb * TB + (tt - 1)) * 1024;
        peptr = pe + (size_t)(tt - 1) * 1024;
        pesc = 1.f;
    }
    const float* wkp = Wk + (size_t)(n0 + rr) * 1024;
    const float* wvp = Wv + (size_t)(n0 + rr) * 1024;

    float ck[4][4] = {{0.f}}, cv[4][4] = {{0.f}};

    for (int k0 = 0; k0 < 1024; k0 += 32) {
        __syncthreads();
        {
            float4 xa0 = *(const float4*)(aptr + k0 + kp);
            float4 xa1 = *(const float4*)(aptr + k0 + kp + 4);
            float4 pe0 = *(const float4*)(peptr + k0 + kp);
            float4 pe1 = *(const float4*)(peptr + k0 + kp + 4);
            xa0.x = fmaf(pesc, pe0.x, xa0.x);
            xa0.y = fmaf(pesc, pe0.y, xa0.y);
            xa0.z = fmaf(pesc, pe0.z, xa0.z);
            xa0.w = fmaf(pesc, pe0.w, xa0.w);
            xa1.x = fmaf(pesc, pe1.x, xa1.x);
            xa1.y = fmaf(pesc, pe1.y, xa1.y);
            xa1.z = fmaf(pesc, pe1.z, xa1.z);
            xa1.w = fmaf(pesc, pe1.w, xa1.w);
            *(float4*)&As[rr][kp]     = xa0;
            *(float4*)&As[rr][kp + 4] = xa1;
            *(float4*)&Bks[rr][kp]     = *(const float4*)(wkp + k0 + kp);
            *(float4*)&Bks[rr][kp + 4] = *(const float4*)(wkp + k0 + kp + 4);
            *(float4*)&Bvs[rr][kp]     = *(const float4*)(wvp + k0 + kp);
            *(float4*)&Bvs[rr][kp + 4] = *(const float4*)(wvp + k0 + kp + 4);
        }
        __syncthreads();
        for (int k4 = 0; k4 < 8; ++k4) {
            float4 a[4], bk[4], bv[4];
            #pragma unroll
            for (int i = 0; i < 4; ++i) a[i] = *(const float4*)&As[ty * 4 + i][k4 * 4];
            #pragma unroll
            for (int j = 0; j < 4; ++j) {
                bk[j] = *(const float4*)&Bks[tx * 4 + j][k4 * 4];
                bv[j] = *(const float4*)&Bvs[tx * 4 + j][k4 * 4];
            }
            #pragma unroll
            for (int i = 0; i < 4; ++i)
                #pragma unroll
                for (int j = 0; j < 4; ++j) {
                    ck[i][j] = fmaf(a[i].x, bk[j].x, ck[i][j]);
                    ck[i][j] = fmaf(a[i].y, bk[j].y, ck[i][j]);
                    ck[i][j] = fmaf(a[i].z, bk[j].z, ck[i][j]);
                    ck[i][j] = fmaf(a[i].w, bk[j].w, ck[i][j]);
                    cv[i][j] = fmaf(a[i].x, bv[j].x, cv[i][j]);
                    cv[i][j] = fmaf(a[i].y, bv[j].y, cv[i][j]);
                    cv[i][j] = fmaf(a[i].z, bv[j].z, cv[i][j]);
                    cv[i][j] = fmaf(a[i].w, bv[j].w, cv[i][j]);
                }
        }
    }

    #pragma unroll
    for (int i = 0; i < 4; ++i) {
        int mrow = m0 + ty * 4 + i;
        if (mrow < MROWS) {
            float4 kq, vq;
            kq.x = ck[i][0]; kq.y = ck[i][1]; kq.z = ck[i][2]; kq.w = ck[i][3];
            vq.x = cv[i][0]; vq.y = cv[i][1]; vq.z = cv[i][2]; vq.w = cv[i][3];
            *(float4*)(kout + (size_t)mrow * 1024 + n0 + tx * 4) = kq;
            *(float4*)(vout + (size_t)mrow * 1024 + n0 + tx * 4) = vq;
        }
    }
}

#define KSTR 68
__device__ __forceinline__ float dot16(const float (&q)[16], const float* kf) {
    float4 k0 = *(const float4*)(kf);
    float4 k1 = *(const float4*)(kf + 4);
    float4 k2 = *(const float4*)(kf + 8);
    float4 k3 = *(const float4*)(kf + 12);
    float p;
    p = q[0] * k0.x;
    p = fmaf(q[1], k0.y, p);  p = fmaf(q[2], k0.z, p);  p = fmaf(q[3], k0.w, p);
    p = fmaf(q[4], k1.x, p);  p = fmaf(q[5], k1.y, p);  p = fmaf(q[6], k1.z, p);  p = fmaf(q[7], k1.w, p);
    p = fmaf(q[8], k2.x, p);  p = fmaf(q[9], k2.y, p);  p = fmaf(q[10], k2.z, p); p = fmaf(q[11], k2.w, p);
    p = fmaf(q[12], k3.x, p); p = fmaf(q[13], k3.y, p); p = fmaf(q[14], k3.z, p); p = fmaf(q[15], k3.w, p);
    return p;
}
__device__ __forceinline__ void pv16(float (&o)[16], float pk, const float* vf) {
    float4 v0 = *(const float4*)(vf);
    float4 v1 = *(const float4*)(vf + 4);
    float4 v2 = *(const float4*)(vf + 8);
    float4 v3 = *(const float4*)(vf + 12);
    o[0]  = fmaf(pk, v0.x, o[0]);  o[1]  = fmaf(pk, v0.y, o[1]);
    o[2]  = fmaf(pk, v0.z, o[2]);  o[3]  = fmaf(pk, v0.w, o[3]);
    o[4]  = fmaf(pk, v1.x, o[4]);  o[5]  = fmaf(pk, v1.y, o[5]);
    o[6]  = fmaf(pk, v1.z, o[6]);  o[7]  = fmaf(pk, v1.w, o[7]);
    o[8]  = fmaf(pk, v2.x, o[8]);  o[9]  = fmaf(pk, v2.y, o[9]);
    o[10] = fmaf(pk, v2.z, o[10]); o[11] = fmaf(pk, v2.w, o[11]);
    o[12] = fmaf(pk, v3.x, o[12]); o[13] = fmaf(pk, v3.y, o[13]);
    o[14] = fmaf(pk, v3.z, o[14]); o[15] = fmaf(pk, v3.w, o[15]);
}

__global__ __launch_bounds__(256) void attn_kernel(
    const float* __restrict__ debug, const float* __restrict__ proj50,
    const float* __restrict__ kmat, const float* __restrict__ vmat,
    const float* __restrict__ gates, float* __restrict__ out) {

    __shared__ float k_s[64][KSTR];
    __shared__ float v_s[64][KSTR];

    const int t = threadIdx.x;
    const int lane = t & 63;
    const int w = t >> 6;
    const int r = lane >> 2;
    const int g = lane & 3;
    const int qi = blockIdx.x * 64 + w * 16 + r;
    const int h = blockIdx.y, b = blockIdx.z;
    const bool valid = qi < Q_;

    float q[16], o[16];
    {
        int qq = valid ? qi : 0;
        int idx = (qq * 50) / Q_;
        const float* dsrc = debug + (((size_t)(b * H_ + h)) * Q_ + qq) * HD + g * 16;
        const float* psrc = proj50 + (size_t)idx * 1024 + h * HD + g * 16;
        #pragma unroll
        for (int j4 = 0; j4 < 4; ++j4) {
            float4 dv = *(const float4*)(dsrc + j4 * 4);
            float4 pv = *(const float4*)(psrc + j4 * 4);
            q[j4 * 4 + 0] = (dv.x + pv.x) * 0.125f;
            q[j4 * 4 + 1] = (dv.y + pv.y) * 0.125f;
            q[j4 * 4 + 2] = (dv.z + pv.z) * 0.125f;
            q[j4 * 4 + 3] = (dv.w + pv.w) * 0.125f;
        }
    }
    float mrun = -INFINITY, lrun = 0.f;
    #pragma unroll
    for (int j = 0; j < 16; ++j) o[j] = 0.f;

    const int srow = t >> 2;
    const int scol = (t & 3) * 16;
    const float* kbase = kmat + ((size_t)b * T_) * E_ + h * HD + scol;
    const float* vbase = vmat + ((size_t)b * T_) * E_ + h * HD + scol;

    for (int t0 = 0; t0 < 2048; t0 += 64) {
        __syncthreads();
        {
            const float* kr = kbase + (size_t)(t0 + srow) * E_;
            const float* vr = vbase + (size_t)(t0 + srow) * E_;
            #pragma unroll
            for (int j4 = 0; j4 < 4; ++j4) {
                *(float4*)&k_s[srow][scol + j4 * 4] = *(const float4*)(kr + j4 * 4);
                *(float4*)&v_s[srow][scol + j4 * 4] = *(const float4*)(vr + j4 * 4);
            }
        }
        __syncthreads();
        #pragma unroll 1
        for (int kb = 0; kb < 64; kb += 16) {
            float sc[16];
            #pragma unroll
            for (int kk = 0; kk < 16; ++kk) {
                float p = dot16(q, &k_s[kb + kk][g * 16]);
                p += __shfl_xor(p, 1);
                p += __shfl_xor(p, 2);
                sc[kk] = p;
            }
            float mt = sc[0];
            #pragma unroll
            for (int kk = 1; kk < 16; ++kk) mt = fmaxf(mt, sc[kk]);
            float mn = fmaxf(mrun, mt);
            float al = __expf(mrun - mn);
            float ssum = 0.f;
            #pragma unroll
            for (int kk = 0; kk < 16; ++kk) { sc[kk] = __expf(sc[kk] - mn); ssum += sc[kk]; }
            mrun = mn;
            lrun = fmaf(lrun, al, ssum);
            #pragma unroll
            for (int j = 0; j < 16; ++j) o[j] *= al;
            #pragma unroll
            for (int kk = 0; kk < 16; ++kk) pv16(o, sc[kk], &v_s[kb + kk][g * 16]);
        }
    }
    {
        const float* kr = kmat + ((size_t)(b * T_ + 2048)) * E_ + h * HD + g * 16;
        const float* vr = vmat + ((size_t)(b * T_ + 2048)) * E_ + h * HD + g * 16;
        float p = dot16(q, kr);
        p += __shfl_xor(p, 1);
        p += __shfl_xor(p, 2);
        float mn = fmaxf(mrun, p);
        float al = __expf(mrun - mn);
        float pk = __expf(p - mn);
        lrun = fmaf(lrun, al, pk);
        #pragma unroll
        for (int j = 0; j < 16; ++j) o[j] *= al;
        pv16(o, pk, vr);
    }

    if (valid) {
        float s = gates[0] / lrun;
        float* dst = out + ((size_t)b * Q_ + qi) * E_ + h * HD + g * 16;
        #pragma unroll
        for (int j4 = 0; j4 < 4; ++j4) {
            float4 ov;
            ov.x = o[j4 * 4 + 0] * s;
            ov.y = o[j4 * 4 + 1] * s;
            ov.z = o[j4 * 4 + 2] * s;
            ov.w = o[j4 * 4 + 3] * s;
            *(float4*)(dst + j4 * 4) = ov;
        }
    }
}

extern "C" void kernel_launch(void* const* d_in, const int* in_sizes, int n_in,
                              void* d_out, int out_size, void* d_ws, size_t ws_size,
                              hipStream_t stream) {
    // inputs: x_a(0), x_b(1), debug(2), Wk(3), Wv(4), Wpos(5),
    //         prompt(6), gates(7), pe(8), full_b_step(9), full_a_step(10)
    const float* x_b = (const float*)d_in[1];
    const float* debug = (const float*)d_in[2];
    const float* Wk = (const float*)d_in[3];
    const float* Wv = (const float*)d_in[4];
    const float* Wpos = (const float*)d_in[5];
    const float* prompt = (const float*)d_in[6];
    const float* gates = (const float*)d_in[7];
    const float* pe = (const float*)d_in[8];
    float* out = (float*)d_out;

    char* ws = (char*)d_ws;
    const size_t KVH = (size_t)MROWS * 1024 * sizeof(ushort);      // 16,785,408
    const size_t VF  = (size_t)B_ * 16 * 65 * 4 * 512 * sizeof(ushort);  // 17,039,360
    const size_t AF  = (size_t)MT_TILES * 32 * 64 * 8 * sizeof(ushort);  // 16,809,984
    const size_t WF  = (size_t)128 * 32 * 64 * 8 * sizeof(ushort);       //  4,194,304
    const size_t P50 = 256 * 1024;

    // Compact layout (R10): vfrag gets exactly VF (not the fp32 slab) —
    // workspace 109.4 -> 92.9 MB (less harness poison traffic per iter).
    float*  proj50 = (float*)ws;                   // 200 KB used of 256 KB
    ushort* v2048u = (ushort*)(ws + 240 * 1024);   // 8 KB spare in P50 slab
    ushort* khi   = (ushort*)(ws + P50);
    ushort* klo   = (ushort*)(ws + P50 + KVH);
    ushort* vfrag = (ushort*)(ws + P50 + 2 * KVH);
    ushort* afhi  = (ushort*)(ws + P50 + 2 * KVH + VF);
    ushort* aflo  = (ushort*)(ws + P50 + 2 * KVH + VF + AF);
    ushort* wfhi  = (ushort*)(ws + P50 + 2 * KVH + VF + 2 * AF);
    ushort* wflo  = (ushort*)(ws + P50 + 2 * KVH + VF + 2 * AF + WF);
    const size_t needed = P50 + 2 * KVH + VF + 2 * AF + 2 * WF;   // 92,902,912

    if (ws_size >= needed) {
        split_all_kernel<<<dim3(MT_TILES + 128 + 200), 256, 0, stream>>>(
            x_b, pe, prompt, Wk, Wv, Wpos, proj50, afhi, aflo, wfhi, wflo);
        kv_mfma_kernel<<<dim3(1040), 256, 0, stream>>>(afhi, aflo, wfhi, wflo,
                                                       khi, klo, vfrag, v2048u);
        attn_mfma_kernel<<<dim3(448), 512, 0, stream>>>(
            debug, proj50, khi, klo, vfrag, v2048u, gates, out);
    } else {
        proj50_kernel<<<dim3(50, 4), 256, 0, stream>>>(pe, Wpos, proj50);
        // fallback: fp32 K in khi+klo region (33.6 MB), fp32 V after it
        float* kbuf = (float*)khi;
        float* vbuf = (float*)(ws + P50 + 2 * KVH);
        kv_gemm_kernel<<<dim3(16, 129), 256, 0, stream>>>(x_b, pe, prompt, Wk, Wv, kbuf, vbuf);
        attn_kernel<<<dim3(13, H_, B_), 256, 0, stream>>>(debug, proj50, kbuf, vbuf, gates, out);
    }
}